// Round 1
// baseline (5824.188 us; speedup 1.0000x reference)
//
#include <hip/hip_runtime.h>
#include <math.h>

#define NPAD   16384
#define PADR   254
#define NTOK   16130
#define NPIX   16129
#define SG     127
#define DD     512
#define NH     8

// ---------------- fp32 GEMM, 128x128 tile, 256 threads, 8x8/thread ----------------
// mode 0: C = acc ; mode 1: C = relu(acc+bias) ; mode 2: C = acc*(col<512?0.125:1)
// mode 3: C += acc + bias
__global__ __launch_bounds__(256) void gemm128(
    const float* __restrict__ A, int lda,
    const float* __restrict__ B, int ldb,
    float* __restrict__ C, int ldc,
    int M, int K, int mode, const float* __restrict__ bias)
{
  __shared__ float As[16][132];
  __shared__ float Bs[16][132];
  const int tid = threadIdx.x;
  const int tx = tid & 15, ty = tid >> 4;
  const int m0 = blockIdx.y * 128;
  const int n0 = blockIdx.x * 128;
  float acc[8][8];
#pragma unroll
  for (int i = 0; i < 8; ++i)
#pragma unroll
    for (int j = 0; j < 8; ++j) acc[i][j] = 0.f;

  for (int k0 = 0; k0 < K; k0 += 16) {
#pragma unroll
    for (int l = 0; l < 2; ++l) {
      int idx = tid + l * 256;
      int row = idx >> 2;
      int k4  = (idx & 3) << 2;
      float4 v = make_float4(0.f, 0.f, 0.f, 0.f);
      int gr = m0 + row;
      if (gr < M) v = *(const float4*)(A + (size_t)gr * lda + k0 + k4);
      As[k4 + 0][row] = v.x;
      As[k4 + 1][row] = v.y;
      As[k4 + 2][row] = v.z;
      As[k4 + 3][row] = v.w;
    }
#pragma unroll
    for (int l = 0; l < 2; ++l) {
      int idx = tid + l * 256;
      int row = idx >> 5;
      int c4  = (idx & 31) << 2;
      *(float4*)&Bs[row][c4] = *(const float4*)(B + (size_t)(k0 + row) * ldb + n0 + c4);
    }
    __syncthreads();
#pragma unroll
    for (int k = 0; k < 16; ++k) {
      float a[8], b[8];
      *(float4*)&a[0] = *(const float4*)&As[k][ty * 4];
      *(float4*)&a[4] = *(const float4*)&As[k][64 + ty * 4];
      *(float4*)&b[0] = *(const float4*)&Bs[k][tx * 4];
      *(float4*)&b[4] = *(const float4*)&Bs[k][64 + tx * 4];
#pragma unroll
      for (int i = 0; i < 8; ++i)
#pragma unroll
        for (int j = 0; j < 8; ++j) acc[i][j] = fmaf(a[i], b[j], acc[i][j]);
    }
    __syncthreads();
  }
#pragma unroll
  for (int i = 0; i < 8; ++i) {
    int rloc = (i < 4) ? (ty * 4 + i) : (64 + ty * 4 + (i - 4));
    int row = m0 + rloc;
    if (row >= M) continue;
#pragma unroll
    for (int jh = 0; jh < 2; ++jh) {
      int col = n0 + jh * 64 + tx * 4;
      float* cp = C + (size_t)row * ldc + col;
      float4 r;
      r.x = acc[i][jh*4+0]; r.y = acc[i][jh*4+1];
      r.z = acc[i][jh*4+2]; r.w = acc[i][jh*4+3];
      if (mode == 1) {
        float4 bb = *(const float4*)(bias + col);
        r.x = fmaxf(r.x + bb.x, 0.f); r.y = fmaxf(r.y + bb.y, 0.f);
        r.z = fmaxf(r.z + bb.z, 0.f); r.w = fmaxf(r.w + bb.w, 0.f);
      } else if (mode == 2) {
        float s = (col < 512) ? 0.125f : 1.f;
        r.x *= s; r.y *= s; r.z *= s; r.w *= s;
      } else if (mode == 3) {
        float4 bb = *(const float4*)(bias + col);
        float4 o  = *(const float4*)cp;
        r.x += o.x + bb.x; r.y += o.y + bb.y;
        r.z += o.z + bb.z; r.w += o.w + bb.w;
      }
      *(float4*)cp = r;
    }
  }
}

// ---------------- assemble: h[0]=cls, h[16001+i]=h[1+i] (i<129) ----------------
__global__ __launch_bounds__(256) void assemble_kernel(float* __restrict__ h,
                                                       const float* __restrict__ cls)
{
  int idx = blockIdx.x * 256 + threadIdx.x;   // 260*256 = 66560 = 512 + 129*512
  if (idx < 512) { h[idx] = cls[idx]; return; }
  idx -= 512;
  int i = idx >> 9, c = idx & 511;
  h[(size_t)(16001 + i) * DD + c] = h[(size_t)(1 + i) * DD + c];
}

// ---------------- LayerNorm rows of h -> xn (front-padded, rows<PADR zeroed) ----------------
__global__ __launch_bounds__(256) void ln_pad_kernel(
    const float* __restrict__ h, float* __restrict__ xn,
    const float* __restrict__ g, const float* __restrict__ b)
{
  int row = blockIdx.x;        // 0..16383
  int t = threadIdx.x;
  if (row < PADR) {
    xn[(size_t)row * DD + t] = 0.f;
    xn[(size_t)row * DD + t + 256] = 0.f;
    return;
  }
  const float* x = h + (size_t)(row - PADR) * DD;
  __shared__ float red[256];
  float v0 = x[t], v1 = x[t + 256];
  red[t] = v0 + v1;
  __syncthreads();
  for (int s = 128; s > 0; s >>= 1) { if (t < s) red[t] += red[t + s]; __syncthreads(); }
  float mu = red[0] * (1.f / 512.f);
  __syncthreads();
  float d0 = v0 - mu, d1 = v1 - mu;
  red[t] = d0 * d0 + d1 * d1;
  __syncthreads();
  for (int s = 128; s > 0; s >>= 1) { if (t < s) red[t] += red[t + s]; __syncthreads(); }
  float rs = rsqrtf(red[0] * (1.f / 512.f) + 1e-5f);
  float* o = xn + (size_t)row * DD;
  o[t]       = d0 * rs * g[t] + b[t];
  o[t + 256] = d1 * rs * g[t + 256] + b[t + 256];
}

// ---------------- landmarks: ql/kl[i][c] = mean_j qkv[(i*64+j)][c(,+512)] ----------------
__global__ __launch_bounds__(256) void landmark_kernel(
    const float* __restrict__ qkv, float* __restrict__ ql, float* __restrict__ kl)
{
  int i = blockIdx.x;                 // landmark 0..255
  int c = blockIdx.y * 256 + threadIdx.x;   // 0..1023
  const float* p = qkv + (size_t)(i * 64) * 1536 + c;
  float s = 0.f;
  for (int j = 0; j < 64; ++j) s += p[(size_t)j * 1536];
  s *= (1.f / 64.f);
  if (c < 512) ql[(size_t)i * 512 + c] = s;
  else         kl[(size_t)i * 512 + (c - 512)] = s;
}

// ---------------- a2 = softmax(ql . kl^T) per head ----------------
__global__ __launch_bounds__(256) void a2_kernel(
    const float* __restrict__ ql, const float* __restrict__ kl, float* __restrict__ a2)
{
  int h_ = blockIdx.x, i = blockIdx.y;
  int t = threadIdx.x;
  __shared__ float q[64];
  __shared__ float red[256];
  if (t < 64) q[t] = ql[(size_t)i * 512 + h_ * 64 + t];
  __syncthreads();
  const float* kr = kl + (size_t)t * 512 + h_ * 64;
  float s = 0.f;
#pragma unroll
  for (int d = 0; d < 64; ++d) s = fmaf(q[d], kr[d], s);
  red[t] = s;
  __syncthreads();
  for (int st = 128; st > 0; st >>= 1) { if (t < st) red[t] = fmaxf(red[t], red[t + st]); __syncthreads(); }
  float mx = red[0];
  __syncthreads();
  float e = __expf(s - mx);
  red[t] = e;
  __syncthreads();
  for (int st = 128; st > 0; st >>= 1) { if (t < st) red[t] += red[t + st]; __syncthreads(); }
  a2[((size_t)h_ * 256 + i) * 256 + t] = e / red[0];
}

// ---------------- pinv init reductions ----------------
__global__ __launch_bounds__(256) void pinv_red1(const float* __restrict__ a2, float* __restrict__ red)
{
  int h_ = blockIdx.x, t = threadIdx.x;
  const float* X = a2 + (size_t)h_ * 65536;
  float rs = 0.f, cs = 0.f;
  for (int j = 0; j < 256; ++j) rs += fabsf(X[(size_t)t * 256 + j]);
  for (int i = 0; i < 256; ++i) cs += fabsf(X[(size_t)i * 256 + t]);
  __shared__ float r1[256], r2[256];
  r1[t] = rs; r2[t] = cs;
  __syncthreads();
  for (int s = 128; s > 0; s >>= 1) {
    if (t < s) { r1[t] = fmaxf(r1[t], r1[t + s]); r2[t] = fmaxf(r2[t], r2[t + s]); }
    __syncthreads();
  }
  if (t == 0) { red[h_ * 2] = r1[0]; red[h_ * 2 + 1] = r2[0]; }
}
__global__ void pinv_red2(float* __restrict__ red)
{
  float mr = 0.f, mc = 0.f;
  for (int h_ = 0; h_ < 8; ++h_) { mr = fmaxf(mr, red[h_ * 2]); mc = fmaxf(mc, red[h_ * 2 + 1]); }
  red[16] = 1.f / (mr * mc);
}
__global__ __launch_bounds__(256) void pinv_init(
    const float* __restrict__ a2, const float* __restrict__ red, float* __restrict__ z)
{
  int h_ = blockIdx.x, i = blockIdx.y, j = threadIdx.x;
  float inv = red[16];
  z[((size_t)h_ * 256 + i) * 256 + j] = a2[((size_t)h_ * 256 + j) * 256 + i] * inv;
}

// ---------------- y = alpha*x + beta*I (batched 8x256x256) ----------------
__global__ __launch_bounds__(256) void axpbi_kernel(
    const float* __restrict__ x, float* __restrict__ y, float alpha, float beta)
{
  int h_ = blockIdx.x, i = blockIdx.y, j = threadIdx.x;
  size_t idx = ((size_t)h_ * 256 + i) * 256 + j;
  y[idx] = alpha * x[idx] + ((i == j) ? beta : 0.f);
}

// ---------------- batched matmul per head: C = alpha*(A @ B), A 256x256, B 256xN ----------------
__global__ __launch_bounds__(256) void mmb_kernel(
    const float* __restrict__ A, const float* __restrict__ B, float* __restrict__ C,
    int N, float alpha)
{
  int h_ = blockIdx.z;
  const float* Ah = A + (size_t)h_ * 256 * 256;
  const float* Bh = B + (size_t)h_ * 256 * N;
  float* Ch = C + (size_t)h_ * 256 * N;
  int m0 = blockIdx.y * 64, n0 = blockIdx.x * 64;
  __shared__ float As[16][68];
  __shared__ float Bs[16][68];
  int tid = threadIdx.x, tx = tid & 15, ty = tid >> 4;
  float acc[4][4];
#pragma unroll
  for (int i = 0; i < 4; ++i)
#pragma unroll
    for (int j = 0; j < 4; ++j) acc[i][j] = 0.f;
  for (int k0 = 0; k0 < 256; k0 += 16) {
    {
      int row = tid >> 2, k4 = (tid & 3) << 2;
      float4 v = *(const float4*)(Ah + (size_t)(m0 + row) * 256 + k0 + k4);
      As[k4 + 0][row] = v.x; As[k4 + 1][row] = v.y;
      As[k4 + 2][row] = v.z; As[k4 + 3][row] = v.w;
    }
    {
      int row = tid >> 4, c4 = (tid & 15) << 2;
      *(float4*)&Bs[row][c4] = *(const float4*)(Bh + (size_t)(k0 + row) * N + n0 + c4);
    }
    __syncthreads();
#pragma unroll
    for (int k = 0; k < 16; ++k) {
      float a[4], b[4];
      *(float4*)a = *(const float4*)&As[k][ty * 4];
      *(float4*)b = *(const float4*)&Bs[k][tx * 4];
#pragma unroll
      for (int i = 0; i < 4; ++i)
#pragma unroll
        for (int j = 0; j < 4; ++j) acc[i][j] = fmaf(a[i], b[j], acc[i][j]);
    }
    __syncthreads();
  }
#pragma unroll
  for (int i = 0; i < 4; ++i) {
    float4 r;
    r.x = alpha * acc[i][0]; r.y = alpha * acc[i][1];
    r.z = alpha * acc[i][2]; r.w = alpha * acc[i][3];
    *(float4*)(Ch + (size_t)(m0 + ty * 4 + i) * N + n0 + tx * 4) = r;
  }
}

// ---------------- a3@v partial (flash, online softmax), grid (8 heads, 32 chunks) ----------------
__global__ __launch_bounds__(256) void a3v_part_kernel(
    const float* __restrict__ qkv, const float* __restrict__ ql,
    float* __restrict__ pacc, float* __restrict__ pms)
{
  int h_ = blockIdx.x;
  int ch = blockIdx.y;
  int t = threadIdx.x;          // landmark row
  float qr[64];
#pragma unroll
  for (int d4 = 0; d4 < 16; ++d4)
    *(float4*)&qr[d4 * 4] = *(const float4*)(ql + (size_t)t * 512 + h_ * 64 + d4 * 4);
  float m = -1e30f, s = 0.f;
  float acc[64];
#pragma unroll
  for (int d = 0; d < 64; ++d) acc[d] = 0.f;
  __shared__ float kt[64][64];
  __shared__ float vt[64][64];
  int jbase = ch * 512;
  for (int j0 = 0; j0 < 512; j0 += 64) {
    __syncthreads();
#pragma unroll
    for (int l = 0; l < 4; ++l) {
      int idx = t + l * 256;
      int r = idx >> 4, c4 = (idx & 15) << 2;
      const float* base = qkv + (size_t)(jbase + j0 + r) * 1536 + h_ * 64 + c4;
      *(float4*)&kt[r][c4] = *(const float4*)(base + 512);
      *(float4*)&vt[r][c4] = *(const float4*)(base + 1024);
    }
    __syncthreads();
    for (int j = 0; j < 64; ++j) {
      float sc = 0.f;
#pragma unroll
      for (int d4 = 0; d4 < 16; ++d4) {
        float4 kv = *(const float4*)&kt[j][d4 * 4];
        sc = fmaf(qr[d4*4+0], kv.x, sc); sc = fmaf(qr[d4*4+1], kv.y, sc);
        sc = fmaf(qr[d4*4+2], kv.z, sc); sc = fmaf(qr[d4*4+3], kv.w, sc);
      }
      if (sc <= m) {
        float p = __expf(sc - m);
        s += p;
#pragma unroll
        for (int d4 = 0; d4 < 16; ++d4) {
          float4 vv = *(const float4*)&vt[j][d4 * 4];
          acc[d4*4+0] = fmaf(p, vv.x, acc[d4*4+0]);
          acc[d4*4+1] = fmaf(p, vv.y, acc[d4*4+1]);
          acc[d4*4+2] = fmaf(p, vv.z, acc[d4*4+2]);
          acc[d4*4+3] = fmaf(p, vv.w, acc[d4*4+3]);
        }
      } else {
        float corr = __expf(m - sc);
        m = sc;
        s = fmaf(s, corr, 1.f);
#pragma unroll
        for (int d4 = 0; d4 < 16; ++d4) {
          float4 vv = *(const float4*)&vt[j][d4 * 4];
          acc[d4*4+0] = fmaf(acc[d4*4+0], corr, vv.x);
          acc[d4*4+1] = fmaf(acc[d4*4+1], corr, vv.y);
          acc[d4*4+2] = fmaf(acc[d4*4+2], corr, vv.z);
          acc[d4*4+3] = fmaf(acc[d4*4+3], corr, vv.w);
        }
      }
    }
  }
  size_t o = ((size_t)h_ * 32 + ch) * 256 + t;
  pms[o * 2] = m; pms[o * 2 + 1] = s;
#pragma unroll
  for (int d4 = 0; d4 < 16; ++d4) {
    float4 r; r.x = acc[d4*4+0]; r.y = acc[d4*4+1]; r.z = acc[d4*4+2]; r.w = acc[d4*4+3];
    *(float4*)(pacc + o * 64 + d4 * 4) = r;
  }
}

// ---------------- merge a3v partials (LSE combine over 32 chunks) ----------------
__global__ __launch_bounds__(64) void a3v_merge_kernel(
    const float* __restrict__ pacc, const float* __restrict__ pms, float* __restrict__ a3v)
{
  int h_ = blockIdx.x, i = blockIdx.y, d = threadIdx.x;
  float M = -1e30f;
  for (int c = 0; c < 32; ++c)
    M = fmaxf(M, pms[(((size_t)h_ * 32 + c) * 256 + i) * 2]);
  float S = 0.f, o = 0.f;
  for (int c = 0; c < 32; ++c) {
    size_t b = ((size_t)h_ * 32 + c) * 256 + i;
    float w = __expf(pms[b * 2] - M);
    S += pms[b * 2 + 1] * w;
    o += pacc[b * 64 + d] * w;
  }
  a3v[((size_t)h_ * 256 + i) * 64 + d] = o / S;
}

// ---------------- out = softmax(q . kl^T) @ w2, fused, grid (8, 64 row-blocks) ----------------
__global__ __launch_bounds__(256) void a1_kernel(
    const float* __restrict__ qkv, const float* __restrict__ kl,
    const float* __restrict__ w2, float* __restrict__ attn)
{
  int h_ = blockIdx.x;
  int r = blockIdx.y * 256 + threadIdx.x;
  int t = threadIdx.x;
  __shared__ float klt[128][64];
  __shared__ float wt[128][64];
  float qr[64];
#pragma unroll
  for (int d4 = 0; d4 < 16; ++d4)
    *(float4*)&qr[d4 * 4] = *(const float4*)(qkv + (size_t)r * 1536 + h_ * 64 + d4 * 4);
  float m = -1e30f, s = 0.f;
  float acc[64];
#pragma unroll
  for (int d = 0; d < 64; ++d) acc[d] = 0.f;
  for (int jh = 0; jh < 2; ++jh) {
    __syncthreads();
#pragma unroll
    for (int l = 0; l < 8; ++l) {
      int idx = t + l * 256;
      int rr = idx >> 4, c4 = (idx & 15) << 2;
      *(float4*)&klt[rr][c4] = *(const float4*)(kl + (size_t)(jh * 128 + rr) * 512 + h_ * 64 + c4);
      *(float4*)&wt[rr][c4]  = *(const float4*)(w2 + ((size_t)h_ * 256 + jh * 128 + rr) * 64 + c4);
    }
    __syncthreads();
    for (int j = 0; j < 128; ++j) {
      float sc = 0.f;
#pragma unroll
      for (int d4 = 0; d4 < 16; ++d4) {
        float4 kv = *(const float4*)&klt[j][d4 * 4];
        sc = fmaf(qr[d4*4+0], kv.x, sc); sc = fmaf(qr[d4*4+1], kv.y, sc);
        sc = fmaf(qr[d4*4+2], kv.z, sc); sc = fmaf(qr[d4*4+3], kv.w, sc);
      }
      if (sc <= m) {
        float p = __expf(sc - m);
        s += p;
#pragma unroll
        for (int d4 = 0; d4 < 16; ++d4) {
          float4 vv = *(const float4*)&wt[j][d4 * 4];
          acc[d4*4+0] = fmaf(p, vv.x, acc[d4*4+0]);
          acc[d4*4+1] = fmaf(p, vv.y, acc[d4*4+1]);
          acc[d4*4+2] = fmaf(p, vv.z, acc[d4*4+2]);
          acc[d4*4+3] = fmaf(p, vv.w, acc[d4*4+3]);
        }
      } else {
        float corr = __expf(m - sc);
        m = sc;
        s = fmaf(s, corr, 1.f);
#pragma unroll
        for (int d4 = 0; d4 < 16; ++d4) {
          float4 vv = *(const float4*)&wt[j][d4 * 4];
          acc[d4*4+0] = fmaf(acc[d4*4+0], corr, vv.x);
          acc[d4*4+1] = fmaf(acc[d4*4+1], corr, vv.y);
          acc[d4*4+2] = fmaf(acc[d4*4+2], corr, vv.z);
          acc[d4*4+3] = fmaf(acc[d4*4+3], corr, vv.w);
        }
      }
    }
  }
  float inv = 1.f / s;
  float* op = attn + (size_t)r * 512 + h_ * 64;
#pragma unroll
  for (int d4 = 0; d4 < 16; ++d4) {
    float4 o;
    o.x = acc[d4*4+0] * inv; o.y = acc[d4*4+1] * inv;
    o.z = acc[d4*4+2] * inv; o.w = acc[d4*4+3] * inv;
    *(float4*)(op + d4 * 4) = o;
  }
}

// ---------------- depthwise res conv over sequence (kernel 33), adds into attn ----------------
__global__ __launch_bounds__(256) void resconv_kernel(
    const float* __restrict__ qkv, const float* __restrict__ rw, float* __restrict__ attn)
{
  int r = blockIdx.x;
  int c = blockIdx.y * 256 + threadIdx.x;
  int h_ = c >> 6;
  float s = 0.f;
#pragma unroll
  for (int tp = 0; tp < 33; ++tp) {
    int rr = r + tp - 16;
    if (rr >= 0 && rr < NPAD)
      s = fmaf(qkv[(size_t)rr * 1536 + 1024 + c], rw[h_ * 33 + tp], s);
  }
  attn[(size_t)r * 512 + c] += s;
}

// ---------------- PPEG depthwise 7/5/3 convs on 127x127 image + identity + biases ----------------
__global__ __launch_bounds__(256) void ppeg_kernel(
    const float* __restrict__ h, float* __restrict__ tmp,
    const float* __restrict__ w7, const float* __restrict__ b7,
    const float* __restrict__ w5, const float* __restrict__ b5,
    const float* __restrict__ w3, const float* __restrict__ b3)
{
  int p = blockIdx.x;
  int y = p / SG, x = p % SG;
  int t = threadIdx.x;
#pragma unroll
  for (int half = 0; half < 2; ++half) {
    int c = half * 256 + t;
    float acc = h[(size_t)(1 + p) * DD + c] + b7[c] + b5[c] + b3[c];
    for (int ky = 0; ky < 7; ++ky) {
      int yy = y + ky - 3;
      if (yy < 0 || yy >= SG) continue;
      for (int kx = 0; kx < 7; ++kx) {
        int xx = x + kx - 3;
        if (xx < 0 || xx >= SG) continue;
        acc = fmaf(h[(size_t)(1 + yy * SG + xx) * DD + c], w7[c * 49 + ky * 7 + kx], acc);
      }
    }
    for (int ky = 0; ky < 5; ++ky) {
      int yy = y + ky - 2;
      if (yy < 0 || yy >= SG) continue;
      for (int kx = 0; kx < 5; ++kx) {
        int xx = x + kx - 2;
        if (xx < 0 || xx >= SG) continue;
        acc = fmaf(h[(size_t)(1 + yy * SG + xx) * DD + c], w5[c * 25 + ky * 5 + kx], acc);
      }
    }
    for (int ky = 0; ky < 3; ++ky) {
      int yy = y + ky - 1;
      if (yy < 0 || yy >= SG) continue;
      for (int kx = 0; kx < 3; ++kx) {
        int xx = x + kx - 1;
        if (xx < 0 || xx >= SG) continue;
        acc = fmaf(h[(size_t)(1 + yy * SG + xx) * DD + c], w3[c * 9 + ky * 3 + kx], acc);
      }
    }
    tmp[(size_t)p * DD + c] = acc;
  }
}

// ---------------- final: LN(row0) -> fc2 -> softmax/argmax -> 5 outputs ----------------
__global__ __launch_bounds__(256) void final_kernel(
    const float* __restrict__ h, const float* __restrict__ g, const float* __restrict__ b,
    const float* __restrict__ w, const float* __restrict__ bias, float* __restrict__ out)
{
  __shared__ float red[256];
  int t = threadIdx.x;
  float v0 = h[t], v1 = h[t + 256];
  red[t] = v0 + v1;
  __syncthreads();
  for (int s = 128; s > 0; s >>= 1) { if (t < s) red[t] += red[t + s]; __syncthreads(); }
  float mu = red[0] * (1.f / 512.f);
  __syncthreads();
  float d0 = v0 - mu, d1 = v1 - mu;
  red[t] = d0 * d0 + d1 * d1;
  __syncthreads();
  for (int s = 128; s > 0; s >>= 1) { if (t < s) red[t] += red[t + s]; __syncthreads(); }
  float rs = rsqrtf(red[0] * (1.f / 512.f) + 1e-5f);
  __syncthreads();
  float x0 = d0 * rs * g[t] + b[t];
  float x1 = d1 * rs * g[t + 256] + b[t + 256];
  red[t] = x0 * w[t * 2] + x1 * w[(t + 256) * 2];
  __syncthreads();
  for (int s = 128; s > 0; s >>= 1) { if (t < s) red[t] += red[t + s]; __syncthreads(); }
  float l0 = red[0] + bias[0];
  __syncthreads();
  red[t] = x0 * w[t * 2 + 1] + x1 * w[(t + 256) * 2 + 1];
  __syncthreads();
  for (int s = 128; s > 0; s >>= 1) { if (t < s) red[t] += red[t + s]; __syncthreads(); }
  float l1 = red[0] + bias[1];
  if (t == 0) {
    out[0] = l0; out[1] = l1;
    float mx = fmaxf(l0, l1);
    float e0 = __expf(l0 - mx), e1 = __expf(l1 - mx);
    float inv = 1.f / (e0 + e1);
    out[2] = e0 * inv; out[3] = e1 * inv;
    out[4] = (l1 > l0) ? 1.f : 0.f;
  }
}

extern "C" void kernel_launch(void* const* d_in, const int* in_sizes, int n_in,
                              void* d_out, int out_size, void* d_ws, size_t ws_size,
                              hipStream_t stream)
{
  const float* data   = (const float*)d_in[0];
  const float* fc1_w  = (const float*)d_in[1];
  const float* fc1_b  = (const float*)d_in[2];
  const float* cls    = (const float*)d_in[3];
  const float* l1_g   = (const float*)d_in[4];
  const float* l1_b   = (const float*)d_in[5];
  const float* l1_qkv = (const float*)d_in[6];
  const float* l1_ow  = (const float*)d_in[7];
  const float* l1_ob  = (const float*)d_in[8];
  const float* l1_rw  = (const float*)d_in[9];
  const float* w7     = (const float*)d_in[10];
  const float* b7     = (const float*)d_in[11];
  const float* w5     = (const float*)d_in[12];
  const float* b5     = (const float*)d_in[13];
  const float* w3     = (const float*)d_in[14];
  const float* b3     = (const float*)d_in[15];
  const float* l2_g   = (const float*)d_in[16];
  const float* l2_b   = (const float*)d_in[17];
  const float* l2_qkv = (const float*)d_in[18];
  const float* l2_ow  = (const float*)d_in[19];
  const float* l2_ob  = (const float*)d_in[20];
  const float* l2_rw  = (const float*)d_in[21];
  const float* ng     = (const float*)d_in[22];
  const float* nb     = (const float*)d_in[23];
  const float* fc2_w  = (const float*)d_in[24];
  const float* fc2_b  = (const float*)d_in[25];
  float* out = (float*)d_out;

  float* ws   = (float*)d_ws;
  float* h    = ws;
  float* xn   = h    + (size_t)16384 * 512;
  float* qkv  = xn   + (size_t)16384 * 512;
  float* attn = qkv  + (size_t)16384 * 1536;
  float* ql   = attn + (size_t)16384 * 512;
  float* kl   = ql   + 256 * 512;
  float* a2b  = kl   + 256 * 512;
  float* z0   = a2b  + 8 * 256 * 256;
  float* z1   = z0   + 8 * 256 * 256;
  float* xzb  = z1   + 8 * 256 * 256;
  float* tb   = xzb  + 8 * 256 * 256;
  float* ub   = tb   + 8 * 256 * 256;
  float* a3v  = ub   + 8 * 256 * 256;
  float* w2   = a3v  + 8 * 256 * 64;
  float* pacc = w2   + 8 * 256 * 64;
  float* pms  = pacc + (size_t)8 * 32 * 256 * 64;
  float* red  = pms  + (size_t)8 * 32 * 256 * 2;

  // fc1 + relu into h rows 1..16000, then cls + duplicated rows
  gemm128<<<dim3(4, 125), 256, 0, stream>>>(data, 1024, fc1_w, 512, h + 512, 512,
                                            16000, 1024, 1, fc1_b);
  assemble_kernel<<<260, 256, 0, stream>>>(h, cls);

  for (int layer = 0; layer < 2; ++layer) {
    const float* gg = layer ? l2_g   : l1_g;
    const float* bb = layer ? l2_b   : l1_b;
    const float* qw = layer ? l2_qkv : l1_qkv;
    const float* ow = layer ? l2_ow  : l1_ow;
    const float* ob = layer ? l2_ob  : l1_ob;
    const float* rw = layer ? l2_rw  : l1_rw;

    ln_pad_kernel<<<16384, 256, 0, stream>>>(h, xn, gg, bb);
    gemm128<<<dim3(12, 128), 256, 0, stream>>>(xn, 512, qw, 1536, qkv, 1536,
                                               16384, 512, 2, nullptr);
    landmark_kernel<<<dim3(256, 4), 256, 0, stream>>>(qkv, ql, kl);
    a2_kernel<<<dim3(8, 256), 256, 0, stream>>>(ql, kl, a2b);
    pinv_red1<<<8, 256, 0, stream>>>(a2b, red);
    pinv_red2<<<1, 1, 0, stream>>>(red);
    pinv_init<<<dim3(8, 256), 256, 0, stream>>>(a2b, red, z0);
    float* zc = z0; float* zn = z1;
    for (int it = 0; it < 6; ++it) {
      mmb_kernel<<<dim3(4, 4, 8), 256, 0, stream>>>(a2b, zc, xzb, 256, 1.f);
      axpbi_kernel<<<dim3(8, 256), 256, 0, stream>>>(xzb, tb, -1.f, 7.f);
      mmb_kernel<<<dim3(4, 4, 8), 256, 0, stream>>>(xzb, tb, ub, 256, 1.f);
      axpbi_kernel<<<dim3(8, 256), 256, 0, stream>>>(ub, tb, -1.f, 15.f);
      mmb_kernel<<<dim3(4, 4, 8), 256, 0, stream>>>(xzb, tb, ub, 256, 1.f);
      axpbi_kernel<<<dim3(8, 256), 256, 0, stream>>>(ub, tb, -1.f, 13.f);
      mmb_kernel<<<dim3(4, 4, 8), 256, 0, stream>>>(zc, tb, zn, 256, 0.25f);
      float* sw = zc; zc = zn; zn = sw;
    }
    a3v_part_kernel<<<dim3(8, 32), 256, 0, stream>>>(qkv, ql, pacc, pms);
    a3v_merge_kernel<<<dim3(8, 256), 64, 0, stream>>>(pacc, pms, a3v);
    mmb_kernel<<<dim3(1, 4, 8), 256, 0, stream>>>(zc, a3v, w2, 64, 1.f);
    a1_kernel<<<dim3(8, 64), 256, 0, stream>>>(qkv, kl, w2, attn);
    resconv_kernel<<<dim3(16384, 2), 256, 0, stream>>>(qkv, rw, attn);
    gemm128<<<dim3(4, 127), 256, 0, stream>>>(attn + (size_t)254 * 512, 512, ow, 512,
                                              h, 512, 16130, 512, 3, ob);
    if (layer == 0) {
      ppeg_kernel<<<16129, 256, 0, stream>>>(h, qkv, w7, b7, w5, b5, w3, b3);
      hipMemcpyAsync(h + 512, qkv, (size_t)16129 * 512 * 4,
                     hipMemcpyDeviceToDevice, stream);
    }
  }
  final_kernel<<<1, 256, 0, stream>>>(h, ng, nb, fc2_w, fc2_b, out);
}

// Round 2
// 4430.915 us; speedup vs baseline: 1.3144x; 1.3144x over previous
//
#include <hip/hip_runtime.h>
#include <math.h>

#define NPAD   16384
#define PADR   254
#define NTOK   16130
#define NPIX   16129
#define SG     127
#define DD     512
#define NH     8

// ---------------- fp32 GEMM, 128x128 tile, 256 threads, 8x8/thread ----------------
// mode 0: C = acc ; mode 1: C = relu(acc+bias) ; mode 2: C = acc*(col<512?0.125:1)
// mode 3: C += acc + bias
__global__ __launch_bounds__(256) void gemm128(
    const float* __restrict__ A, int lda,
    const float* __restrict__ B, int ldb,
    float* __restrict__ C, int ldc,
    int M, int K, int mode, const float* __restrict__ bias)
{
  __shared__ float As[16][132];
  __shared__ float Bs[16][132];
  const int tid = threadIdx.x;
  const int tx = tid & 15, ty = tid >> 4;
  const int m0 = blockIdx.y * 128;
  const int n0 = blockIdx.x * 128;
  float acc[8][8];
#pragma unroll
  for (int i = 0; i < 8; ++i)
#pragma unroll
    for (int j = 0; j < 8; ++j) acc[i][j] = 0.f;

  for (int k0 = 0; k0 < K; k0 += 16) {
#pragma unroll
    for (int l = 0; l < 2; ++l) {
      int idx = tid + l * 256;
      int row = idx >> 2;
      int k4  = (idx & 3) << 2;
      float4 v = make_float4(0.f, 0.f, 0.f, 0.f);
      int gr = m0 + row;
      if (gr < M) v = *(const float4*)(A + (size_t)gr * lda + k0 + k4);
      As[k4 + 0][row] = v.x;
      As[k4 + 1][row] = v.y;
      As[k4 + 2][row] = v.z;
      As[k4 + 3][row] = v.w;
    }
#pragma unroll
    for (int l = 0; l < 2; ++l) {
      int idx = tid + l * 256;
      int row = idx >> 5;
      int c4  = (idx & 31) << 2;
      *(float4*)&Bs[row][c4] = *(const float4*)(B + (size_t)(k0 + row) * ldb + n0 + c4);
    }
    __syncthreads();
#pragma unroll
    for (int k = 0; k < 16; ++k) {
      float a[8], b[8];
      *(float4*)&a[0] = *(const float4*)&As[k][ty * 4];
      *(float4*)&a[4] = *(const float4*)&As[k][64 + ty * 4];
      *(float4*)&b[0] = *(const float4*)&Bs[k][tx * 4];
      *(float4*)&b[4] = *(const float4*)&Bs[k][64 + tx * 4];
#pragma unroll
      for (int i = 0; i < 8; ++i)
#pragma unroll
        for (int j = 0; j < 8; ++j) acc[i][j] = fmaf(a[i], b[j], acc[i][j]);
    }
    __syncthreads();
  }
#pragma unroll
  for (int i = 0; i < 8; ++i) {
    int rloc = (i < 4) ? (ty * 4 + i) : (64 + ty * 4 + (i - 4));
    int row = m0 + rloc;
    if (row >= M) continue;
#pragma unroll
    for (int jh = 0; jh < 2; ++jh) {
      int col = n0 + jh * 64 + tx * 4;
      float* cp = C + (size_t)row * ldc + col;
      float4 r;
      r.x = acc[i][jh*4+0]; r.y = acc[i][jh*4+1];
      r.z = acc[i][jh*4+2]; r.w = acc[i][jh*4+3];
      if (mode == 1) {
        float4 bb = *(const float4*)(bias + col);
        r.x = fmaxf(r.x + bb.x, 0.f); r.y = fmaxf(r.y + bb.y, 0.f);
        r.z = fmaxf(r.z + bb.z, 0.f); r.w = fmaxf(r.w + bb.w, 0.f);
      } else if (mode == 2) {
        float s = (col < 512) ? 0.125f : 1.f;
        r.x *= s; r.y *= s; r.z *= s; r.w *= s;
      } else if (mode == 3) {
        float4 bb = *(const float4*)(bias + col);
        float4 o  = *(const float4*)cp;
        r.x += o.x + bb.x; r.y += o.y + bb.y;
        r.z += o.z + bb.z; r.w += o.w + bb.w;
      }
      *(float4*)cp = r;
    }
  }
}

// ---------------- assemble: h[0]=cls, h[16001+i]=h[1+i] (i<129) ----------------
__global__ __launch_bounds__(256) void assemble_kernel(float* __restrict__ h,
                                                       const float* __restrict__ cls)
{
  int idx = blockIdx.x * 256 + threadIdx.x;   // 260*256 = 66560 = 512 + 129*512
  if (idx < 512) { h[idx] = cls[idx]; return; }
  idx -= 512;
  int i = idx >> 9, c = idx & 511;
  h[(size_t)(16001 + i) * DD + c] = h[(size_t)(1 + i) * DD + c];
}

// ---------------- LayerNorm rows of h -> xn (front-padded, rows<PADR zeroed) ----------------
__global__ __launch_bounds__(256) void ln_pad_kernel(
    const float* __restrict__ h, float* __restrict__ xn,
    const float* __restrict__ g, const float* __restrict__ b)
{
  int row = blockIdx.x;        // 0..16383
  int t = threadIdx.x;
  if (row < PADR) {
    xn[(size_t)row * DD + t] = 0.f;
    xn[(size_t)row * DD + t + 256] = 0.f;
    return;
  }
  const float* x = h + (size_t)(row - PADR) * DD;
  __shared__ float red[256];
  float v0 = x[t], v1 = x[t + 256];
  red[t] = v0 + v1;
  __syncthreads();
  for (int s = 128; s > 0; s >>= 1) { if (t < s) red[t] += red[t + s]; __syncthreads(); }
  float mu = red[0] * (1.f / 512.f);
  __syncthreads();
  float d0 = v0 - mu, d1 = v1 - mu;
  red[t] = d0 * d0 + d1 * d1;
  __syncthreads();
  for (int s = 128; s > 0; s >>= 1) { if (t < s) red[t] += red[t + s]; __syncthreads(); }
  float rs = rsqrtf(red[0] * (1.f / 512.f) + 1e-5f);
  float* o = xn + (size_t)row * DD;
  o[t]       = d0 * rs * g[t] + b[t];
  o[t + 256] = d1 * rs * g[t + 256] + b[t + 256];
}

// ---------------- landmarks: ql/kl[i][c] = mean_j qkv[(i*64+j)][c(,+512)] ----------------
__global__ __launch_bounds__(256) void landmark_kernel(
    const float* __restrict__ qkv, float* __restrict__ ql, float* __restrict__ kl)
{
  int i = blockIdx.x;                 // landmark 0..255
  int c = blockIdx.y * 256 + threadIdx.x;   // 0..1023
  const float* p = qkv + (size_t)(i * 64) * 1536 + c;
  float s = 0.f;
  for (int j = 0; j < 64; ++j) s += p[(size_t)j * 1536];
  s *= (1.f / 64.f);
  if (c < 512) ql[(size_t)i * 512 + c] = s;
  else         kl[(size_t)i * 512 + (c - 512)] = s;
}

// ---------------- a2 = softmax(ql . kl^T) per head ----------------
__global__ __launch_bounds__(256) void a2_kernel(
    const float* __restrict__ ql, const float* __restrict__ kl, float* __restrict__ a2)
{
  int h_ = blockIdx.x, i = blockIdx.y;
  int t = threadIdx.x;
  __shared__ float q[64];
  __shared__ float red[256];
  if (t < 64) q[t] = ql[(size_t)i * 512 + h_ * 64 + t];
  __syncthreads();
  const float* kr = kl + (size_t)t * 512 + h_ * 64;
  float s = 0.f;
#pragma unroll
  for (int d = 0; d < 64; ++d) s = fmaf(q[d], kr[d], s);
  red[t] = s;
  __syncthreads();
  for (int st = 128; st > 0; st >>= 1) { if (t < st) red[t] = fmaxf(red[t], red[t + st]); __syncthreads(); }
  float mx = red[0];
  __syncthreads();
  float e = __expf(s - mx);
  red[t] = e;
  __syncthreads();
  for (int st = 128; st > 0; st >>= 1) { if (t < st) red[t] += red[t + st]; __syncthreads(); }
  a2[((size_t)h_ * 256 + i) * 256 + t] = e / red[0];
}

// ---------------- pinv init reductions ----------------
__global__ __launch_bounds__(256) void pinv_red1(const float* __restrict__ a2, float* __restrict__ red)
{
  int h_ = blockIdx.x, t = threadIdx.x;
  const float* X = a2 + (size_t)h_ * 65536;
  float rs = 0.f, cs = 0.f;
  for (int j = 0; j < 256; ++j) rs += fabsf(X[(size_t)t * 256 + j]);
  for (int i = 0; i < 256; ++i) cs += fabsf(X[(size_t)i * 256 + t]);
  __shared__ float r1[256], r2[256];
  r1[t] = rs; r2[t] = cs;
  __syncthreads();
  for (int s = 128; s > 0; s >>= 1) {
    if (t < s) { r1[t] = fmaxf(r1[t], r1[t + s]); r2[t] = fmaxf(r2[t], r2[t + s]); }
    __syncthreads();
  }
  if (t == 0) { red[h_ * 2] = r1[0]; red[h_ * 2 + 1] = r2[0]; }
}
__global__ void pinv_red2(float* __restrict__ red)
{
  float mr = 0.f, mc = 0.f;
  for (int h_ = 0; h_ < 8; ++h_) { mr = fmaxf(mr, red[h_ * 2]); mc = fmaxf(mc, red[h_ * 2 + 1]); }
  red[16] = 1.f / (mr * mc);
}
__global__ __launch_bounds__(256) void pinv_init(
    const float* __restrict__ a2, const float* __restrict__ red, float* __restrict__ z)
{
  int h_ = blockIdx.x, i = blockIdx.y, j = threadIdx.x;
  float inv = red[16];
  z[((size_t)h_ * 256 + i) * 256 + j] = a2[((size_t)h_ * 256 + j) * 256 + i] * inv;
}

// ---------------- y = alpha*x + beta*I (batched 8x256x256) ----------------
__global__ __launch_bounds__(256) void axpbi_kernel(
    const float* __restrict__ x, float* __restrict__ y, float alpha, float beta)
{
  int h_ = blockIdx.x, i = blockIdx.y, j = threadIdx.x;
  size_t idx = ((size_t)h_ * 256 + i) * 256 + j;
  y[idx] = alpha * x[idx] + ((i == j) ? beta : 0.f);
}

// ---------------- batched matmul per head: C = alpha*(A @ B), A 256x256, B 256xN ----------------
__global__ __launch_bounds__(256) void mmb_kernel(
    const float* __restrict__ A, const float* __restrict__ B, float* __restrict__ C,
    int N, float alpha)
{
  int h_ = blockIdx.z;
  const float* Ah = A + (size_t)h_ * 256 * 256;
  const float* Bh = B + (size_t)h_ * 256 * N;
  float* Ch = C + (size_t)h_ * 256 * N;
  int m0 = blockIdx.y * 64, n0 = blockIdx.x * 64;
  __shared__ float As[16][68];
  __shared__ float Bs[16][68];
  int tid = threadIdx.x, tx = tid & 15, ty = tid >> 4;
  float acc[4][4];
#pragma unroll
  for (int i = 0; i < 4; ++i)
#pragma unroll
    for (int j = 0; j < 4; ++j) acc[i][j] = 0.f;
  for (int k0 = 0; k0 < 256; k0 += 16) {
    {
      int row = tid >> 2, k4 = (tid & 3) << 2;
      float4 v = *(const float4*)(Ah + (size_t)(m0 + row) * 256 + k0 + k4);
      As[k4 + 0][row] = v.x; As[k4 + 1][row] = v.y;
      As[k4 + 2][row] = v.z; As[k4 + 3][row] = v.w;
    }
    {
      int row = tid >> 4, c4 = (tid & 15) << 2;
      *(float4*)&Bs[row][c4] = *(const float4*)(Bh + (size_t)(k0 + row) * N + n0 + c4);
    }
    __syncthreads();
#pragma unroll
    for (int k = 0; k < 16; ++k) {
      float a[4], b[4];
      *(float4*)a = *(const float4*)&As[k][ty * 4];
      *(float4*)b = *(const float4*)&Bs[k][tx * 4];
#pragma unroll
      for (int i = 0; i < 4; ++i)
#pragma unroll
        for (int j = 0; j < 4; ++j) acc[i][j] = fmaf(a[i], b[j], acc[i][j]);
    }
    __syncthreads();
  }
#pragma unroll
  for (int i = 0; i < 4; ++i) {
    float4 r;
    r.x = alpha * acc[i][0]; r.y = alpha * acc[i][1];
    r.z = alpha * acc[i][2]; r.w = alpha * acc[i][3];
    *(float4*)(Ch + (size_t)(m0 + ty * 4 + i) * N + n0 + tx * 4) = r;
  }
}

// ---------------- a3@v partial (flash, online softmax), grid (8 heads, 32 chunks) ----------------
__global__ __launch_bounds__(256) void a3v_part_kernel(
    const float* __restrict__ qkv, const float* __restrict__ ql,
    float* __restrict__ pacc, float* __restrict__ pms)
{
  int h_ = blockIdx.x;
  int ch = blockIdx.y;
  int t = threadIdx.x;          // landmark row
  float qr[64];
#pragma unroll
  for (int d4 = 0; d4 < 16; ++d4)
    *(float4*)&qr[d4 * 4] = *(const float4*)(ql + (size_t)t * 512 + h_ * 64 + d4 * 4);
  float m = -1e30f, s = 0.f;
  float acc[64];
#pragma unroll
  for (int d = 0; d < 64; ++d) acc[d] = 0.f;
  __shared__ float kt[64][64];
  __shared__ float vt[64][64];
  int jbase = ch * 512;
  for (int j0 = 0; j0 < 512; j0 += 64) {
    __syncthreads();
#pragma unroll
    for (int l = 0; l < 4; ++l) {
      int idx = t + l * 256;
      int r = idx >> 4, c4 = (idx & 15) << 2;
      const float* base = qkv + (size_t)(jbase + j0 + r) * 1536 + h_ * 64 + c4;
      *(float4*)&kt[r][c4] = *(const float4*)(base + 512);
      *(float4*)&vt[r][c4] = *(const float4*)(base + 1024);
    }
    __syncthreads();
    for (int j = 0; j < 64; ++j) {
      float sc = 0.f;
#pragma unroll
      for (int d4 = 0; d4 < 16; ++d4) {
        float4 kv = *(const float4*)&kt[j][d4 * 4];
        sc = fmaf(qr[d4*4+0], kv.x, sc); sc = fmaf(qr[d4*4+1], kv.y, sc);
        sc = fmaf(qr[d4*4+2], kv.z, sc); sc = fmaf(qr[d4*4+3], kv.w, sc);
      }
      if (sc <= m) {
        float p = __expf(sc - m);
        s += p;
#pragma unroll
        for (int d4 = 0; d4 < 16; ++d4) {
          float4 vv = *(const float4*)&vt[j][d4 * 4];
          acc[d4*4+0] = fmaf(p, vv.x, acc[d4*4+0]);
          acc[d4*4+1] = fmaf(p, vv.y, acc[d4*4+1]);
          acc[d4*4+2] = fmaf(p, vv.z, acc[d4*4+2]);
          acc[d4*4+3] = fmaf(p, vv.w, acc[d4*4+3]);
        }
      } else {
        float corr = __expf(m - sc);
        m = sc;
        s = fmaf(s, corr, 1.f);
#pragma unroll
        for (int d4 = 0; d4 < 16; ++d4) {
          float4 vv = *(const float4*)&vt[j][d4 * 4];
          acc[d4*4+0] = fmaf(acc[d4*4+0], corr, vv.x);
          acc[d4*4+1] = fmaf(acc[d4*4+1], corr, vv.y);
          acc[d4*4+2] = fmaf(acc[d4*4+2], corr, vv.z);
          acc[d4*4+3] = fmaf(acc[d4*4+3], corr, vv.w);
        }
      }
    }
  }
  size_t o = ((size_t)h_ * 32 + ch) * 256 + t;
  pms[o * 2] = m; pms[o * 2 + 1] = s;
#pragma unroll
  for (int d4 = 0; d4 < 16; ++d4) {
    float4 r; r.x = acc[d4*4+0]; r.y = acc[d4*4+1]; r.z = acc[d4*4+2]; r.w = acc[d4*4+3];
    *(float4*)(pacc + o * 64 + d4 * 4) = r;
  }
}

// ---------------- merge a3v partials (LSE combine over 32 chunks) ----------------
__global__ __launch_bounds__(64) void a3v_merge_kernel(
    const float* __restrict__ pacc, const float* __restrict__ pms, float* __restrict__ a3v)
{
  int h_ = blockIdx.x, i = blockIdx.y, d = threadIdx.x;
  float M = -1e30f;
  for (int c = 0; c < 32; ++c)
    M = fmaxf(M, pms[(((size_t)h_ * 32 + c) * 256 + i) * 2]);
  float S = 0.f, o = 0.f;
  for (int c = 0; c < 32; ++c) {
    size_t b = ((size_t)h_ * 32 + c) * 256 + i;
    float w = __expf(pms[b * 2] - M);
    S += pms[b * 2 + 1] * w;
    o += pacc[b * 64 + d] * w;
  }
  a3v[((size_t)h_ * 256 + i) * 64 + d] = o / S;
}

// ---------------- out = softmax(q . kl^T) @ w2, fused, grid (8, 64 row-blocks) ----------------
__global__ __launch_bounds__(256) void a1_kernel(
    const float* __restrict__ qkv, const float* __restrict__ kl,
    const float* __restrict__ w2, float* __restrict__ attn)
{
  int h_ = blockIdx.x;
  int r = blockIdx.y * 256 + threadIdx.x;
  int t = threadIdx.x;
  __shared__ float klt[128][64];
  __shared__ float wt[128][64];
  float qr[64];
#pragma unroll
  for (int d4 = 0; d4 < 16; ++d4)
    *(float4*)&qr[d4 * 4] = *(const float4*)(qkv + (size_t)r * 1536 + h_ * 64 + d4 * 4);
  float m = -1e30f, s = 0.f;
  float acc[64];
#pragma unroll
  for (int d = 0; d < 64; ++d) acc[d] = 0.f;
  for (int jh = 0; jh < 2; ++jh) {
    __syncthreads();
#pragma unroll
    for (int l = 0; l < 8; ++l) {
      int idx = t + l * 256;
      int rr = idx >> 4, c4 = (idx & 15) << 2;
      *(float4*)&klt[rr][c4] = *(const float4*)(kl + (size_t)(jh * 128 + rr) * 512 + h_ * 64 + c4);
      *(float4*)&wt[rr][c4]  = *(const float4*)(w2 + ((size_t)h_ * 256 + jh * 128 + rr) * 64 + c4);
    }
    __syncthreads();
    for (int j = 0; j < 128; ++j) {
      float sc = 0.f;
#pragma unroll
      for (int d4 = 0; d4 < 16; ++d4) {
        float4 kv = *(const float4*)&klt[j][d4 * 4];
        sc = fmaf(qr[d4*4+0], kv.x, sc); sc = fmaf(qr[d4*4+1], kv.y, sc);
        sc = fmaf(qr[d4*4+2], kv.z, sc); sc = fmaf(qr[d4*4+3], kv.w, sc);
      }
      if (sc <= m) {
        float p = __expf(sc - m);
        s += p;
#pragma unroll
        for (int d4 = 0; d4 < 16; ++d4) {
          float4 vv = *(const float4*)&wt[j][d4 * 4];
          acc[d4*4+0] = fmaf(p, vv.x, acc[d4*4+0]);
          acc[d4*4+1] = fmaf(p, vv.y, acc[d4*4+1]);
          acc[d4*4+2] = fmaf(p, vv.z, acc[d4*4+2]);
          acc[d4*4+3] = fmaf(p, vv.w, acc[d4*4+3]);
        }
      } else {
        float corr = __expf(m - sc);
        m = sc;
        s = fmaf(s, corr, 1.f);
#pragma unroll
        for (int d4 = 0; d4 < 16; ++d4) {
          float4 vv = *(const float4*)&wt[j][d4 * 4];
          acc[d4*4+0] = fmaf(acc[d4*4+0], corr, vv.x);
          acc[d4*4+1] = fmaf(acc[d4*4+1], corr, vv.y);
          acc[d4*4+2] = fmaf(acc[d4*4+2], corr, vv.z);
          acc[d4*4+3] = fmaf(acc[d4*4+3], corr, vv.w);
        }
      }
    }
  }
  float inv = 1.f / s;
  float* op = attn + (size_t)r * 512 + h_ * 64;
#pragma unroll
  for (int d4 = 0; d4 < 16; ++d4) {
    float4 o;
    o.x = acc[d4*4+0] * inv; o.y = acc[d4*4+1] * inv;
    o.z = acc[d4*4+2] * inv; o.w = acc[d4*4+3] * inv;
    *(float4*)(op + d4 * 4) = o;
  }
}

// ---------------- depthwise res conv over sequence (kernel 33), adds into attn ----------------
__global__ __launch_bounds__(256) void resconv_kernel(
    const float* __restrict__ qkv, const float* __restrict__ rw, float* __restrict__ attn)
{
  int r = blockIdx.x;
  int c = blockIdx.y * 256 + threadIdx.x;
  int h_ = c >> 6;
  float s = 0.f;
#pragma unroll
  for (int tp = 0; tp < 33; ++tp) {
    int rr = r + tp - 16;
    if (rr >= 0 && rr < NPAD)
      s = fmaf(qkv[(size_t)rr * 1536 + 1024 + c], rw[h_ * 33 + tp], s);
  }
  attn[(size_t)r * 512 + c] += s;
}

// ---------------- PPEG: 1 thread = 1 channel, weights in registers, 64-pixel loop ----------------
// grid (ceil(NPIX/64), 2); block 256. Branches are wave-uniform (pixel idx uniform
// per iteration); tap loops fully unrolled so weight-register indexing is static.
__global__ __launch_bounds__(256) void ppeg_kernel(
    const float* __restrict__ h, float* __restrict__ tmp,
    const float* __restrict__ w7, const float* __restrict__ b7,
    const float* __restrict__ w5, const float* __restrict__ b5,
    const float* __restrict__ w3, const float* __restrict__ b3)
{
  const int c = blockIdx.y * 256 + threadIdx.x;
  const int p0 = blockIdx.x * 64;
  float W7[49], W5[25], W3[9];
#pragma unroll
  for (int k = 0; k < 49; ++k) W7[k] = w7[c * 49 + k];
#pragma unroll
  for (int k = 0; k < 25; ++k) W5[k] = w5[c * 25 + k];
#pragma unroll
  for (int k = 0; k < 9; ++k)  W3[k] = w3[c * 9 + k];
  const float bsum = b7[c] + b5[c] + b3[c];

  for (int i = 0; i < 64; ++i) {
    int p = p0 + i;
    if (p >= NPIX) break;            // uniform across block
    int y = p / SG, x = p - y * SG;
    float acc = h[(size_t)(1 + p) * DD + c] + bsum;
    if (y >= 3 && y <= SG - 4 && x >= 3 && x <= SG - 4) {
      // interior fast path: no bounds checks
#pragma unroll
      for (int ky = 0; ky < 7; ++ky)
#pragma unroll
        for (int kx = 0; kx < 7; ++kx)
          acc = fmaf(h[(size_t)(1 + (y + ky - 3) * SG + (x + kx - 3)) * DD + c],
                     W7[ky * 7 + kx], acc);
#pragma unroll
      for (int ky = 0; ky < 5; ++ky)
#pragma unroll
        for (int kx = 0; kx < 5; ++kx)
          acc = fmaf(h[(size_t)(1 + (y + ky - 2) * SG + (x + kx - 2)) * DD + c],
                     W5[ky * 5 + kx], acc);
#pragma unroll
      for (int ky = 0; ky < 3; ++ky)
#pragma unroll
        for (int kx = 0; kx < 3; ++kx)
          acc = fmaf(h[(size_t)(1 + (y + ky - 1) * SG + (x + kx - 1)) * DD + c],
                     W3[ky * 3 + kx], acc);
    } else {
#pragma unroll
      for (int ky = 0; ky < 7; ++ky) {
        int yy = y + ky - 3;
        if (yy < 0 || yy >= SG) continue;
#pragma unroll
        for (int kx = 0; kx < 7; ++kx) {
          int xx = x + kx - 3;
          if (xx < 0 || xx >= SG) continue;
          acc = fmaf(h[(size_t)(1 + yy * SG + xx) * DD + c], W7[ky * 7 + kx], acc);
        }
      }
#pragma unroll
      for (int ky = 0; ky < 5; ++ky) {
        int yy = y + ky - 2;
        if (yy < 0 || yy >= SG) continue;
#pragma unroll
        for (int kx = 0; kx < 5; ++kx) {
          int xx = x + kx - 2;
          if (xx < 0 || xx >= SG) continue;
          acc = fmaf(h[(size_t)(1 + yy * SG + xx) * DD + c], W5[ky * 5 + kx], acc);
        }
      }
#pragma unroll
      for (int ky = 0; ky < 3; ++ky) {
        int yy = y + ky - 1;
        if (yy < 0 || yy >= SG) continue;
#pragma unroll
        for (int kx = 0; kx < 3; ++kx) {
          int xx = x + kx - 1;
          if (xx < 0 || xx >= SG) continue;
          acc = fmaf(h[(size_t)(1 + yy * SG + xx) * DD + c], W3[ky * 3 + kx], acc);
        }
      }
    }
    tmp[(size_t)p * DD + c] = acc;
  }
}

// ---------------- final: LN(row0) -> fc2 -> softmax/argmax -> 5 outputs ----------------
__global__ __launch_bounds__(256) void final_kernel(
    const float* __restrict__ h, const float* __restrict__ g, const float* __restrict__ b,
    const float* __restrict__ w, const float* __restrict__ bias, float* __restrict__ out)
{
  __shared__ float red[256];
  int t = threadIdx.x;
  float v0 = h[t], v1 = h[t + 256];
  red[t] = v0 + v1;
  __syncthreads();
  for (int s = 128; s > 0; s >>= 1) { if (t < s) red[t] += red[t + s]; __syncthreads(); }
  float mu = red[0] * (1.f / 512.f);
  __syncthreads();
  float d0 = v0 - mu, d1 = v1 - mu;
  red[t] = d0 * d0 + d1 * d1;
  __syncthreads();
  for (int s = 128; s > 0; s >>= 1) { if (t < s) red[t] += red[t + s]; __syncthreads(); }
  float rs = rsqrtf(red[0] * (1.f / 512.f) + 1e-5f);
  __syncthreads();
  float x0 = d0 * rs * g[t] + b[t];
  float x1 = d1 * rs * g[t + 256] + b[t + 256];
  red[t] = x0 * w[t * 2] + x1 * w[(t + 256) * 2];
  __syncthreads();
  for (int s = 128; s > 0; s >>= 1) { if (t < s) red[t] += red[t + s]; __syncthreads(); }
  float l0 = red[0] + bias[0];
  __syncthreads();
  red[t] = x0 * w[t * 2 + 1] + x1 * w[(t + 256) * 2 + 1];
  __syncthreads();
  for (int s = 128; s > 0; s >>= 1) { if (t < s) red[t] += red[t + s]; __syncthreads(); }
  float l1 = red[0] + bias[1];
  if (t == 0) {
    out[0] = l0; out[1] = l1;
    float mx = fmaxf(l0, l1);
    float e0 = __expf(l0 - mx), e1 = __expf(l1 - mx);
    float inv = 1.f / (e0 + e1);
    out[2] = e0 * inv; out[3] = e1 * inv;
    out[4] = (l1 > l0) ? 1.f : 0.f;
  }
}

extern "C" void kernel_launch(void* const* d_in, const int* in_sizes, int n_in,
                              void* d_out, int out_size, void* d_ws, size_t ws_size,
                              hipStream_t stream)
{
  const float* data   = (const float*)d_in[0];
  const float* fc1_w  = (const float*)d_in[1];
  const float* fc1_b  = (const float*)d_in[2];
  const float* cls    = (const float*)d_in[3];
  const float* l1_g   = (const float*)d_in[4];
  const float* l1_b   = (const float*)d_in[5];
  const float* l1_qkv = (const float*)d_in[6];
  const float* l1_ow  = (const float*)d_in[7];
  const float* l1_ob  = (const float*)d_in[8];
  const float* l1_rw  = (const float*)d_in[9];
  const float* w7     = (const float*)d_in[10];
  const float* b7     = (const float*)d_in[11];
  const float* w5     = (const float*)d_in[12];
  const float* b5     = (const float*)d_in[13];
  const float* w3     = (const float*)d_in[14];
  const float* b3     = (const float*)d_in[15];
  const float* l2_g   = (const float*)d_in[16];
  const float* l2_b   = (const float*)d_in[17];
  const float* l2_qkv = (const float*)d_in[18];
  const float* l2_ow  = (const float*)d_in[19];
  const float* l2_ob  = (const float*)d_in[20];
  const float* l2_rw  = (const float*)d_in[21];
  const float* ng     = (const float*)d_in[22];
  const float* nb     = (const float*)d_in[23];
  const float* fc2_w  = (const float*)d_in[24];
  const float* fc2_b  = (const float*)d_in[25];
  float* out = (float*)d_out;

  float* ws   = (float*)d_ws;
  float* h    = ws;
  float* xn   = h    + (size_t)16384 * 512;
  float* qkv  = xn   + (size_t)16384 * 512;
  float* attn = qkv  + (size_t)16384 * 1536;
  float* ql   = attn + (size_t)16384 * 512;
  float* kl   = ql   + 256 * 512;
  float* a2b  = kl   + 256 * 512;
  float* z0   = a2b  + 8 * 256 * 256;
  float* z1   = z0   + 8 * 256 * 256;
  float* xzb  = z1   + 8 * 256 * 256;
  float* tb   = xzb  + 8 * 256 * 256;
  float* ub   = tb   + 8 * 256 * 256;
  float* a3v  = ub   + 8 * 256 * 256;
  float* w2   = a3v  + 8 * 256 * 64;
  float* pacc = w2   + 8 * 256 * 64;
  float* pms  = pacc + (size_t)8 * 32 * 256 * 64;
  float* red  = pms  + (size_t)8 * 32 * 256 * 2;

  // fc1 + relu into h rows 1..16000, then cls + duplicated rows
  gemm128<<<dim3(4, 125), 256, 0, stream>>>(data, 1024, fc1_w, 512, h + 512, 512,
                                            16000, 1024, 1, fc1_b);
  assemble_kernel<<<260, 256, 0, stream>>>(h, cls);

  for (int layer = 0; layer < 2; ++layer) {
    const float* gg = layer ? l2_g   : l1_g;
    const float* bb = layer ? l2_b   : l1_b;
    const float* qw = layer ? l2_qkv : l1_qkv;
    const float* ow = layer ? l2_ow  : l1_ow;
    const float* ob = layer ? l2_ob  : l1_ob;
    const float* rw = layer ? l2_rw  : l1_rw;

    ln_pad_kernel<<<16384, 256, 0, stream>>>(h, xn, gg, bb);
    gemm128<<<dim3(12, 128), 256, 0, stream>>>(xn, 512, qw, 1536, qkv, 1536,
                                               16384, 512, 2, nullptr);
    landmark_kernel<<<dim3(256, 4), 256, 0, stream>>>(qkv, ql, kl);
    a2_kernel<<<dim3(8, 256), 256, 0, stream>>>(ql, kl, a2b);
    pinv_red1<<<8, 256, 0, stream>>>(a2b, red);
    pinv_red2<<<1, 1, 0, stream>>>(red);
    pinv_init<<<dim3(8, 256), 256, 0, stream>>>(a2b, red, z0);
    float* zc = z0; float* zn = z1;
    for (int it = 0; it < 6; ++it) {
      mmb_kernel<<<dim3(4, 4, 8), 256, 0, stream>>>(a2b, zc, xzb, 256, 1.f);
      axpbi_kernel<<<dim3(8, 256), 256, 0, stream>>>(xzb, tb, -1.f, 7.f);
      mmb_kernel<<<dim3(4, 4, 8), 256, 0, stream>>>(xzb, tb, ub, 256, 1.f);
      axpbi_kernel<<<dim3(8, 256), 256, 0, stream>>>(ub, tb, -1.f, 15.f);
      mmb_kernel<<<dim3(4, 4, 8), 256, 0, stream>>>(xzb, tb, ub, 256, 1.f);
      axpbi_kernel<<<dim3(8, 256), 256, 0, stream>>>(ub, tb, -1.f, 13.f);
      mmb_kernel<<<dim3(4, 4, 8), 256, 0, stream>>>(zc, tb, zn, 256, 0.25f);
      float* sw = zc; zc = zn; zn = sw;
    }
    a3v_part_kernel<<<dim3(8, 32), 256, 0, stream>>>(qkv, ql, pacc, pms);
    a3v_merge_kernel<<<dim3(8, 256), 64, 0, stream>>>(pacc, pms, a3v);
    mmb_kernel<<<dim3(1, 4, 8), 256, 0, stream>>>(zc, a3v, w2, 64, 1.f);
    a1_kernel<<<dim3(8, 64), 256, 0, stream>>>(qkv, kl, w2, attn);
    resconv_kernel<<<dim3(16384, 2), 256, 0, stream>>>(qkv, rw, attn);
    gemm128<<<dim3(4, 127), 256, 0, stream>>>(attn + (size_t)254 * 512, 512, ow, 512,
                                              h, 512, 16130, 512, 3, ob);
    if (layer == 0) {
      ppeg_kernel<<<dim3((NPIX + 63) / 64, 2), 256, 0, stream>>>(h, qkv, w7, b7, w5, b5, w3, b3);
      hipMemcpyAsync(h + 512, qkv, (size_t)16129 * 512 * 4,
                     hipMemcpyDeviceToDevice, stream);
    }
  }
  final_kernel<<<1, 256, 0, stream>>>(h, ng, nb, fc2_w, fc2_b, out);
}

// Round 3
// 3902.997 us; speedup vs baseline: 1.4922x; 1.1353x over previous
//
#include <hip/hip_runtime.h>
#include <math.h>

#define NPAD   16384
#define PADR   254
#define NTOK   16130
#define NPIX   16129
#define SG     127
#define DD     512
#define NH     8

// ---------------- fp32 GEMM, 128x128 tile, 256 threads, 8x8/thread ----------------
// mode 0: C = acc ; mode 1: C = relu(acc+bias) ; mode 2: C = acc*(col<512?0.125:1)
// mode 3: C += acc + bias
__global__ __launch_bounds__(256) void gemm128(
    const float* __restrict__ A, int lda,
    const float* __restrict__ B, int ldb,
    float* __restrict__ C, int ldc,
    int M, int K, int mode, const float* __restrict__ bias)
{
  __shared__ float As[16][132];
  __shared__ float Bs[16][132];
  const int tid = threadIdx.x;
  const int tx = tid & 15, ty = tid >> 4;
  const int m0 = blockIdx.y * 128;
  const int n0 = blockIdx.x * 128;
  float acc[8][8];
#pragma unroll
  for (int i = 0; i < 8; ++i)
#pragma unroll
    for (int j = 0; j < 8; ++j) acc[i][j] = 0.f;

  for (int k0 = 0; k0 < K; k0 += 16) {
#pragma unroll
    for (int l = 0; l < 2; ++l) {
      int idx = tid + l * 256;
      int row = idx >> 2;
      int k4  = (idx & 3) << 2;
      float4 v = make_float4(0.f, 0.f, 0.f, 0.f);
      int gr = m0 + row;
      if (gr < M) v = *(const float4*)(A + (size_t)gr * lda + k0 + k4);
      As[k4 + 0][row] = v.x;
      As[k4 + 1][row] = v.y;
      As[k4 + 2][row] = v.z;
      As[k4 + 3][row] = v.w;
    }
#pragma unroll
    for (int l = 0; l < 2; ++l) {
      int idx = tid + l * 256;
      int row = idx >> 5;
      int c4  = (idx & 31) << 2;
      *(float4*)&Bs[row][c4] = *(const float4*)(B + (size_t)(k0 + row) * ldb + n0 + c4);
    }
    __syncthreads();
#pragma unroll
    for (int k = 0; k < 16; ++k) {
      float a[8], b[8];
      *(float4*)&a[0] = *(const float4*)&As[k][ty * 4];
      *(float4*)&a[4] = *(const float4*)&As[k][64 + ty * 4];
      *(float4*)&b[0] = *(const float4*)&Bs[k][tx * 4];
      *(float4*)&b[4] = *(const float4*)&Bs[k][64 + tx * 4];
#pragma unroll
      for (int i = 0; i < 8; ++i)
#pragma unroll
        for (int j = 0; j < 8; ++j) acc[i][j] = fmaf(a[i], b[j], acc[i][j]);
    }
    __syncthreads();
  }
#pragma unroll
  for (int i = 0; i < 8; ++i) {
    int rloc = (i < 4) ? (ty * 4 + i) : (64 + ty * 4 + (i - 4));
    int row = m0 + rloc;
    if (row >= M) continue;
#pragma unroll
    for (int jh = 0; jh < 2; ++jh) {
      int col = n0 + jh * 64 + tx * 4;
      float* cp = C + (size_t)row * ldc + col;
      float4 r;
      r.x = acc[i][jh*4+0]; r.y = acc[i][jh*4+1];
      r.z = acc[i][jh*4+2]; r.w = acc[i][jh*4+3];
      if (mode == 1) {
        float4 bb = *(const float4*)(bias + col);
        r.x = fmaxf(r.x + bb.x, 0.f); r.y = fmaxf(r.y + bb.y, 0.f);
        r.z = fmaxf(r.z + bb.z, 0.f); r.w = fmaxf(r.w + bb.w, 0.f);
      } else if (mode == 2) {
        float s = (col < 512) ? 0.125f : 1.f;
        r.x *= s; r.y *= s; r.z *= s; r.w *= s;
      } else if (mode == 3) {
        float4 bb = *(const float4*)(bias + col);
        float4 o  = *(const float4*)cp;
        r.x += o.x + bb.x; r.y += o.y + bb.y;
        r.z += o.z + bb.z; r.w += o.w + bb.w;
      }
      *(float4*)cp = r;
    }
  }
}

// ---------------- assemble: h[0]=cls, h[16001+i]=h[1+i] (i<129) ----------------
__global__ __launch_bounds__(256) void assemble_kernel(float* __restrict__ h,
                                                       const float* __restrict__ cls)
{
  int idx = blockIdx.x * 256 + threadIdx.x;   // 260*256 = 66560 = 512 + 129*512
  if (idx < 512) { h[idx] = cls[idx]; return; }
  idx -= 512;
  int i = idx >> 9, c = idx & 511;
  h[(size_t)(16001 + i) * DD + c] = h[(size_t)(1 + i) * DD + c];
}

// ---------------- LayerNorm rows of h -> xn (front-padded, rows<PADR zeroed) ----------------
__global__ __launch_bounds__(256) void ln_pad_kernel(
    const float* __restrict__ h, float* __restrict__ xn,
    const float* __restrict__ g, const float* __restrict__ b)
{
  int row = blockIdx.x;        // 0..16383
  int t = threadIdx.x;
  if (row < PADR) {
    xn[(size_t)row * DD + t] = 0.f;
    xn[(size_t)row * DD + t + 256] = 0.f;
    return;
  }
  const float* x = h + (size_t)(row - PADR) * DD;
  __shared__ float red[256];
  float v0 = x[t], v1 = x[t + 256];
  red[t] = v0 + v1;
  __syncthreads();
  for (int s = 128; s > 0; s >>= 1) { if (t < s) red[t] += red[t + s]; __syncthreads(); }
  float mu = red[0] * (1.f / 512.f);
  __syncthreads();
  float d0 = v0 - mu, d1 = v1 - mu;
  red[t] = d0 * d0 + d1 * d1;
  __syncthreads();
  for (int s = 128; s > 0; s >>= 1) { if (t < s) red[t] += red[t + s]; __syncthreads(); }
  float rs = rsqrtf(red[0] * (1.f / 512.f) + 1e-5f);
  float* o = xn + (size_t)row * DD;
  o[t]       = d0 * rs * g[t] + b[t];
  o[t + 256] = d1 * rs * g[t + 256] + b[t + 256];
}

// ---------------- landmarks: ql/kl[i][c] = mean_j qkv[(i*64+j)][c(,+512)] ----------------
__global__ __launch_bounds__(256) void landmark_kernel(
    const float* __restrict__ qkv, float* __restrict__ ql, float* __restrict__ kl)
{
  int i = blockIdx.x;                 // landmark 0..255
  int c = blockIdx.y * 256 + threadIdx.x;   // 0..1023
  const float* p = qkv + (size_t)(i * 64) * 1536 + c;
  float s = 0.f;
  for (int j = 0; j < 64; ++j) s += p[(size_t)j * 1536];
  s *= (1.f / 64.f);
  if (c < 512) ql[(size_t)i * 512 + c] = s;
  else         kl[(size_t)i * 512 + (c - 512)] = s;
}

// ---------------- a2 = softmax(ql . kl^T) per head ----------------
__global__ __launch_bounds__(256) void a2_kernel(
    const float* __restrict__ ql, const float* __restrict__ kl, float* __restrict__ a2)
{
  int h_ = blockIdx.x, i = blockIdx.y;
  int t = threadIdx.x;
  __shared__ float q[64];
  __shared__ float red[256];
  if (t < 64) q[t] = ql[(size_t)i * 512 + h_ * 64 + t];
  __syncthreads();
  const float* kr = kl + (size_t)t * 512 + h_ * 64;
  float s = 0.f;
#pragma unroll
  for (int d = 0; d < 64; ++d) s = fmaf(q[d], kr[d], s);
  red[t] = s;
  __syncthreads();
  for (int st = 128; st > 0; st >>= 1) { if (t < st) red[t] = fmaxf(red[t], red[t + st]); __syncthreads(); }
  float mx = red[0];
  __syncthreads();
  float e = __expf(s - mx);
  red[t] = e;
  __syncthreads();
  for (int st = 128; st > 0; st >>= 1) { if (t < st) red[t] += red[t + st]; __syncthreads(); }
  a2[((size_t)h_ * 256 + i) * 256 + t] = e / red[0];
}

// ---------------- pinv init reductions ----------------
__global__ __launch_bounds__(256) void pinv_red1(const float* __restrict__ a2, float* __restrict__ red)
{
  int h_ = blockIdx.x, t = threadIdx.x;
  const float* X = a2 + (size_t)h_ * 65536;
  float rs = 0.f, cs = 0.f;
  for (int j = 0; j < 256; ++j) rs += fabsf(X[(size_t)t * 256 + j]);
  for (int i = 0; i < 256; ++i) cs += fabsf(X[(size_t)i * 256 + t]);
  __shared__ float r1[256], r2[256];
  r1[t] = rs; r2[t] = cs;
  __syncthreads();
  for (int s = 128; s > 0; s >>= 1) {
    if (t < s) { r1[t] = fmaxf(r1[t], r1[t + s]); r2[t] = fmaxf(r2[t], r2[t + s]); }
    __syncthreads();
  }
  if (t == 0) { red[h_ * 2] = r1[0]; red[h_ * 2 + 1] = r2[0]; }
}
__global__ void pinv_red2(float* __restrict__ red)
{
  float mr = 0.f, mc = 0.f;
  for (int h_ = 0; h_ < 8; ++h_) { mr = fmaxf(mr, red[h_ * 2]); mc = fmaxf(mc, red[h_ * 2 + 1]); }
  red[16] = 1.f / (mr * mc);
}
__global__ __launch_bounds__(256) void pinv_init(
    const float* __restrict__ a2, const float* __restrict__ red, float* __restrict__ z)
{
  int h_ = blockIdx.x, i = blockIdx.y, j = threadIdx.x;
  float inv = red[16];
  z[((size_t)h_ * 256 + i) * 256 + j] = a2[((size_t)h_ * 256 + j) * 256 + i] * inv;
}

// ---------------- y = alpha*x + beta*I (batched 8x256x256) ----------------
__global__ __launch_bounds__(256) void axpbi_kernel(
    const float* __restrict__ x, float* __restrict__ y, float alpha, float beta)
{
  int h_ = blockIdx.x, i = blockIdx.y, j = threadIdx.x;
  size_t idx = ((size_t)h_ * 256 + i) * 256 + j;
  y[idx] = alpha * x[idx] + ((i == j) ? beta : 0.f);
}

// ---------------- batched matmul per head: C = alpha*(A @ B), A 256x256, B 256xN ----------------
__global__ __launch_bounds__(256) void mmb_kernel(
    const float* __restrict__ A, const float* __restrict__ B, float* __restrict__ C,
    int N, float alpha)
{
  int h_ = blockIdx.z;
  const float* Ah = A + (size_t)h_ * 256 * 256;
  const float* Bh = B + (size_t)h_ * 256 * N;
  float* Ch = C + (size_t)h_ * 256 * N;
  int m0 = blockIdx.y * 64, n0 = blockIdx.x * 64;
  __shared__ float As[16][68];
  __shared__ float Bs[16][68];
  int tid = threadIdx.x, tx = tid & 15, ty = tid >> 4;
  float acc[4][4];
#pragma unroll
  for (int i = 0; i < 4; ++i)
#pragma unroll
    for (int j = 0; j < 4; ++j) acc[i][j] = 0.f;
  for (int k0 = 0; k0 < 256; k0 += 16) {
    {
      int row = tid >> 2, k4 = (tid & 3) << 2;
      float4 v = *(const float4*)(Ah + (size_t)(m0 + row) * 256 + k0 + k4);
      As[k4 + 0][row] = v.x; As[k4 + 1][row] = v.y;
      As[k4 + 2][row] = v.z; As[k4 + 3][row] = v.w;
    }
    {
      int row = tid >> 4, c4 = (tid & 15) << 2;
      *(float4*)&Bs[row][c4] = *(const float4*)(Bh + (size_t)(k0 + row) * N + n0 + c4);
    }
    __syncthreads();
#pragma unroll
    for (int k = 0; k < 16; ++k) {
      float a[4], b[4];
      *(float4*)a = *(const float4*)&As[k][ty * 4];
      *(float4*)b = *(const float4*)&Bs[k][tx * 4];
#pragma unroll
      for (int i = 0; i < 4; ++i)
#pragma unroll
        for (int j = 0; j < 4; ++j) acc[i][j] = fmaf(a[i], b[j], acc[i][j]);
    }
    __syncthreads();
  }
#pragma unroll
  for (int i = 0; i < 4; ++i) {
    float4 r;
    r.x = alpha * acc[i][0]; r.y = alpha * acc[i][1];
    r.z = alpha * acc[i][2]; r.w = alpha * acc[i][3];
    *(float4*)(Ch + (size_t)(m0 + ty * 4 + i) * N + n0 + tx * 4) = r;
  }
}

// ---------------- a3@v partial (flash, online softmax), grid (8 heads, 32 chunks) ----------------
__global__ __launch_bounds__(256) void a3v_part_kernel(
    const float* __restrict__ qkv, const float* __restrict__ ql,
    float* __restrict__ pacc, float* __restrict__ pms)
{
  int h_ = blockIdx.x;
  int ch = blockIdx.y;
  int t = threadIdx.x;          // landmark row
  float qr[64];
#pragma unroll
  for (int d4 = 0; d4 < 16; ++d4)
    *(float4*)&qr[d4 * 4] = *(const float4*)(ql + (size_t)t * 512 + h_ * 64 + d4 * 4);
  float m = -1e30f, s = 0.f;
  float acc[64];
#pragma unroll
  for (int d = 0; d < 64; ++d) acc[d] = 0.f;
  __shared__ float kt[64][64];
  __shared__ float vt[64][64];
  int jbase = ch * 512;
  for (int j0 = 0; j0 < 512; j0 += 64) {
    __syncthreads();
#pragma unroll
    for (int l = 0; l < 4; ++l) {
      int idx = t + l * 256;
      int r = idx >> 4, c4 = (idx & 15) << 2;
      const float* base = qkv + (size_t)(jbase + j0 + r) * 1536 + h_ * 64 + c4;
      *(float4*)&kt[r][c4] = *(const float4*)(base + 512);
      *(float4*)&vt[r][c4] = *(const float4*)(base + 1024);
    }
    __syncthreads();
    for (int j = 0; j < 64; ++j) {
      float sc = 0.f;
#pragma unroll
      for (int d4 = 0; d4 < 16; ++d4) {
        float4 kv = *(const float4*)&kt[j][d4 * 4];
        sc = fmaf(qr[d4*4+0], kv.x, sc); sc = fmaf(qr[d4*4+1], kv.y, sc);
        sc = fmaf(qr[d4*4+2], kv.z, sc); sc = fmaf(qr[d4*4+3], kv.w, sc);
      }
      if (sc <= m) {
        float p = __expf(sc - m);
        s += p;
#pragma unroll
        for (int d4 = 0; d4 < 16; ++d4) {
          float4 vv = *(const float4*)&vt[j][d4 * 4];
          acc[d4*4+0] = fmaf(p, vv.x, acc[d4*4+0]);
          acc[d4*4+1] = fmaf(p, vv.y, acc[d4*4+1]);
          acc[d4*4+2] = fmaf(p, vv.z, acc[d4*4+2]);
          acc[d4*4+3] = fmaf(p, vv.w, acc[d4*4+3]);
        }
      } else {
        float corr = __expf(m - sc);
        m = sc;
        s = fmaf(s, corr, 1.f);
#pragma unroll
        for (int d4 = 0; d4 < 16; ++d4) {
          float4 vv = *(const float4*)&vt[j][d4 * 4];
          acc[d4*4+0] = fmaf(acc[d4*4+0], corr, vv.x);
          acc[d4*4+1] = fmaf(acc[d4*4+1], corr, vv.y);
          acc[d4*4+2] = fmaf(acc[d4*4+2], corr, vv.z);
          acc[d4*4+3] = fmaf(acc[d4*4+3], corr, vv.w);
        }
      }
    }
  }
  size_t o = ((size_t)h_ * 32 + ch) * 256 + t;
  pms[o * 2] = m; pms[o * 2 + 1] = s;
#pragma unroll
  for (int d4 = 0; d4 < 16; ++d4) {
    float4 r; r.x = acc[d4*4+0]; r.y = acc[d4*4+1]; r.z = acc[d4*4+2]; r.w = acc[d4*4+3];
    *(float4*)(pacc + o * 64 + d4 * 4) = r;
  }
}

// ---------------- merge a3v partials (LSE combine over 32 chunks) ----------------
__global__ __launch_bounds__(64) void a3v_merge_kernel(
    const float* __restrict__ pacc, const float* __restrict__ pms, float* __restrict__ a3v)
{
  int h_ = blockIdx.x, i = blockIdx.y, d = threadIdx.x;
  float M = -1e30f;
  for (int c = 0; c < 32; ++c)
    M = fmaxf(M, pms[(((size_t)h_ * 32 + c) * 256 + i) * 2]);
  float S = 0.f, o = 0.f;
  for (int c = 0; c < 32; ++c) {
    size_t b = ((size_t)h_ * 32 + c) * 256 + i;
    float w = __expf(pms[b * 2] - M);
    S += pms[b * 2 + 1] * w;
    o += pacc[b * 64 + d] * w;
  }
  a3v[((size_t)h_ * 256 + i) * 64 + d] = o / S;
}

// ---------------- out = softmax(q . kl^T) @ w2, fused, grid (8, 64 row-blocks) ----------------
__global__ __launch_bounds__(256) void a1_kernel(
    const float* __restrict__ qkv, const float* __restrict__ kl,
    const float* __restrict__ w2, float* __restrict__ attn)
{
  int h_ = blockIdx.x;
  int r = blockIdx.y * 256 + threadIdx.x;
  int t = threadIdx.x;
  __shared__ float klt[128][64];
  __shared__ float wt[128][64];
  float qr[64];
#pragma unroll
  for (int d4 = 0; d4 < 16; ++d4)
    *(float4*)&qr[d4 * 4] = *(const float4*)(qkv + (size_t)r * 1536 + h_ * 64 + d4 * 4);
  float m = -1e30f, s = 0.f;
  float acc[64];
#pragma unroll
  for (int d = 0; d < 64; ++d) acc[d] = 0.f;
  for (int jh = 0; jh < 2; ++jh) {
    __syncthreads();
#pragma unroll
    for (int l = 0; l < 8; ++l) {
      int idx = t + l * 256;
      int rr = idx >> 4, c4 = (idx & 15) << 2;
      *(float4*)&klt[rr][c4] = *(const float4*)(kl + (size_t)(jh * 128 + rr) * 512 + h_ * 64 + c4);
      *(float4*)&wt[rr][c4]  = *(const float4*)(w2 + ((size_t)h_ * 256 + jh * 128 + rr) * 64 + c4);
    }
    __syncthreads();
    for (int j = 0; j < 128; ++j) {
      float sc = 0.f;
#pragma unroll
      for (int d4 = 0; d4 < 16; ++d4) {
        float4 kv = *(const float4*)&klt[j][d4 * 4];
        sc = fmaf(qr[d4*4+0], kv.x, sc); sc = fmaf(qr[d4*4+1], kv.y, sc);
        sc = fmaf(qr[d4*4+2], kv.z, sc); sc = fmaf(qr[d4*4+3], kv.w, sc);
      }
      if (sc <= m) {
        float p = __expf(sc - m);
        s += p;
#pragma unroll
        for (int d4 = 0; d4 < 16; ++d4) {
          float4 vv = *(const float4*)&wt[j][d4 * 4];
          acc[d4*4+0] = fmaf(p, vv.x, acc[d4*4+0]);
          acc[d4*4+1] = fmaf(p, vv.y, acc[d4*4+1]);
          acc[d4*4+2] = fmaf(p, vv.z, acc[d4*4+2]);
          acc[d4*4+3] = fmaf(p, vv.w, acc[d4*4+3]);
        }
      } else {
        float corr = __expf(m - sc);
        m = sc;
        s = fmaf(s, corr, 1.f);
#pragma unroll
        for (int d4 = 0; d4 < 16; ++d4) {
          float4 vv = *(const float4*)&wt[j][d4 * 4];
          acc[d4*4+0] = fmaf(acc[d4*4+0], corr, vv.x);
          acc[d4*4+1] = fmaf(acc[d4*4+1], corr, vv.y);
          acc[d4*4+2] = fmaf(acc[d4*4+2], corr, vv.z);
          acc[d4*4+3] = fmaf(acc[d4*4+3], corr, vv.w);
        }
      }
    }
  }
  float inv = 1.f / s;
  float* op = attn + (size_t)r * 512 + h_ * 64;
#pragma unroll
  for (int d4 = 0; d4 < 16; ++d4) {
    float4 o;
    o.x = acc[d4*4+0] * inv; o.y = acc[d4*4+1] * inv;
    o.z = acc[d4*4+2] * inv; o.w = acc[d4*4+3] * inv;
    *(float4*)(op + d4 * 4) = o;
  }
}

// ---------------- depthwise res conv over sequence (kernel 33), adds into attn ----------------
__global__ __launch_bounds__(256) void resconv_kernel(
    const float* __restrict__ qkv, const float* __restrict__ rw, float* __restrict__ attn)
{
  int r = blockIdx.x;
  int c = blockIdx.y * 256 + threadIdx.x;
  int h_ = c >> 6;
  float s = 0.f;
#pragma unroll
  for (int tp = 0; tp < 33; ++tp) {
    int rr = r + tp - 16;
    if (rr >= 0 && rr < NPAD)
      s = fmaf(qkv[(size_t)rr * 1536 + 1024 + c], rw[h_ * 33 + tp], s);
  }
  attn[(size_t)r * 512 + c] += s;
}

// ---------------- weight transpose: wt[k*512+c] for k in [0,83) ----------------
// k 0..48 = w7 taps, 49..73 = w5 taps, 74..82 = w3 taps
__global__ __launch_bounds__(256) void wtrans_kernel(
    const float* __restrict__ w7, const float* __restrict__ w5,
    const float* __restrict__ w3, float* __restrict__ wt)
{
  int c = blockIdx.x * 256 + threadIdx.x;   // 0..511
  for (int k = 0; k < 49; ++k) wt[(size_t)k * 512 + c]        = w7[(size_t)c * 49 + k];
  for (int k = 0; k < 25; ++k) wt[(size_t)(49 + k) * 512 + c] = w5[(size_t)c * 25 + k];
  for (int k = 0; k < 9;  ++k) wt[(size_t)(74 + k) * 512 + c] = w3[(size_t)c * 9 + k];
}

// ---------------- PPEG: weights staged in LDS (85KB), 256 ch x 64 px per block ----------
// LDS read wl[k*256+t] is stride-4B across lanes -> 2 lanes/bank (free).
// 5x5/3x3 windows are subsets of the 7x7 window -> 49 unique h-loads/px (CSE).
__global__ __launch_bounds__(256) void ppeg_kernel(
    const float* __restrict__ h, float* __restrict__ tmp,
    const float* __restrict__ wt,
    const float* __restrict__ b7, const float* __restrict__ b5,
    const float* __restrict__ b3)
{
  __shared__ float wl[83 * 256];           // 84,992 B
  const int t = threadIdx.x;
  const int c = blockIdx.y * 256 + t;
#pragma unroll
  for (int k = 0; k < 83; ++k)
    wl[k * 256 + t] = wt[(size_t)k * 512 + c];
  const float bsum = b7[c] + b5[c] + b3[c];
  __syncthreads();

  const int p0 = blockIdx.x * 64;
  for (int i = 0; i < 64; ++i) {
    int p = p0 + i;
    if (p >= NPIX) break;                  // uniform across block
    int y = p / SG, x = p - y * SG;
    float a7 = 0.f, a5 = 0.f, a3 = 0.f;
    if (y >= 3 && y <= SG - 4 && x >= 3 && x <= SG - 4) {
#pragma unroll
      for (int ky = 0; ky < 7; ++ky)
#pragma unroll
        for (int kx = 0; kx < 7; ++kx) {
          float v = h[(size_t)(1 + (y + ky - 3) * SG + (x + kx - 3)) * DD + c];
          a7 = fmaf(v, wl[(ky * 7 + kx) * 256 + t], a7);
          if (ky >= 1 && ky <= 5 && kx >= 1 && kx <= 5)
            a5 = fmaf(v, wl[(49 + (ky - 1) * 5 + (kx - 1)) * 256 + t], a5);
          if (ky >= 2 && ky <= 4 && kx >= 2 && kx <= 4)
            a3 = fmaf(v, wl[(74 + (ky - 2) * 3 + (kx - 2)) * 256 + t], a3);
        }
    } else {
#pragma unroll
      for (int ky = 0; ky < 7; ++ky) {
        int yy = y + ky - 3;
        bool oky = (yy >= 0 && yy < SG);
#pragma unroll
        for (int kx = 0; kx < 7; ++kx) {
          int xx = x + kx - 3;
          float v = (oky && xx >= 0 && xx < SG)
                        ? h[(size_t)(1 + yy * SG + xx) * DD + c] : 0.f;
          a7 = fmaf(v, wl[(ky * 7 + kx) * 256 + t], a7);
          if (ky >= 1 && ky <= 5 && kx >= 1 && kx <= 5)
            a5 = fmaf(v, wl[(49 + (ky - 1) * 5 + (kx - 1)) * 256 + t], a5);
          if (ky >= 2 && ky <= 4 && kx >= 2 && kx <= 4)
            a3 = fmaf(v, wl[(74 + (ky - 2) * 3 + (kx - 2)) * 256 + t], a3);
        }
      }
    }
    tmp[(size_t)p * DD + c] = h[(size_t)(1 + p) * DD + c] + bsum + a7 + a5 + a3;
  }
}

// ---------------- final: LN(row0) -> fc2 -> softmax/argmax -> 5 outputs ----------------
__global__ __launch_bounds__(256) void final_kernel(
    const float* __restrict__ h, const float* __restrict__ g, const float* __restrict__ b,
    const float* __restrict__ w, const float* __restrict__ bias, float* __restrict__ out)
{
  __shared__ float red[256];
  int t = threadIdx.x;
  float v0 = h[t], v1 = h[t + 256];
  red[t] = v0 + v1;
  __syncthreads();
  for (int s = 128; s > 0; s >>= 1) { if (t < s) red[t] += red[t + s]; __syncthreads(); }
  float mu = red[0] * (1.f / 512.f);
  __syncthreads();
  float d0 = v0 - mu, d1 = v1 - mu;
  red[t] = d0 * d0 + d1 * d1;
  __syncthreads();
  for (int s = 128; s > 0; s >>= 1) { if (t < s) red[t] += red[t + s]; __syncthreads(); }
  float rs = rsqrtf(red[0] * (1.f / 512.f) + 1e-5f);
  __syncthreads();
  float x0 = d0 * rs * g[t] + b[t];
  float x1 = d1 * rs * g[t + 256] + b[t + 256];
  red[t] = x0 * w[t * 2] + x1 * w[(t + 256) * 2];
  __syncthreads();
  for (int s = 128; s > 0; s >>= 1) { if (t < s) red[t] += red[t + s]; __syncthreads(); }
  float l0 = red[0] + bias[0];
  __syncthreads();
  red[t] = x0 * w[t * 2 + 1] + x1 * w[(t + 256) * 2 + 1];
  __syncthreads();
  for (int s = 128; s > 0; s >>= 1) { if (t < s) red[t] += red[t + s]; __syncthreads(); }
  float l1 = red[0] + bias[1];
  if (t == 0) {
    out[0] = l0; out[1] = l1;
    float mx = fmaxf(l0, l1);
    float e0 = __expf(l0 - mx), e1 = __expf(l1 - mx);
    float inv = 1.f / (e0 + e1);
    out[2] = e0 * inv; out[3] = e1 * inv;
    out[4] = (l1 > l0) ? 1.f : 0.f;
  }
}

extern "C" void kernel_launch(void* const* d_in, const int* in_sizes, int n_in,
                              void* d_out, int out_size, void* d_ws, size_t ws_size,
                              hipStream_t stream)
{
  const float* data   = (const float*)d_in[0];
  const float* fc1_w  = (const float*)d_in[1];
  const float* fc1_b  = (const float*)d_in[2];
  const float* cls    = (const float*)d_in[3];
  const float* l1_g   = (const float*)d_in[4];
  const float* l1_b   = (const float*)d_in[5];
  const float* l1_qkv = (const float*)d_in[6];
  const float* l1_ow  = (const float*)d_in[7];
  const float* l1_ob  = (const float*)d_in[8];
  const float* l1_rw  = (const float*)d_in[9];
  const float* w7     = (const float*)d_in[10];
  const float* b7     = (const float*)d_in[11];
  const float* w5     = (const float*)d_in[12];
  const float* b5     = (const float*)d_in[13];
  const float* w3     = (const float*)d_in[14];
  const float* b3     = (const float*)d_in[15];
  const float* l2_g   = (const float*)d_in[16];
  const float* l2_b   = (const float*)d_in[17];
  const float* l2_qkv = (const float*)d_in[18];
  const float* l2_ow  = (const float*)d_in[19];
  const float* l2_ob  = (const float*)d_in[20];
  const float* l2_rw  = (const float*)d_in[21];
  const float* ng     = (const float*)d_in[22];
  const float* nb     = (const float*)d_in[23];
  const float* fc2_w  = (const float*)d_in[24];
  const float* fc2_b  = (const float*)d_in[25];
  float* out = (float*)d_out;

  float* ws   = (float*)d_ws;
  float* h    = ws;
  float* xn   = h    + (size_t)16384 * 512;
  float* qkv  = xn   + (size_t)16384 * 512;
  float* attn = qkv  + (size_t)16384 * 1536;
  float* ql   = attn + (size_t)16384 * 512;
  float* kl   = ql   + 256 * 512;
  float* a2b  = kl   + 256 * 512;
  float* z0   = a2b  + 8 * 256 * 256;
  float* z1   = z0   + 8 * 256 * 256;
  float* xzb  = z1   + 8 * 256 * 256;
  float* tb   = xzb  + 8 * 256 * 256;
  float* ub   = tb   + 8 * 256 * 256;
  float* a3v  = ub   + 8 * 256 * 256;
  float* w2   = a3v  + 8 * 256 * 64;
  float* pacc = w2   + 8 * 256 * 64;
  float* pms  = pacc + (size_t)8 * 32 * 256 * 64;
  float* red  = pms  + (size_t)8 * 32 * 256 * 2;
  float* wtb  = red  + 32;                       // 83*512 floats

  // fc1 + relu into h rows 1..16000, then cls + duplicated rows
  gemm128<<<dim3(4, 125), 256, 0, stream>>>(data, 1024, fc1_w, 512, h + 512, 512,
                                            16000, 1024, 1, fc1_b);
  assemble_kernel<<<260, 256, 0, stream>>>(h, cls);
  wtrans_kernel<<<2, 256, 0, stream>>>(w7, w5, w3, wtb);

  for (int layer = 0; layer < 2; ++layer) {
    const float* gg = layer ? l2_g   : l1_g;
    const float* bb = layer ? l2_b   : l1_b;
    const float* qw = layer ? l2_qkv : l1_qkv;
    const float* ow = layer ? l2_ow  : l1_ow;
    const float* ob = layer ? l2_ob  : l1_ob;
    const float* rw = layer ? l2_rw  : l1_rw;

    ln_pad_kernel<<<16384, 256, 0, stream>>>(h, xn, gg, bb);
    gemm128<<<dim3(12, 128), 256, 0, stream>>>(xn, 512, qw, 1536, qkv, 1536,
                                               16384, 512, 2, nullptr);
    landmark_kernel<<<dim3(256, 4), 256, 0, stream>>>(qkv, ql, kl);
    a2_kernel<<<dim3(8, 256), 256, 0, stream>>>(ql, kl, a2b);
    pinv_red1<<<8, 256, 0, stream>>>(a2b, red);
    pinv_red2<<<1, 1, 0, stream>>>(red);
    pinv_init<<<dim3(8, 256), 256, 0, stream>>>(a2b, red, z0);
    float* zc = z0; float* zn = z1;
    for (int it = 0; it < 6; ++it) {
      mmb_kernel<<<dim3(4, 4, 8), 256, 0, stream>>>(a2b, zc, xzb, 256, 1.f);
      axpbi_kernel<<<dim3(8, 256), 256, 0, stream>>>(xzb, tb, -1.f, 7.f);
      mmb_kernel<<<dim3(4, 4, 8), 256, 0, stream>>>(xzb, tb, ub, 256, 1.f);
      axpbi_kernel<<<dim3(8, 256), 256, 0, stream>>>(ub, tb, -1.f, 15.f);
      mmb_kernel<<<dim3(4, 4, 8), 256, 0, stream>>>(xzb, tb, ub, 256, 1.f);
      axpbi_kernel<<<dim3(8, 256), 256, 0, stream>>>(ub, tb, -1.f, 13.f);
      mmb_kernel<<<dim3(4, 4, 8), 256, 0, stream>>>(zc, tb, zn, 256, 0.25f);
      float* sw = zc; zc = zn; zn = sw;
    }
    a3v_part_kernel<<<dim3(8, 32), 256, 0, stream>>>(qkv, ql, pacc, pms);
    a3v_merge_kernel<<<dim3(8, 256), 64, 0, stream>>>(pacc, pms, a3v);
    mmb_kernel<<<dim3(1, 4, 8), 256, 0, stream>>>(zc, a3v, w2, 64, 1.f);
    a1_kernel<<<dim3(8, 64), 256, 0, stream>>>(qkv, kl, w2, attn);
    resconv_kernel<<<dim3(16384, 2), 256, 0, stream>>>(qkv, rw, attn);
    gemm128<<<dim3(4, 127), 256, 0, stream>>>(attn + (size_t)254 * 512, 512, ow, 512,
                                              h, 512, 16130, 512, 3, ob);
    if (layer == 0) {
      ppeg_kernel<<<dim3((NPIX + 63) / 64, 2), 256, 0, stream>>>(h, qkv, wtb, b7, b5, b3);
      hipMemcpyAsync(h + 512, qkv, (size_t)16129 * 512 * 4,
                     hipMemcpyDeviceToDevice, stream);
    }
  }
  final_kernel<<<1, 256, 0, stream>>>(h, ng, nb, fc2_w, fc2_b, out);
}

// Round 4
// 3095.132 us; speedup vs baseline: 1.8817x; 1.2610x over previous
//
#include <hip/hip_runtime.h>
#include <math.h>

#define NPAD   16384
#define PADR   254
#define NTOK   16130
#define NPIX   16129
#define SG     127
#define DD     512
#define NH     8
#define CHK    64          // key-chunks per head for a3v

typedef __attribute__((ext_vector_type(8))) short bf16x8;
typedef __attribute__((ext_vector_type(4))) float f32x4;

__device__ __forceinline__ ushort f2bf(float f) {
  uint u = __float_as_uint(f);
  u = (u + 0x7fffu + ((u >> 16) & 1u)) >> 16;
  return (ushort)u;
}

// ---------------- fp32 GEMM, 128x128 tile, 256 threads, 8x8/thread ----------------
// mode 0: C = acc ; mode 1: C = relu(acc+bias) ; mode 2: C = acc*(col<512?0.125:1)
// mode 3: C += acc + bias
__global__ __launch_bounds__(256) void gemm128(
    const float* __restrict__ A, int lda,
    const float* __restrict__ B, int ldb,
    float* __restrict__ C, int ldc,
    int M, int K, int mode, const float* __restrict__ bias)
{
  __shared__ float As[16][132];
  __shared__ float Bs[16][132];
  const int tid = threadIdx.x;
  const int tx = tid & 15, ty = tid >> 4;
  const int m0 = blockIdx.y * 128;
  const int n0 = blockIdx.x * 128;
  float acc[8][8];
#pragma unroll
  for (int i = 0; i < 8; ++i)
#pragma unroll
    for (int j = 0; j < 8; ++j) acc[i][j] = 0.f;

  for (int k0 = 0; k0 < K; k0 += 16) {
#pragma unroll
    for (int l = 0; l < 2; ++l) {
      int idx = tid + l * 256;
      int row = idx >> 2;
      int k4  = (idx & 3) << 2;
      float4 v = make_float4(0.f, 0.f, 0.f, 0.f);
      int gr = m0 + row;
      if (gr < M) v = *(const float4*)(A + (size_t)gr * lda + k0 + k4);
      As[k4 + 0][row] = v.x;
      As[k4 + 1][row] = v.y;
      As[k4 + 2][row] = v.z;
      As[k4 + 3][row] = v.w;
    }
#pragma unroll
    for (int l = 0; l < 2; ++l) {
      int idx = tid + l * 256;
      int row = idx >> 5;
      int c4  = (idx & 31) << 2;
      *(float4*)&Bs[row][c4] = *(const float4*)(B + (size_t)(k0 + row) * ldb + n0 + c4);
    }
    __syncthreads();
#pragma unroll
    for (int k = 0; k < 16; ++k) {
      float a[8], b[8];
      *(float4*)&a[0] = *(const float4*)&As[k][ty * 4];
      *(float4*)&a[4] = *(const float4*)&As[k][64 + ty * 4];
      *(float4*)&b[0] = *(const float4*)&Bs[k][tx * 4];
      *(float4*)&b[4] = *(const float4*)&Bs[k][64 + tx * 4];
#pragma unroll
      for (int i = 0; i < 8; ++i)
#pragma unroll
        for (int j = 0; j < 8; ++j) acc[i][j] = fmaf(a[i], b[j], acc[i][j]);
    }
    __syncthreads();
  }
#pragma unroll
  for (int i = 0; i < 8; ++i) {
    int rloc = (i < 4) ? (ty * 4 + i) : (64 + ty * 4 + (i - 4));
    int row = m0 + rloc;
    if (row >= M) continue;
#pragma unroll
    for (int jh = 0; jh < 2; ++jh) {
      int col = n0 + jh * 64 + tx * 4;
      float* cp = C + (size_t)row * ldc + col;
      float4 r;
      r.x = acc[i][jh*4+0]; r.y = acc[i][jh*4+1];
      r.z = acc[i][jh*4+2]; r.w = acc[i][jh*4+3];
      if (mode == 1) {
        float4 bb = *(const float4*)(bias + col);
        r.x = fmaxf(r.x + bb.x, 0.f); r.y = fmaxf(r.y + bb.y, 0.f);
        r.z = fmaxf(r.z + bb.z, 0.f); r.w = fmaxf(r.w + bb.w, 0.f);
      } else if (mode == 2) {
        float s = (col < 512) ? 0.125f : 1.f;
        r.x *= s; r.y *= s; r.z *= s; r.w *= s;
      } else if (mode == 3) {
        float4 bb = *(const float4*)(bias + col);
        float4 o  = *(const float4*)cp;
        r.x += o.x + bb.x; r.y += o.y + bb.y;
        r.z += o.z + bb.z; r.w += o.w + bb.w;
      }
      *(float4*)cp = r;
    }
  }
}

// ---------------- assemble: h[0]=cls, h[16001+i]=h[1+i] (i<129) ----------------
__global__ __launch_bounds__(256) void assemble_kernel(float* __restrict__ h,
                                                       const float* __restrict__ cls)
{
  int idx = blockIdx.x * 256 + threadIdx.x;   // 260*256 = 66560 = 512 + 129*512
  if (idx < 512) { h[idx] = cls[idx]; return; }
  idx -= 512;
  int i = idx >> 9, c = idx & 511;
  h[(size_t)(16001 + i) * DD + c] = h[(size_t)(1 + i) * DD + c];
}

// ---------------- LayerNorm rows of h -> xn (front-padded, rows<PADR zeroed) ----------------
__global__ __launch_bounds__(256) void ln_pad_kernel(
    const float* __restrict__ h, float* __restrict__ xn,
    const float* __restrict__ g, const float* __restrict__ b)
{
  int row = blockIdx.x;        // 0..16383
  int t = threadIdx.x;
  if (row < PADR) {
    xn[(size_t)row * DD + t] = 0.f;
    xn[(size_t)row * DD + t + 256] = 0.f;
    return;
  }
  const float* x = h + (size_t)(row - PADR) * DD;
  __shared__ float red[256];
  float v0 = x[t], v1 = x[t + 256];
  red[t] = v0 + v1;
  __syncthreads();
  for (int s = 128; s > 0; s >>= 1) { if (t < s) red[t] += red[t + s]; __syncthreads(); }
  float mu = red[0] * (1.f / 512.f);
  __syncthreads();
  float d0 = v0 - mu, d1 = v1 - mu;
  red[t] = d0 * d0 + d1 * d1;
  __syncthreads();
  for (int s = 128; s > 0; s >>= 1) { if (t < s) red[t] += red[t + s]; __syncthreads(); }
  float rs = rsqrtf(red[0] * (1.f / 512.f) + 1e-5f);
  float* o = xn + (size_t)row * DD;
  o[t]       = d0 * rs * g[t] + b[t];
  o[t + 256] = d1 * rs * g[t + 256] + b[t + 256];
}

// ---------------- landmarks: ql/kl[i][c] = mean_j qkv[(i*64+j)][c(,+512)] ----------------
__global__ __launch_bounds__(256) void landmark_kernel(
    const float* __restrict__ qkv, float* __restrict__ ql, float* __restrict__ kl)
{
  int i = blockIdx.x;                 // landmark 0..255
  int c = blockIdx.y * 256 + threadIdx.x;   // 0..1023
  const float* p = qkv + (size_t)(i * 64) * 1536 + c;
  float s = 0.f;
  for (int j = 0; j < 64; ++j) s += p[(size_t)j * 1536];
  s *= (1.f / 64.f);
  if (c < 512) ql[(size_t)i * 512 + c] = s;
  else         kl[(size_t)i * 512 + (c - 512)] = s;
}

// ---------------- a2 = softmax(ql . kl^T) per head ----------------
__global__ __launch_bounds__(256) void a2_kernel(
    const float* __restrict__ ql, const float* __restrict__ kl, float* __restrict__ a2)
{
  int h_ = blockIdx.x, i = blockIdx.y;
  int t = threadIdx.x;
  __shared__ float q[64];
  __shared__ float red[256];
  if (t < 64) q[t] = ql[(size_t)i * 512 + h_ * 64 + t];
  __syncthreads();
  const float* kr = kl + (size_t)t * 512 + h_ * 64;
  float s = 0.f;
#pragma unroll
  for (int d = 0; d < 64; ++d) s = fmaf(q[d], kr[d], s);
  red[t] = s;
  __syncthreads();
  for (int st = 128; st > 0; st >>= 1) { if (t < st) red[t] = fmaxf(red[t], red[t + st]); __syncthreads(); }
  float mx = red[0];
  __syncthreads();
  float e = __expf(s - mx);
  red[t] = e;
  __syncthreads();
  for (int st = 128; st > 0; st >>= 1) { if (t < st) red[t] += red[t + st]; __syncthreads(); }
  a2[((size_t)h_ * 256 + i) * 256 + t] = e / red[0];
}

// ---------------- pinv init reductions ----------------
__global__ __launch_bounds__(256) void pinv_red1(const float* __restrict__ a2, float* __restrict__ red)
{
  int h_ = blockIdx.x, t = threadIdx.x;
  const float* X = a2 + (size_t)h_ * 65536;
  float rs = 0.f, cs = 0.f;
  for (int j = 0; j < 256; ++j) rs += fabsf(X[(size_t)t * 256 + j]);
  for (int i = 0; i < 256; ++i) cs += fabsf(X[(size_t)i * 256 + t]);
  __shared__ float r1[256], r2[256];
  r1[t] = rs; r2[t] = cs;
  __syncthreads();
  for (int s = 128; s > 0; s >>= 1) {
    if (t < s) { r1[t] = fmaxf(r1[t], r1[t + s]); r2[t] = fmaxf(r2[t], r2[t + s]); }
    __syncthreads();
  }
  if (t == 0) { red[h_ * 2] = r1[0]; red[h_ * 2 + 1] = r2[0]; }
}
__global__ void pinv_red2(float* __restrict__ red)
{
  float mr = 0.f, mc = 0.f;
  for (int h_ = 0; h_ < 8; ++h_) { mr = fmaxf(mr, red[h_ * 2]); mc = fmaxf(mc, red[h_ * 2 + 1]); }
  red[16] = 1.f / (mr * mc);
}
__global__ __launch_bounds__(256) void pinv_init(
    const float* __restrict__ a2, const float* __restrict__ red, float* __restrict__ z)
{
  int h_ = blockIdx.x, i = blockIdx.y, j = threadIdx.x;
  float inv = red[16];
  z[((size_t)h_ * 256 + i) * 256 + j] = a2[((size_t)h_ * 256 + j) * 256 + i] * inv;
}

// ---------------- y = alpha*x + beta*I (batched 8x256x256) ----------------
__global__ __launch_bounds__(256) void axpbi_kernel(
    const float* __restrict__ x, float* __restrict__ y, float alpha, float beta)
{
  int h_ = blockIdx.x, i = blockIdx.y, j = threadIdx.x;
  size_t idx = ((size_t)h_ * 256 + i) * 256 + j;
  y[idx] = alpha * x[idx] + ((i == j) ? beta : 0.f);
}

// ---------------- batched matmul per head: C = alpha*(A @ B), A 256x256, B 256xN ----------------
__global__ __launch_bounds__(256) void mmb_kernel(
    const float* __restrict__ A, const float* __restrict__ B, float* __restrict__ C,
    int N, float alpha)
{
  int h_ = blockIdx.z;
  const float* Ah = A + (size_t)h_ * 256 * 256;
  const float* Bh = B + (size_t)h_ * 256 * N;
  float* Ch = C + (size_t)h_ * 256 * N;
  int m0 = blockIdx.y * 64, n0 = blockIdx.x * 64;
  __shared__ float As[16][68];
  __shared__ float Bs[16][68];
  int tid = threadIdx.x, tx = tid & 15, ty = tid >> 4;
  float acc[4][4];
#pragma unroll
  for (int i = 0; i < 4; ++i)
#pragma unroll
    for (int j = 0; j < 4; ++j) acc[i][j] = 0.f;
  for (int k0 = 0; k0 < 256; k0 += 16) {
    {
      int row = tid >> 2, k4 = (tid & 3) << 2;
      float4 v = *(const float4*)(Ah + (size_t)(m0 + row) * 256 + k0 + k4);
      As[k4 + 0][row] = v.x; As[k4 + 1][row] = v.y;
      As[k4 + 2][row] = v.z; As[k4 + 3][row] = v.w;
    }
    {
      int row = tid >> 4, c4 = (tid & 15) << 2;
      *(float4*)&Bs[row][c4] = *(const float4*)(Bh + (size_t)(k0 + row) * N + n0 + c4);
    }
    __syncthreads();
#pragma unroll
    for (int k = 0; k < 16; ++k) {
      float a[4], b[4];
      *(float4*)a = *(const float4*)&As[k][ty * 4];
      *(float4*)b = *(const float4*)&Bs[k][tx * 4];
#pragma unroll
      for (int i = 0; i < 4; ++i)
#pragma unroll
        for (int j = 0; j < 4; ++j) acc[i][j] = fmaf(a[i], b[j], acc[i][j]);
    }
    __syncthreads();
  }
#pragma unroll
  for (int i = 0; i < 4; ++i) {
    float4 r;
    r.x = alpha * acc[i][0]; r.y = alpha * acc[i][1];
    r.z = alpha * acc[i][2]; r.w = alpha * acc[i][3];
    *(float4*)(Ch + (size_t)(m0 + ty * 4 + i) * N + n0 + tx * 4) = r;
  }
}

// ---------------- a3@v partials via bf16 MFMA flash (no-max exp, ones-column den) ----------
// grid (8 heads, CHK chunks), 256 threads = 4 waves; wave w owns landmark rows 64w..64w+63.
// S = ql@K^T in fp32 via mfma; P = exp(S) (scores bounded |S|<~1, no max needed);
// O_ext = P @ [V | 1] gives numerator cols 0..63 and denominator at col 64.
// Partials are plain sums across chunks (no LSE merge).
__global__ __launch_bounds__(256) void a3v_mfma(
    const float* __restrict__ qkv, const float* __restrict__ ql,
    float* __restrict__ pacc, float* __restrict__ den)
{
  const int h_ = blockIdx.x;
  const int ch = blockIdx.y;
  const int t  = threadIdx.x;
  const int w  = t >> 6;
  const int l  = t & 63;
  const int lr = l & 15;
  const int lg = l >> 4;

  __shared__ __align__(16) ushort kls[64 * 64];     // K tile [j][d] bf16, 16B-block XOR swizzle
  __shared__ __align__(16) ushort vls[80 * 64];     // V^T tile [d][j] (+16 ones/zero rows)
  __shared__ __align__(16) ushort pls[4][64 * 64];  // per-wave P [i][j]

  // Q A-fragments: row = 64w + rt*16 + lr, k(d) = dc*32 + lg*8 + e
  bf16x8 qf[4][2];
#pragma unroll
  for (int rt = 0; rt < 4; ++rt)
#pragma unroll
    for (int dc = 0; dc < 2; ++dc) {
      const float* p = ql + (size_t)(64 * w + rt * 16 + lr) * 512 + h_ * 64 + dc * 32 + lg * 8;
      float4 f0 = *(const float4*)p;
      float4 f1 = *(const float4*)(p + 4);
      bf16x8 v;
      v[0] = f2bf(f0.x); v[1] = f2bf(f0.y); v[2] = f2bf(f0.z); v[3] = f2bf(f0.w);
      v[4] = f2bf(f1.x); v[5] = f2bf(f1.y); v[6] = f2bf(f1.z); v[7] = f2bf(f1.w);
      qf[rt][dc] = v;
    }

  // ones rows of VT (row 64 = 1.0, rows 65..79 = 0), written once
  if (t < 128) {
    int rr = t >> 3, cb = t & 7;
    ushort val = (rr == 0) ? (ushort)0x3f80 : (ushort)0;
    bf16x8 vv;
#pragma unroll
    for (int k = 0; k < 8; ++k) vv[k] = (short)val;
    *(bf16x8*)(vls + (64 + rr) * 64 + ((cb ^ (rr & 7)) << 3)) = vv;
  }

  f32x4 acc[4][5];
#pragma unroll
  for (int rt = 0; rt < 4; ++rt)
#pragma unroll
    for (int dt = 0; dt < 5; ++dt) acc[rt][dt] = (f32x4){0.f, 0.f, 0.f, 0.f};

  const int j0base = ch * 256;
  for (int jt = 0; jt < 4; ++jt) {
    const int j0 = j0base + jt * 64;
    __syncthreads();
    // stage K tile: thread -> (row r, 16-float block db)
    {
      int r = t >> 2, db = t & 3;
      const float* src = qkv + (size_t)(j0 + r) * 1536 + 512 + h_ * 64 + db * 16;
      float4 g0 = *(const float4*)(src + 0);
      float4 g1 = *(const float4*)(src + 4);
      float4 g2 = *(const float4*)(src + 8);
      float4 g3 = *(const float4*)(src + 12);
      bf16x8 e0, e1;
      e0[0] = f2bf(g0.x); e0[1] = f2bf(g0.y); e0[2] = f2bf(g0.z); e0[3] = f2bf(g0.w);
      e0[4] = f2bf(g1.x); e0[5] = f2bf(g1.y); e0[6] = f2bf(g1.z); e0[7] = f2bf(g1.w);
      e1[0] = f2bf(g2.x); e1[1] = f2bf(g2.y); e1[2] = f2bf(g2.z); e1[3] = f2bf(g2.w);
      e1[4] = f2bf(g3.x); e1[5] = f2bf(g3.y); e1[6] = f2bf(g3.z); e1[7] = f2bf(g3.w);
      ushort* base = kls + r * 64;
      *(bf16x8*)(base + (((db * 2 + 0) ^ (r & 7)) << 3)) = e0;
      *(bf16x8*)(base + (((db * 2 + 1) ^ (r & 7)) << 3)) = e1;
    }
    // stage V^T tile: thread -> (d = t&63, two 8-key blocks)
    {
      int d = t & 63, jg = t >> 6;
#pragma unroll
      for (int half = 0; half < 2; ++half) {
        int jb = jg + half * 4;
        bf16x8 e;
#pragma unroll
        for (int jj = 0; jj < 8; ++jj)
          e[jj] = f2bf(qkv[(size_t)(j0 + jb * 8 + jj) * 1536 + 1024 + h_ * 64 + d]);
        *(bf16x8*)(vls + d * 64 + ((jb ^ (d & 7)) << 3)) = e;
      }
    }
    __syncthreads();

    // QK^T (fp32 D) -> exp -> P (bf16, per-wave LDS)
    ushort* pw = pls[w];
#pragma unroll
    for (int sjt = 0; sjt < 4; ++sjt) {
      const int krow = sjt * 16 + lr;
      bf16x8 kf0 = *(const bf16x8*)(kls + krow * 64 + (((0 * 4 + lg) ^ (lr & 7)) << 3));
      bf16x8 kf1 = *(const bf16x8*)(kls + krow * 64 + (((1 * 4 + lg) ^ (lr & 7)) << 3));
#pragma unroll
      for (int rt = 0; rt < 4; ++rt) {
        f32x4 s = (f32x4){0.f, 0.f, 0.f, 0.f};
        s = __builtin_amdgcn_mfma_f32_16x16x32_bf16(qf[rt][0], kf0, s, 0, 0, 0);
        s = __builtin_amdgcn_mfma_f32_16x16x32_bf16(qf[rt][1], kf1, s, 0, 0, 0);
#pragma unroll
        for (int r = 0; r < 4; ++r) {
          int i  = rt * 16 + lg * 4 + r;
          int jj = sjt * 16 + lr;
          pw[i * 64 + ((((jj >> 3) ^ (i & 7)) << 3)) + (jj & 7)] = (short)f2bf(__expf(s[r]));
        }
      }
    }
    // load P A-fragments (same-wave LDS RAW: DS pipe is in-order per wave)
    bf16x8 pf[4][2];
#pragma unroll
    for (int rt = 0; rt < 4; ++rt)
#pragma unroll
      for (int jc = 0; jc < 2; ++jc)
        pf[rt][jc] = *(const bf16x8*)(pw + (rt * 16 + lr) * 64 + (((jc * 4 + lg) ^ (lr & 7)) << 3));
    // PV: acc[rt][dt] += P . [V|1]
#pragma unroll
    for (int dt = 0; dt < 5; ++dt) {
      const int vrow = dt * 16 + lr;
      bf16x8 vf0 = *(const bf16x8*)(vls + vrow * 64 + (((0 * 4 + lg) ^ (lr & 7)) << 3));
      bf16x8 vf1 = *(const bf16x8*)(vls + vrow * 64 + (((1 * 4 + lg) ^ (lr & 7)) << 3));
#pragma unroll
      for (int rt = 0; rt < 4; ++rt) {
        acc[rt][dt] = __builtin_amdgcn_mfma_f32_16x16x32_bf16(pf[rt][0], vf0, acc[rt][dt], 0, 0, 0);
        acc[rt][dt] = __builtin_amdgcn_mfma_f32_16x16x32_bf16(pf[rt][1], vf1, acc[rt][dt], 0, 0, 0);
      }
    }
  }

  // write partials: rows i = 64w + rt*16 + lg*4 + r ; cols dt*16 + lr ; den = col 64
  const size_t pbase = (size_t)(h_ * CHK + ch) * 256;
#pragma unroll
  for (int rt = 0; rt < 4; ++rt) {
    int i = 64 * w + rt * 16 + lg * 4;
#pragma unroll
    for (int dt = 0; dt < 4; ++dt)
#pragma unroll
      for (int r = 0; r < 4; ++r)
        pacc[(pbase + i + r) * 64 + dt * 16 + lr] = acc[rt][dt][r];
    if (lr == 0) {
#pragma unroll
      for (int r = 0; r < 4; ++r)
        den[pbase + i + r] = acc[rt][4][r];
    }
  }
}

// ---------------- merge a3v partials (plain sums over CHK chunks) ----------------
__global__ __launch_bounds__(64) void a3v_merge_kernel(
    const float* __restrict__ pacc, const float* __restrict__ den, float* __restrict__ a3v)
{
  int h_ = blockIdx.x, i = blockIdx.y, d = threadIdx.x;
  float S = 0.f, o = 0.f;
  for (int c = 0; c < CHK; ++c) {
    size_t b = (size_t)(h_ * CHK + c) * 256 + i;
    o += pacc[b * 64 + d];
    S += den[b];
  }
  a3v[((size_t)h_ * 256 + i) * 64 + d] = o / S;
}

// ---------------- out = softmax(q . kl^T) @ w2, fused, grid (8, 64 row-blocks) ----------------
__global__ __launch_bounds__(256) void a1_kernel(
    const float* __restrict__ qkv, const float* __restrict__ kl,
    const float* __restrict__ w2, float* __restrict__ attn)
{
  int h_ = blockIdx.x;
  int r = blockIdx.y * 256 + threadIdx.x;
  int t = threadIdx.x;
  __shared__ float klt[128][64];
  __shared__ float wt[128][64];
  float qr[64];
#pragma unroll
  for (int d4 = 0; d4 < 16; ++d4)
    *(float4*)&qr[d4 * 4] = *(const float4*)(qkv + (size_t)r * 1536 + h_ * 64 + d4 * 4);
  float m = -1e30f, s = 0.f;
  float acc[64];
#pragma unroll
  for (int d = 0; d < 64; ++d) acc[d] = 0.f;
  for (int jh = 0; jh < 2; ++jh) {
    __syncthreads();
#pragma unroll
    for (int l = 0; l < 8; ++l) {
      int idx = t + l * 256;
      int rr = idx >> 4, c4 = (idx & 15) << 2;
      *(float4*)&klt[rr][c4] = *(const float4*)(kl + (size_t)(jh * 128 + rr) * 512 + h_ * 64 + c4);
      *(float4*)&wt[rr][c4]  = *(const float4*)(w2 + ((size_t)h_ * 256 + jh * 128 + rr) * 64 + c4);
    }
    __syncthreads();
    for (int j = 0; j < 128; ++j) {
      float sc = 0.f;
#pragma unroll
      for (int d4 = 0; d4 < 16; ++d4) {
        float4 kv = *(const float4*)&klt[j][d4 * 4];
        sc = fmaf(qr[d4*4+0], kv.x, sc); sc = fmaf(qr[d4*4+1], kv.y, sc);
        sc = fmaf(qr[d4*4+2], kv.z, sc); sc = fmaf(qr[d4*4+3], kv.w, sc);
      }
      if (sc <= m) {
        float p = __expf(sc - m);
        s += p;
#pragma unroll
        for (int d4 = 0; d4 < 16; ++d4) {
          float4 vv = *(const float4*)&wt[j][d4 * 4];
          acc[d4*4+0] = fmaf(p, vv.x, acc[d4*4+0]);
          acc[d4*4+1] = fmaf(p, vv.y, acc[d4*4+1]);
          acc[d4*4+2] = fmaf(p, vv.z, acc[d4*4+2]);
          acc[d4*4+3] = fmaf(p, vv.w, acc[d4*4+3]);
        }
      } else {
        float corr = __expf(m - sc);
        m = sc;
        s = fmaf(s, corr, 1.f);
#pragma unroll
        for (int d4 = 0; d4 < 16; ++d4) {
          float4 vv = *(const float4*)&wt[j][d4 * 4];
          acc[d4*4+0] = fmaf(acc[d4*4+0], corr, vv.x);
          acc[d4*4+1] = fmaf(acc[d4*4+1], corr, vv.y);
          acc[d4*4+2] = fmaf(acc[d4*4+2], corr, vv.z);
          acc[d4*4+3] = fmaf(acc[d4*4+3], corr, vv.w);
        }
      }
    }
  }
  float inv = 1.f / s;
  float* op = attn + (size_t)r * 512 + h_ * 64;
#pragma unroll
  for (int d4 = 0; d4 < 16; ++d4) {
    float4 o;
    o.x = acc[d4*4+0] * inv; o.y = acc[d4*4+1] * inv;
    o.z = acc[d4*4+2] * inv; o.w = acc[d4*4+3] * inv;
    *(float4*)(op + d4 * 4) = o;
  }
}

// ---------------- depthwise res conv over sequence (kernel 33), adds into attn ----------------
__global__ __launch_bounds__(256) void resconv_kernel(
    const float* __restrict__ qkv, const float* __restrict__ rw, float* __restrict__ attn)
{
  int r = blockIdx.x;
  int c = blockIdx.y * 256 + threadIdx.x;
  int h_ = c >> 6;
  float s = 0.f;
#pragma unroll
  for (int tp = 0; tp < 33; ++tp) {
    int rr = r + tp - 16;
    if (rr >= 0 && rr < NPAD)
      s = fmaf(qkv[(size_t)rr * 1536 + 1024 + c], rw[h_ * 33 + tp], s);
  }
  attn[(size_t)r * 512 + c] += s;
}

// ---------------- weight transpose: wt[k*512+c] for k in [0,83) ----------------
__global__ __launch_bounds__(256) void wtrans_kernel(
    const float* __restrict__ w7, const float* __restrict__ w5,
    const float* __restrict__ w3, float* __restrict__ wt)
{
  int c = blockIdx.x * 256 + threadIdx.x;   // 0..511
  for (int k = 0; k < 49; ++k) wt[(size_t)k * 512 + c]        = w7[(size_t)c * 49 + k];
  for (int k = 0; k < 25; ++k) wt[(size_t)(49 + k) * 512 + c] = w5[(size_t)c * 25 + k];
  for (int k = 0; k < 9;  ++k) wt[(size_t)(74 + k) * 512 + c] = w3[(size_t)c * 9 + k];
}

// ---------------- PPEG: weights staged in LDS (85KB), 256 ch x 64 px per block ----------
__global__ __launch_bounds__(256) void ppeg_kernel(
    const float* __restrict__ h, float* __restrict__ tmp,
    const float* __restrict__ wt,
    const float* __restrict__ b7, const float* __restrict__ b5,
    const float* __restrict__ b3)
{
  __shared__ float wl[83 * 256];           // 84,992 B
  const int t = threadIdx.x;
  const int c = blockIdx.y * 256 + t;
#pragma unroll
  for (int k = 0; k < 83; ++k)
    wl[k * 256 + t] = wt[(size_t)k * 512 + c];
  const float bsum = b7[c] + b5[c] + b3[c];
  __syncthreads();

  const int p0 = blockIdx.x * 64;
  for (int i = 0; i < 64; ++i) {
    int p = p0 + i;
    if (p >= NPIX) break;                  // uniform across block
    int y = p / SG, x = p - y * SG;
    float a7 = 0.f, a5 = 0.f, a3 = 0.f;
    if (y >= 3 && y <= SG - 4 && x >= 3 && x <= SG - 4) {
#pragma unroll
      for (int ky = 0; ky < 7; ++ky)
#pragma unroll
        for (int kx = 0; kx < 7; ++kx) {
          float v = h[(size_t)(1 + (y + ky - 3) * SG + (x + kx - 3)) * DD + c];
          a7 = fmaf(v, wl[(ky * 7 + kx) * 256 + t], a7);
          if (ky >= 1 && ky <= 5 && kx >= 1 && kx <= 5)
            a5 = fmaf(v, wl[(49 + (ky - 1) * 5 + (kx - 1)) * 256 + t], a5);
          if (ky >= 2 && ky <= 4 && kx >= 2 && kx <= 4)
            a3 = fmaf(v, wl[(74 + (ky - 2) * 3 + (kx - 2)) * 256 + t], a3);
        }
    } else {
#pragma unroll
      for (int ky = 0; ky < 7; ++ky) {
        int yy = y + ky - 3;
        bool oky = (yy >= 0 && yy < SG);
#pragma unroll
        for (int kx = 0; kx < 7; ++kx) {
          int xx = x + kx - 3;
          float v = (oky && xx >= 0 && xx < SG)
                        ? h[(size_t)(1 + yy * SG + xx) * DD + c] : 0.f;
          a7 = fmaf(v, wl[(ky * 7 + kx) * 256 + t], a7);
          if (ky >= 1 && ky <= 5 && kx >= 1 && kx <= 5)
            a5 = fmaf(v, wl[(49 + (ky - 1) * 5 + (kx - 1)) * 256 + t], a5);
          if (ky >= 2 && ky <= 4 && kx >= 2 && kx <= 4)
            a3 = fmaf(v, wl[(74 + (ky - 2) * 3 + (kx - 2)) * 256 + t], a3);
        }
      }
    }
    tmp[(size_t)p * DD + c] = h[(size_t)(1 + p) * DD + c] + bsum + a7 + a5 + a3;
  }
}

// ---------------- final: LN(row0) -> fc2 -> softmax/argmax -> 5 outputs ----------------
__global__ __launch_bounds__(256) void final_kernel(
    const float* __restrict__ h, const float* __restrict__ g, const float* __restrict__ b,
    const float* __restrict__ w, const float* __restrict__ bias, float* __restrict__ out)
{
  __shared__ float red[256];
  int t = threadIdx.x;
  float v0 = h[t], v1 = h[t + 256];
  red[t] = v0 + v1;
  __syncthreads();
  for (int s = 128; s > 0; s >>= 1) { if (t < s) red[t] += red[t + s]; __syncthreads(); }
  float mu = red[0] * (1.f / 512.f);
  __syncthreads();
  float d0 = v0 - mu, d1 = v1 - mu;
  red[t] = d0 * d0 + d1 * d1;
  __syncthreads();
  for (int s = 128; s > 0; s >>= 1) { if (t < s) red[t] += red[t + s]; __syncthreads(); }
  float rs = rsqrtf(red[0] * (1.f / 512.f) + 1e-5f);
  __syncthreads();
  float x0 = d0 * rs * g[t] + b[t];
  float x1 = d1 * rs * g[t + 256] + b[t + 256];
  red[t] = x0 * w[t * 2] + x1 * w[(t + 256) * 2];
  __syncthreads();
  for (int s = 128; s > 0; s >>= 1) { if (t < s) red[t] += red[t + s]; __syncthreads(); }
  float l0 = red[0] + bias[0];
  __syncthreads();
  red[t] = x0 * w[t * 2 + 1] + x1 * w[(t + 256) * 2 + 1];
  __syncthreads();
  for (int s = 128; s > 0; s >>= 1) { if (t < s) red[t] += red[t + s]; __syncthreads(); }
  float l1 = red[0] + bias[1];
  if (t == 0) {
    out[0] = l0; out[1] = l1;
    float mx = fmaxf(l0, l1);
    float e0 = __expf(l0 - mx), e1 = __expf(l1 - mx);
    float inv = 1.f / (e0 + e1);
    out[2] = e0 * inv; out[3] = e1 * inv;
    out[4] = (l1 > l0) ? 1.f : 0.f;
  }
}

extern "C" void kernel_launch(void* const* d_in, const int* in_sizes, int n_in,
                              void* d_out, int out_size, void* d_ws, size_t ws_size,
                              hipStream_t stream)
{
  const float* data   = (const float*)d_in[0];
  const float* fc1_w  = (const float*)d_in[1];
  const float* fc1_b  = (const float*)d_in[2];
  const float* cls    = (const float*)d_in[3];
  const float* l1_g   = (const float*)d_in[4];
  const float* l1_b   = (const float*)d_in[5];
  const float* l1_qkv = (const float*)d_in[6];
  const float* l1_ow  = (const float*)d_in[7];
  const float* l1_ob  = (const float*)d_in[8];
  const float* l1_rw  = (const float*)d_in[9];
  const float* w7     = (const float*)d_in[10];
  const float* b7     = (const float*)d_in[11];
  const float* w5     = (const float*)d_in[12];
  const float* b5     = (const float*)d_in[13];
  const float* w3     = (const float*)d_in[14];
  const float* b3     = (const float*)d_in[15];
  const float* l2_g   = (const float*)d_in[16];
  const float* l2_b   = (const float*)d_in[17];
  const float* l2_qkv = (const float*)d_in[18];
  const float* l2_ow  = (const float*)d_in[19];
  const float* l2_ob  = (const float*)d_in[20];
  const float* l2_rw  = (const float*)d_in[21];
  const float* ng     = (const float*)d_in[22];
  const float* nb     = (const float*)d_in[23];
  const float* fc2_w  = (const float*)d_in[24];
  const float* fc2_b  = (const float*)d_in[25];
  float* out = (float*)d_out;

  float* ws   = (float*)d_ws;
  float* h    = ws;
  float* xn   = h    + (size_t)16384 * 512;
  float* qkv  = xn   + (size_t)16384 * 512;
  float* attn = qkv  + (size_t)16384 * 1536;
  float* ql   = attn + (size_t)16384 * 512;
  float* kl   = ql   + 256 * 512;
  float* a2b  = kl   + 256 * 512;
  float* z0   = a2b  + 8 * 256 * 256;
  float* z1   = z0   + 8 * 256 * 256;
  float* xzb  = z1   + 8 * 256 * 256;
  float* tb   = xzb  + 8 * 256 * 256;
  float* ub   = tb   + 8 * 256 * 256;
  float* a3v  = ub   + 8 * 256 * 256;
  float* w2   = a3v  + 8 * 256 * 64;
  float* pacc = w2   + 8 * 256 * 64;           // (unused region kept for layout)
  float* pms  = pacc + (size_t)8 * 32 * 256 * 64;   // den partials (8*64*256 floats fit here)
  float* red  = pms  + (size_t)8 * 32 * 256 * 2;
  float* wtb  = red  + 32;                       // 83*512 floats

  // a3v MFMA partial buffers: numerators alias xn (dead between qkv-GEMM and next ln_pad)
  float* a3v_pacc = xn;    // 8*CHK*256*64 = 8.39M floats == size of xn exactly
  float* a3v_den  = pms;   // 8*CHK*256   = 131072 floats == old pms size exactly

  // fc1 + relu into h rows 1..16000, then cls + duplicated rows
  gemm128<<<dim3(4, 125), 256, 0, stream>>>(data, 1024, fc1_w, 512, h + 512, 512,
                                            16000, 1024, 1, fc1_b);
  assemble_kernel<<<260, 256, 0, stream>>>(h, cls);
  wtrans_kernel<<<2, 256, 0, stream>>>(w7, w5, w3, wtb);

  for (int layer = 0; layer < 2; ++layer) {
    const float* gg = layer ? l2_g   : l1_g;
    const float* bb = layer ? l2_b   : l1_b;
    const float* qw = layer ? l2_qkv : l1_qkv;
    const float* ow = layer ? l2_ow  : l1_ow;
    const float* ob = layer ? l2_ob  : l1_ob;
    const float* rw = layer ? l2_rw  : l1_rw;

    ln_pad_kernel<<<16384, 256, 0, stream>>>(h, xn, gg, bb);
    gemm128<<<dim3(12, 128), 256, 0, stream>>>(xn, 512, qw, 1536, qkv, 1536,
                                               16384, 512, 2, nullptr);
    landmark_kernel<<<dim3(256, 4), 256, 0, stream>>>(qkv, ql, kl);
    a2_kernel<<<dim3(8, 256), 256, 0, stream>>>(ql, kl, a2b);
    pinv_red1<<<8, 256, 0, stream>>>(a2b, red);
    pinv_red2<<<1, 1, 0, stream>>>(red);
    pinv_init<<<dim3(8, 256), 256, 0, stream>>>(a2b, red, z0);
    float* zc = z0; float* zn = z1;
    for (int it = 0; it < 6; ++it) {
      mmb_kernel<<<dim3(4, 4, 8), 256, 0, stream>>>(a2b, zc, xzb, 256, 1.f);
      axpbi_kernel<<<dim3(8, 256), 256, 0, stream>>>(xzb, tb, -1.f, 7.f);
      mmb_kernel<<<dim3(4, 4, 8), 256, 0, stream>>>(xzb, tb, ub, 256, 1.f);
      axpbi_kernel<<<dim3(8, 256), 256, 0, stream>>>(ub, tb, -1.f, 15.f);
      mmb_kernel<<<dim3(4, 4, 8), 256, 0, stream>>>(xzb, tb, ub, 256, 1.f);
      axpbi_kernel<<<dim3(8, 256), 256, 0, stream>>>(ub, tb, -1.f, 13.f);
      mmb_kernel<<<dim3(4, 4, 8), 256, 0, stream>>>(zc, tb, zn, 256, 0.25f);
      float* sw = zc; zc = zn; zn = sw;
    }
    a3v_mfma<<<dim3(8, CHK), 256, 0, stream>>>(qkv, ql, a3v_pacc, a3v_den);
    a3v_merge_kernel<<<dim3(8, 256), 64, 0, stream>>>(a3v_pacc, a3v_den, a3v);
    mmb_kernel<<<dim3(1, 4, 8), 256, 0, stream>>>(zc, a3v, w2, 64, 1.f);
    a1_kernel<<<dim3(8, 64), 256, 0, stream>>>(qkv, kl, w2, attn);
    resconv_kernel<<<dim3(16384, 2), 256, 0, stream>>>(qkv, rw, attn);
    gemm128<<<dim3(4, 127), 256, 0, stream>>>(attn + (size_t)254 * 512, 512, ow, 512,
                                              h, 512, 16130, 512, 3, ob);
    if (layer == 0) {
      ppeg_kernel<<<dim3((NPIX + 63) / 64, 2), 256, 0, stream>>>(h, qkv, wtb, b7, b5, b3);
      hipMemcpyAsync(h + 512, qkv, (size_t)16129 * 512 * 4,
                     hipMemcpyDeviceToDevice, stream);
    }
  }
  final_kernel<<<1, 256, 0, stream>>>(h, ng, nb, fc2_w, fc2_b, out);
}

// Round 5
// 3090.278 us; speedup vs baseline: 1.8847x; 1.0016x over previous
//
#include <hip/hip_runtime.h>
#include <math.h>

#define NPAD   16384
#define PADR   254
#define NTOK   16130
#define NPIX   16129
#define SG     127
#define DD     512
#define NH     8
#define CHK    64          // key-chunks per head for a3v

typedef __attribute__((ext_vector_type(8))) short bf16x8;
typedef __attribute__((ext_vector_type(4))) float f32x4;

__device__ __forceinline__ ushort f2bf(float f) {
  uint u = __float_as_uint(f);
  u = (u + 0x7fffu + ((u >> 16) & 1u)) >> 16;
  return (ushort)u;
}

// ---------------- fp32 GEMM, 128x128 tile, 256 threads, 8x8/thread ----------------
// mode 0: C = acc ; mode 1: C = relu(acc+bias) ; mode 2: C = acc*(col<512?0.125:1)
// mode 3: C += acc + bias
__global__ __launch_bounds__(256) void gemm128(
    const float* __restrict__ A, int lda,
    const float* __restrict__ B, int ldb,
    float* __restrict__ C, int ldc,
    int M, int K, int mode, const float* __restrict__ bias)
{
  __shared__ float As[16][132];
  __shared__ float Bs[16][132];
  const int tid = threadIdx.x;
  const int tx = tid & 15, ty = tid >> 4;
  const int m0 = blockIdx.y * 128;
  const int n0 = blockIdx.x * 128;
  float acc[8][8];
#pragma unroll
  for (int i = 0; i < 8; ++i)
#pragma unroll
    for (int j = 0; j < 8; ++j) acc[i][j] = 0.f;

  for (int k0 = 0; k0 < K; k0 += 16) {
#pragma unroll
    for (int l = 0; l < 2; ++l) {
      int idx = tid + l * 256;
      int row = idx >> 2;
      int k4  = (idx & 3) << 2;
      float4 v = make_float4(0.f, 0.f, 0.f, 0.f);
      int gr = m0 + row;
      if (gr < M) v = *(const float4*)(A + (size_t)gr * lda + k0 + k4);
      As[k4 + 0][row] = v.x;
      As[k4 + 1][row] = v.y;
      As[k4 + 2][row] = v.z;
      As[k4 + 3][row] = v.w;
    }
#pragma unroll
    for (int l = 0; l < 2; ++l) {
      int idx = tid + l * 256;
      int row = idx >> 5;
      int c4  = (idx & 31) << 2;
      *(float4*)&Bs[row][c4] = *(const float4*)(B + (size_t)(k0 + row) * ldb + n0 + c4);
    }
    __syncthreads();
#pragma unroll
    for (int k = 0; k < 16; ++k) {
      float a[8], b[8];
      *(float4*)&a[0] = *(const float4*)&As[k][ty * 4];
      *(float4*)&a[4] = *(const float4*)&As[k][64 + ty * 4];
      *(float4*)&b[0] = *(const float4*)&Bs[k][tx * 4];
      *(float4*)&b[4] = *(const float4*)&Bs[k][64 + tx * 4];
#pragma unroll
      for (int i = 0; i < 8; ++i)
#pragma unroll
        for (int j = 0; j < 8; ++j) acc[i][j] = fmaf(a[i], b[j], acc[i][j]);
    }
    __syncthreads();
  }
#pragma unroll
  for (int i = 0; i < 8; ++i) {
    int rloc = (i < 4) ? (ty * 4 + i) : (64 + ty * 4 + (i - 4));
    int row = m0 + rloc;
    if (row >= M) continue;
#pragma unroll
    for (int jh = 0; jh < 2; ++jh) {
      int col = n0 + jh * 64 + tx * 4;
      float* cp = C + (size_t)row * ldc + col;
      float4 r;
      r.x = acc[i][jh*4+0]; r.y = acc[i][jh*4+1];
      r.z = acc[i][jh*4+2]; r.w = acc[i][jh*4+3];
      if (mode == 1) {
        float4 bb = *(const float4*)(bias + col);
        r.x = fmaxf(r.x + bb.x, 0.f); r.y = fmaxf(r.y + bb.y, 0.f);
        r.z = fmaxf(r.z + bb.z, 0.f); r.w = fmaxf(r.w + bb.w, 0.f);
      } else if (mode == 2) {
        float s = (col < 512) ? 0.125f : 1.f;
        r.x *= s; r.y *= s; r.z *= s; r.w *= s;
      } else if (mode == 3) {
        float4 bb = *(const float4*)(bias + col);
        float4 o  = *(const float4*)cp;
        r.x += o.x + bb.x; r.y += o.y + bb.y;
        r.z += o.z + bb.z; r.w += o.w + bb.w;
      }
      *(float4*)cp = r;
    }
  }
}

// ---------------- assemble: h[0]=cls, h[16001+i]=h[1+i] (i<129) ----------------
__global__ __launch_bounds__(256) void assemble_kernel(float* __restrict__ h,
                                                       const float* __restrict__ cls)
{
  int idx = blockIdx.x * 256 + threadIdx.x;   // 260*256 = 66560 = 512 + 129*512
  if (idx < 512) { h[idx] = cls[idx]; return; }
  idx -= 512;
  int i = idx >> 9, c = idx & 511;
  h[(size_t)(16001 + i) * DD + c] = h[(size_t)(1 + i) * DD + c];
}

// ---------------- LayerNorm rows of h -> xn (front-padded, rows<PADR zeroed) ----------------
__global__ __launch_bounds__(256) void ln_pad_kernel(
    const float* __restrict__ h, float* __restrict__ xn,
    const float* __restrict__ g, const float* __restrict__ b)
{
  int row = blockIdx.x;        // 0..16383
  int t = threadIdx.x;
  if (row < PADR) {
    xn[(size_t)row * DD + t] = 0.f;
    xn[(size_t)row * DD + t + 256] = 0.f;
    return;
  }
  const float* x = h + (size_t)(row - PADR) * DD;
  __shared__ float red[256];
  float v0 = x[t], v1 = x[t + 256];
  red[t] = v0 + v1;
  __syncthreads();
  for (int s = 128; s > 0; s >>= 1) { if (t < s) red[t] += red[t + s]; __syncthreads(); }
  float mu = red[0] * (1.f / 512.f);
  __syncthreads();
  float d0 = v0 - mu, d1 = v1 - mu;
  red[t] = d0 * d0 + d1 * d1;
  __syncthreads();
  for (int s = 128; s > 0; s >>= 1) { if (t < s) red[t] += red[t + s]; __syncthreads(); }
  float rs = rsqrtf(red[0] * (1.f / 512.f) + 1e-5f);
  float* o = xn + (size_t)row * DD;
  o[t]       = d0 * rs * g[t] + b[t];
  o[t + 256] = d1 * rs * g[t + 256] + b[t + 256];
}

// ---------------- landmarks: ql/kl[i][c] = mean_j qkv[(i*64+j)][c(,+512)] ----------------
__global__ __launch_bounds__(256) void landmark_kernel(
    const float* __restrict__ qkv, float* __restrict__ ql, float* __restrict__ kl)
{
  int i = blockIdx.x;                 // landmark 0..255
  int c = blockIdx.y * 256 + threadIdx.x;   // 0..1023
  const float* p = qkv + (size_t)(i * 64) * 1536 + c;
  float s = 0.f;
  for (int j = 0; j < 64; ++j) s += p[(size_t)j * 1536];
  s *= (1.f / 64.f);
  if (c < 512) ql[(size_t)i * 512 + c] = s;
  else         kl[(size_t)i * 512 + (c - 512)] = s;
}

// ---------------- a2 = softmax(ql . kl^T) per head ----------------
__global__ __launch_bounds__(256) void a2_kernel(
    const float* __restrict__ ql, const float* __restrict__ kl, float* __restrict__ a2)
{
  int h_ = blockIdx.x, i = blockIdx.y;
  int t = threadIdx.x;
  __shared__ float q[64];
  __shared__ float red[256];
  if (t < 64) q[t] = ql[(size_t)i * 512 + h_ * 64 + t];
  __syncthreads();
  const float* kr = kl + (size_t)t * 512 + h_ * 64;
  float s = 0.f;
#pragma unroll
  for (int d = 0; d < 64; ++d) s = fmaf(q[d], kr[d], s);
  red[t] = s;
  __syncthreads();
  for (int st = 128; st > 0; st >>= 1) { if (t < st) red[t] = fmaxf(red[t], red[t + st]); __syncthreads(); }
  float mx = red[0];
  __syncthreads();
  float e = __expf(s - mx);
  red[t] = e;
  __syncthreads();
  for (int st = 128; st > 0; st >>= 1) { if (t < st) red[t] += red[t + st]; __syncthreads(); }
  a2[((size_t)h_ * 256 + i) * 256 + t] = e / red[0];
}

// ---------------- pinv init reductions ----------------
__global__ __launch_bounds__(256) void pinv_red1(const float* __restrict__ a2, float* __restrict__ red)
{
  int h_ = blockIdx.x, t = threadIdx.x;
  const float* X = a2 + (size_t)h_ * 65536;
  float rs = 0.f, cs = 0.f;
  for (int j = 0; j < 256; ++j) rs += fabsf(X[(size_t)t * 256 + j]);
  for (int i = 0; i < 256; ++i) cs += fabsf(X[(size_t)i * 256 + t]);
  __shared__ float r1[256], r2[256];
  r1[t] = rs; r2[t] = cs;
  __syncthreads();
  for (int s = 128; s > 0; s >>= 1) {
    if (t < s) { r1[t] = fmaxf(r1[t], r1[t + s]); r2[t] = fmaxf(r2[t], r2[t + s]); }
    __syncthreads();
  }
  if (t == 0) { red[h_ * 2] = r1[0]; red[h_ * 2 + 1] = r2[0]; }
}
__global__ void pinv_red2(float* __restrict__ red)
{
  float mr = 0.f, mc = 0.f;
  for (int h_ = 0; h_ < 8; ++h_) { mr = fmaxf(mr, red[h_ * 2]); mc = fmaxf(mc, red[h_ * 2 + 1]); }
  red[16] = 1.f / (mr * mc);
}
__global__ __launch_bounds__(256) void pinv_init(
    const float* __restrict__ a2, const float* __restrict__ red, float* __restrict__ z)
{
  int h_ = blockIdx.x, i = blockIdx.y, j = threadIdx.x;
  float inv = red[16];
  z[((size_t)h_ * 256 + i) * 256 + j] = a2[((size_t)h_ * 256 + j) * 256 + i] * inv;
}

// ---------------- y = alpha*x + beta*I (batched 8x256x256) ----------------
__global__ __launch_bounds__(256) void axpbi_kernel(
    const float* __restrict__ x, float* __restrict__ y, float alpha, float beta)
{
  int h_ = blockIdx.x, i = blockIdx.y, j = threadIdx.x;
  size_t idx = ((size_t)h_ * 256 + i) * 256 + j;
  y[idx] = alpha * x[idx] + ((i == j) ? beta : 0.f);
}

// ---------------- batched matmul per head: C = alpha*(A @ B), A 256x256, B 256xN ----------------
__global__ __launch_bounds__(256) void mmb_kernel(
    const float* __restrict__ A, const float* __restrict__ B, float* __restrict__ C,
    int N, float alpha)
{
  int h_ = blockIdx.z;
  const float* Ah = A + (size_t)h_ * 256 * 256;
  const float* Bh = B + (size_t)h_ * 256 * N;
  float* Ch = C + (size_t)h_ * 256 * N;
  int m0 = blockIdx.y * 64, n0 = blockIdx.x * 64;
  __shared__ float As[16][68];
  __shared__ float Bs[16][68];
  int tid = threadIdx.x, tx = tid & 15, ty = tid >> 4;
  float acc[4][4];
#pragma unroll
  for (int i = 0; i < 4; ++i)
#pragma unroll
    for (int j = 0; j < 4; ++j) acc[i][j] = 0.f;
  for (int k0 = 0; k0 < 256; k0 += 16) {
    {
      int row = tid >> 2, k4 = (tid & 3) << 2;
      float4 v = *(const float4*)(Ah + (size_t)(m0 + row) * 256 + k0 + k4);
      As[k4 + 0][row] = v.x; As[k4 + 1][row] = v.y;
      As[k4 + 2][row] = v.z; As[k4 + 3][row] = v.w;
    }
    {
      int row = tid >> 4, c4 = (tid & 15) << 2;
      *(float4*)&Bs[row][c4] = *(const float4*)(Bh + (size_t)(k0 + row) * N + n0 + c4);
    }
    __syncthreads();
#pragma unroll
    for (int k = 0; k < 16; ++k) {
      float a[4], b[4];
      *(float4*)a = *(const float4*)&As[k][ty * 4];
      *(float4*)b = *(const float4*)&Bs[k][tx * 4];
#pragma unroll
      for (int i = 0; i < 4; ++i)
#pragma unroll
        for (int j = 0; j < 4; ++j) acc[i][j] = fmaf(a[i], b[j], acc[i][j]);
    }
    __syncthreads();
  }
#pragma unroll
  for (int i = 0; i < 4; ++i) {
    float4 r;
    r.x = alpha * acc[i][0]; r.y = alpha * acc[i][1];
    r.z = alpha * acc[i][2]; r.w = alpha * acc[i][3];
    *(float4*)(Ch + (size_t)(m0 + ty * 4 + i) * N + n0 + tx * 4) = r;
  }
}

// ---------------- a3@v partials via bf16 MFMA flash (no-max exp, ones-column den) ----------
// grid (8 heads, CHK chunks), 256 threads = 4 waves; wave w owns landmark rows 64w..64w+63.
// S = ql@K^T in fp32 via mfma; P = exp(S) (scores bounded |S|<~1, no max needed);
// O_ext = P @ [V | 1] gives numerator cols 0..63 and denominator at col 64.
// Partials are plain sums across chunks (no LSE merge).
__global__ __launch_bounds__(256) void a3v_mfma(
    const float* __restrict__ qkv, const float* __restrict__ ql,
    float* __restrict__ pacc, float* __restrict__ den)
{
  const int h_ = blockIdx.x;
  const int ch = blockIdx.y;
  const int t  = threadIdx.x;
  const int w  = t >> 6;
  const int l  = t & 63;
  const int lr = l & 15;
  const int lg = l >> 4;

  __shared__ __align__(16) ushort kls[64 * 64];     // K tile [j][d] bf16, 16B-block XOR swizzle
  __shared__ __align__(16) ushort vls[80 * 64];     // V^T tile [d][j] (+16 ones/zero rows)
  __shared__ __align__(16) ushort pls[4][64 * 64];  // per-wave P [i][j]

  // Q A-fragments: row = 64w + rt*16 + lr, k(d) = dc*32 + lg*8 + e
  bf16x8 qf[4][2];
#pragma unroll
  for (int rt = 0; rt < 4; ++rt)
#pragma unroll
    for (int dc = 0; dc < 2; ++dc) {
      const float* p = ql + (size_t)(64 * w + rt * 16 + lr) * 512 + h_ * 64 + dc * 32 + lg * 8;
      float4 f0 = *(const float4*)p;
      float4 f1 = *(const float4*)(p + 4);
      bf16x8 v;
      v[0] = f2bf(f0.x); v[1] = f2bf(f0.y); v[2] = f2bf(f0.z); v[3] = f2bf(f0.w);
      v[4] = f2bf(f1.x); v[5] = f2bf(f1.y); v[6] = f2bf(f1.z); v[7] = f2bf(f1.w);
      qf[rt][dc] = v;
    }

  // ones rows of VT (row 64 = 1.0, rows 65..79 = 0), written once
  if (t < 128) {
    int rr = t >> 3, cb = t & 7;
    ushort val = (rr == 0) ? (ushort)0x3f80 : (ushort)0;
    bf16x8 vv;
#pragma unroll
    for (int k = 0; k < 8; ++k) vv[k] = (short)val;
    *(bf16x8*)(vls + (64 + rr) * 64 + ((cb ^ (rr & 7)) << 3)) = vv;
  }

  f32x4 acc[4][5];
#pragma unroll
  for (int rt = 0; rt < 4; ++rt)
#pragma unroll
    for (int dt = 0; dt < 5; ++dt) acc[rt][dt] = (f32x4){0.f, 0.f, 0.f, 0.f};

  const int j0base = ch * 256;
  for (int jt = 0; jt < 4; ++jt) {
    const int j0 = j0base + jt * 64;
    __syncthreads();
    // stage K tile: thread -> (row r, 16-float block db)
    {
      int r = t >> 2, db = t & 3;
      const float* src = qkv + (size_t)(j0 + r) * 1536 + 512 + h_ * 64 + db * 16;
      float4 g0 = *(const float4*)(src + 0);
      float4 g1 = *(const float4*)(src + 4);
      float4 g2 = *(const float4*)(src + 8);
      float4 g3 = *(const float4*)(src + 12);
      bf16x8 e0, e1;
      e0[0] = f2bf(g0.x); e0[1] = f2bf(g0.y); e0[2] = f2bf(g0.z); e0[3] = f2bf(g0.w);
      e0[4] = f2bf(g1.x); e0[5] = f2bf(g1.y); e0[6] = f2bf(g1.z); e0[7] = f2bf(g1.w);
      e1[0] = f2bf(g2.x); e1[1] = f2bf(g2.y); e1[2] = f2bf(g2.z); e1[3] = f2bf(g2.w);
      e1[4] = f2bf(g3.x); e1[5] = f2bf(g3.y); e1[6] = f2bf(g3.z); e1[7] = f2bf(g3.w);
      ushort* base = kls + r * 64;
      *(bf16x8*)(base + (((db * 2 + 0) ^ (r & 7)) << 3)) = e0;
      *(bf16x8*)(base + (((db * 2 + 1) ^ (r & 7)) << 3)) = e1;
    }
    // stage V^T tile: thread -> (d = t&63, two 8-key blocks)
    {
      int d = t & 63, jg = t >> 6;
#pragma unroll
      for (int half = 0; half < 2; ++half) {
        int jb = jg + half * 4;
        bf16x8 e;
#pragma unroll
        for (int jj = 0; jj < 8; ++jj)
          e[jj] = f2bf(qkv[(size_t)(j0 + jb * 8 + jj) * 1536 + 1024 + h_ * 64 + d]);
        *(bf16x8*)(vls + d * 64 + ((jb ^ (d & 7)) << 3)) = e;
      }
    }
    __syncthreads();

    // QK^T (fp32 D) -> exp -> P (bf16, per-wave LDS)
    ushort* pw = pls[w];
#pragma unroll
    for (int sjt = 0; sjt < 4; ++sjt) {
      const int krow = sjt * 16 + lr;
      bf16x8 kf0 = *(const bf16x8*)(kls + krow * 64 + (((0 * 4 + lg) ^ (lr & 7)) << 3));
      bf16x8 kf1 = *(const bf16x8*)(kls + krow * 64 + (((1 * 4 + lg) ^ (lr & 7)) << 3));
#pragma unroll
      for (int rt = 0; rt < 4; ++rt) {
        f32x4 s = (f32x4){0.f, 0.f, 0.f, 0.f};
        s = __builtin_amdgcn_mfma_f32_16x16x32_bf16(qf[rt][0], kf0, s, 0, 0, 0);
        s = __builtin_amdgcn_mfma_f32_16x16x32_bf16(qf[rt][1], kf1, s, 0, 0, 0);
#pragma unroll
        for (int r = 0; r < 4; ++r) {
          int i  = rt * 16 + lg * 4 + r;
          int jj = sjt * 16 + lr;
          pw[i * 64 + ((((jj >> 3) ^ (i & 7)) << 3)) + (jj & 7)] = (short)f2bf(__expf(s[r]));
        }
      }
    }
    // load P A-fragments (same-wave LDS RAW: DS pipe is in-order per wave)
    bf16x8 pf[4][2];
#pragma unroll
    for (int rt = 0; rt < 4; ++rt)
#pragma unroll
      for (int jc = 0; jc < 2; ++jc)
        pf[rt][jc] = *(const bf16x8*)(pw + (rt * 16 + lr) * 64 + (((jc * 4 + lg) ^ (lr & 7)) << 3));
    // PV: acc[rt][dt] += P . [V|1]
#pragma unroll
    for (int dt = 0; dt < 5; ++dt) {
      const int vrow = dt * 16 + lr;
      bf16x8 vf0 = *(const bf16x8*)(vls + vrow * 64 + (((0 * 4 + lg) ^ (lr & 7)) << 3));
      bf16x8 vf1 = *(const bf16x8*)(vls + vrow * 64 + (((1 * 4 + lg) ^ (lr & 7)) << 3));
#pragma unroll
      for (int rt = 0; rt < 4; ++rt) {
        acc[rt][dt] = __builtin_amdgcn_mfma_f32_16x16x32_bf16(pf[rt][0], vf0, acc[rt][dt], 0, 0, 0);
        acc[rt][dt] = __builtin_amdgcn_mfma_f32_16x16x32_bf16(pf[rt][1], vf1, acc[rt][dt], 0, 0, 0);
      }
    }
  }

  // write partials: rows i = 64w + rt*16 + lg*4 + r ; cols dt*16 + lr ; den = col 64
  const size_t pbase = (size_t)(h_ * CHK + ch) * 256;
#pragma unroll
  for (int rt = 0; rt < 4; ++rt) {
    int i = 64 * w + rt * 16 + lg * 4;
#pragma unroll
    for (int dt = 0; dt < 4; ++dt)
#pragma unroll
      for (int r = 0; r < 4; ++r)
        pacc[(pbase + i + r) * 64 + dt * 16 + lr] = acc[rt][dt][r];
    if (lr == 0) {
#pragma unroll
      for (int r = 0; r < 4; ++r)
        den[pbase + i + r] = acc[rt][4][r];
    }
  }
}

// ---------------- merge a3v partials (plain sums over CHK chunks) ----------------
__global__ __launch_bounds__(64) void a3v_merge_kernel(
    const float* __restrict__ pacc, const float* __restrict__ den, float* __restrict__ a3v)
{
  int h_ = blockIdx.x, i = blockIdx.y, d = threadIdx.x;
  float S = 0.f, o = 0.f;
  for (int c = 0; c < CHK; ++c) {
    size_t b = (size_t)(h_ * CHK + c) * 256 + i;
    o += pacc[b * 64 + d];
    S += den[b];
  }
  a3v[((size_t)h_ * 256 + i) * 64 + d] = o / S;
}

// ---------------- out = softmax(q . kl^T) @ w2, fused, grid (8, 64 row-blocks) ----------------
__global__ __launch_bounds__(256) void a1_kernel(
    const float* __restrict__ qkv, const float* __restrict__ kl,
    const float* __restrict__ w2, float* __restrict__ attn)
{
  int h_ = blockIdx.x;
  int r = blockIdx.y * 256 + threadIdx.x;
  int t = threadIdx.x;
  __shared__ float klt[128][64];
  __shared__ float wt[128][64];
  float qr[64];
#pragma unroll
  for (int d4 = 0; d4 < 16; ++d4)
    *(float4*)&qr[d4 * 4] = *(const float4*)(qkv + (size_t)r * 1536 + h_ * 64 + d4 * 4);
  float m = -1e30f, s = 0.f;
  float acc[64];
#pragma unroll
  for (int d = 0; d < 64; ++d) acc[d] = 0.f;
  for (int jh = 0; jh < 2; ++jh) {
    __syncthreads();
#pragma unroll
    for (int l = 0; l < 8; ++l) {
      int idx = t + l * 256;
      int rr = idx >> 4, c4 = (idx & 15) << 2;
      *(float4*)&klt[rr][c4] = *(const float4*)(kl + (size_t)(jh * 128 + rr) * 512 + h_ * 64 + c4);
      *(float4*)&wt[rr][c4]  = *(const float4*)(w2 + ((size_t)h_ * 256 + jh * 128 + rr) * 64 + c4);
    }
    __syncthreads();
    for (int j = 0; j < 128; ++j) {
      float sc = 0.f;
#pragma unroll
      for (int d4 = 0; d4 < 16; ++d4) {
        float4 kv = *(const float4*)&klt[j][d4 * 4];
        sc = fmaf(qr[d4*4+0], kv.x, sc); sc = fmaf(qr[d4*4+1], kv.y, sc);
        sc = fmaf(qr[d4*4+2], kv.z, sc); sc = fmaf(qr[d4*4+3], kv.w, sc);
      }
      if (sc <= m) {
        float p = __expf(sc - m);
        s += p;
#pragma unroll
        for (int d4 = 0; d4 < 16; ++d4) {
          float4 vv = *(const float4*)&wt[j][d4 * 4];
          acc[d4*4+0] = fmaf(p, vv.x, acc[d4*4+0]);
          acc[d4*4+1] = fmaf(p, vv.y, acc[d4*4+1]);
          acc[d4*4+2] = fmaf(p, vv.z, acc[d4*4+2]);
          acc[d4*4+3] = fmaf(p, vv.w, acc[d4*4+3]);
        }
      } else {
        float corr = __expf(m - sc);
        m = sc;
        s = fmaf(s, corr, 1.f);
#pragma unroll
        for (int d4 = 0; d4 < 16; ++d4) {
          float4 vv = *(const float4*)&wt[j][d4 * 4];
          acc[d4*4+0] = fmaf(acc[d4*4+0], corr, vv.x);
          acc[d4*4+1] = fmaf(acc[d4*4+1], corr, vv.y);
          acc[d4*4+2] = fmaf(acc[d4*4+2], corr, vv.z);
          acc[d4*4+3] = fmaf(acc[d4*4+3], corr, vv.w);
        }
      }
    }
  }
  float inv = 1.f / s;
  float* op = attn + (size_t)r * 512 + h_ * 64;
#pragma unroll
  for (int d4 = 0; d4 < 16; ++d4) {
    float4 o;
    o.x = acc[d4*4+0] * inv; o.y = acc[d4*4+1] * inv;
    o.z = acc[d4*4+2] * inv; o.w = acc[d4*4+3] * inv;
    *(float4*)(op + d4 * 4) = o;
  }
}

// ---------------- depthwise res conv over sequence (kernel 33), adds into attn ----------------
__global__ __launch_bounds__(256) void resconv_kernel(
    const float* __restrict__ qkv, const float* __restrict__ rw, float* __restrict__ attn)
{
  int r = blockIdx.x;
  int c = blockIdx.y * 256 + threadIdx.x;
  int h_ = c >> 6;
  float s = 0.f;
#pragma unroll
  for (int tp = 0; tp < 33; ++tp) {
    int rr = r + tp - 16;
    if (rr >= 0 && rr < NPAD)
      s = fmaf(qkv[(size_t)rr * 1536 + 1024 + c], rw[h_ * 33 + tp], s);
  }
  attn[(size_t)r * 512 + c] += s;
}

// ---------------- weight transpose: wt[k*512+c] for k in [0,83) ----------------
__global__ __launch_bounds__(256) void wtrans_kernel(
    const float* __restrict__ w7, const float* __restrict__ w5,
    const float* __restrict__ w3, float* __restrict__ wt)
{
  int c = blockIdx.x * 256 + threadIdx.x;   // 0..511
  for (int k = 0; k < 49; ++k) wt[(size_t)k * 512 + c]        = w7[(size_t)c * 49 + k];
  for (int k = 0; k < 25; ++k) wt[(size_t)(49 + k) * 512 + c] = w5[(size_t)c * 25 + k];
  for (int k = 0; k < 9;  ++k) wt[(size_t)(74 + k) * 512 + c] = w3[(size_t)c * 9 + k];
}

// ---------------- PPEG: weights staged in LDS (85KB), 256 ch x 64 px per block ----------
__global__ __launch_bounds__(256) void ppeg_kernel(
    const float* __restrict__ h, float* __restrict__ tmp,
    const float* __restrict__ wt,
    const float* __restrict__ b7, const float* __restrict__ b5,
    const float* __restrict__ b3)
{
  __shared__ float wl[83 * 256];           // 84,992 B
  const int t = threadIdx.x;
  const int c = blockIdx.y * 256 + t;
#pragma unroll
  for (int k = 0; k < 83; ++k)
    wl[k * 256 + t] = wt[(size_t)k * 512 + c];
  const float bsum = b7[c] + b5[c] + b3[c];
  __syncthreads();

  const int p0 = blockIdx.x * 64;
  for (int i = 0; i < 64; ++i) {
    int p = p0 + i;
    if (p >= NPIX) break;                  // uniform across block
    int y = p / SG, x = p - y * SG;
    float a7 = 0.f, a5 = 0.f, a3 = 0.f;
    if (y >= 3 && y <= SG - 4 && x >= 3 && x <= SG - 4) {
#pragma unroll
      for (int ky = 0; ky < 7; ++ky)
#pragma unroll
        for (int kx = 0; kx < 7; ++kx) {
          float v = h[(size_t)(1 + (y + ky - 3) * SG + (x + kx - 3)) * DD + c];
          a7 = fmaf(v, wl[(ky * 7 + kx) * 256 + t], a7);
          if (ky >= 1 && ky <= 5 && kx >= 1 && kx <= 5)
            a5 = fmaf(v, wl[(49 + (ky - 1) * 5 + (kx - 1)) * 256 + t], a5);
          if (ky >= 2 && ky <= 4 && kx >= 2 && kx <= 4)
            a3 = fmaf(v, wl[(74 + (ky - 2) * 3 + (kx - 2)) * 256 + t], a3);
        }
    } else {
#pragma unroll
      for (int ky = 0; ky < 7; ++ky) {
        int yy = y + ky - 3;
        bool oky = (yy >= 0 && yy < SG);
#pragma unroll
        for (int kx = 0; kx < 7; ++kx) {
          int xx = x + kx - 3;
          float v = (oky && xx >= 0 && xx < SG)
                        ? h[(size_t)(1 + yy * SG + xx) * DD + c] : 0.f;
          a7 = fmaf(v, wl[(ky * 7 + kx) * 256 + t], a7);
          if (ky >= 1 && ky <= 5 && kx >= 1 && kx <= 5)
            a5 = fmaf(v, wl[(49 + (ky - 1) * 5 + (kx - 1)) * 256 + t], a5);
          if (ky >= 2 && ky <= 4 && kx >= 2 && kx <= 4)
            a3 = fmaf(v, wl[(74 + (ky - 2) * 3 + (kx - 2)) * 256 + t], a3);
        }
      }
    }
    tmp[(size_t)p * DD + c] = h[(size_t)(1 + p) * DD + c] + bsum + a7 + a5 + a3;
  }
}

// ---------------- final: LN(row0) -> fc2 -> softmax/argmax -> 5 outputs ----------------
__global__ __launch_bounds__(256) void final_kernel(
    const float* __restrict__ h, const float* __restrict__ g, const float* __restrict__ b,
    const float* __restrict__ w, const float* __restrict__ bias, float* __restrict__ out)
{
  __shared__ float red[256];
  int t = threadIdx.x;
  float v0 = h[t], v1 = h[t + 256];
  red[t] = v0 + v1;
  __syncthreads();
  for (int s = 128; s > 0; s >>= 1) { if (t < s) red[t] += red[t + s]; __syncthreads(); }
  float mu = red[0] * (1.f / 512.f);
  __syncthreads();
  float d0 = v0 - mu, d1 = v1 - mu;
  red[t] = d0 * d0 + d1 * d1;
  __syncthreads();
  for (int s = 128; s > 0; s >>= 1) { if (t < s) red[t] += red[t + s]; __syncthreads(); }
  float rs = rsqrtf(red[0] * (1.f / 512.f) + 1e-5f);
  __syncthreads();
  float x0 = d0 * rs * g[t] + b[t];
  float x1 = d1 * rs * g[t + 256] + b[t + 256];
  red[t] = x0 * w[t * 2] + x1 * w[(t + 256) * 2];
  __syncthreads();
  for (int s = 128; s > 0; s >>= 1) { if (t < s) red[t] += red[t + s]; __syncthreads(); }
  float l0 = red[0] + bias[0];
  __syncthreads();
  red[t] = x0 * w[t * 2 + 1] + x1 * w[(t + 256) * 2 + 1];
  __syncthreads();
  for (int s = 128; s > 0; s >>= 1) { if (t < s) red[t] += red[t + s]; __syncthreads(); }
  float l1 = red[0] + bias[1];
  if (t == 0) {
    out[0] = l0; out[1] = l1;
    float mx = fmaxf(l0, l1);
    float e0 = __expf(l0 - mx), e1 = __expf(l1 - mx);
    float inv = 1.f / (e0 + e1);
    out[2] = e0 * inv; out[3] = e1 * inv;
    out[4] = (l1 > l0) ? 1.f : 0.f;
  }
}

extern "C" void kernel_launch(void* const* d_in, const int* in_sizes, int n_in,
                              void* d_out, int out_size, void* d_ws, size_t ws_size,
                              hipStream_t stream)
{
  const float* data   = (const float*)d_in[0];
  const float* fc1_w  = (const float*)d_in[1];
  const float* fc1_b  = (const float*)d_in[2];
  const float* cls    = (const float*)d_in[3];
  const float* l1_g   = (const float*)d_in[4];
  const float* l1_b   = (const float*)d_in[5];
  const float* l1_qkv = (const float*)d_in[6];
  const float* l1_ow  = (const float*)d_in[7];
  const float* l1_ob  = (const float*)d_in[8];
  const float* l1_rw  = (const float*)d_in[9];
  const float* w7     = (const float*)d_in[10];
  const float* b7     = (const float*)d_in[11];
  const float* w5     = (const float*)d_in[12];
  const float* b5     = (const float*)d_in[13];
  const float* w3     = (const float*)d_in[14];
  const float* b3     = (const float*)d_in[15];
  const float* l2_g   = (const float*)d_in[16];
  const float* l2_b   = (const float*)d_in[17];
  const float* l2_qkv = (const float*)d_in[18];
  const float* l2_ow  = (const float*)d_in[19];
  const float* l2_ob  = (const float*)d_in[20];
  const float* l2_rw  = (const float*)d_in[21];
  const float* ng     = (const float*)d_in[22];
  const float* nb     = (const float*)d_in[23];
  const float* fc2_w  = (const float*)d_in[24];
  const float* fc2_b  = (const float*)d_in[25];
  float* out = (float*)d_out;

  float* ws   = (float*)d_ws;
  float* h    = ws;
  float* xn   = h    + (size_t)16384 * 512;
  float* qkv  = xn   + (size_t)16384 * 512;
  float* attn = qkv  + (size_t)16384 * 1536;
  float* ql   = attn + (size_t)16384 * 512;
  float* kl   = ql   + 256 * 512;
  float* a2b  = kl   + 256 * 512;
  float* z0   = a2b  + 8 * 256 * 256;
  float* z1   = z0   + 8 * 256 * 256;
  float* xzb  = z1   + 8 * 256 * 256;
  float* tb   = xzb  + 8 * 256 * 256;
  float* ub   = tb   + 8 * 256 * 256;
  float* a3v  = ub   + 8 * 256 * 256;
  float* w2   = a3v  + 8 * 256 * 64;
  float* pacc = w2   + 8 * 256 * 64;           // (unused region kept for layout)
  float* pms  = pacc + (size_t)8 * 32 * 256 * 64;   // den partials (8*64*256 floats fit here)
  float* red  = pms  + (size_t)8 * 32 * 256 * 2;
  float* wtb  = red  + 32;                       // 83*512 floats

  // a3v MFMA partial buffers: numerators alias xn (dead between qkv-GEMM and next ln_pad)
  float* a3v_pacc = xn;    // 8*CHK*256*64 = 8.39M floats == size of xn exactly
  float* a3v_den  = pms;   // 8*CHK*256   = 131072 floats == old pms size exactly

  // fc1 + relu into h rows 1..16000, then cls + duplicated rows
  gemm128<<<dim3(4, 125), 256, 0, stream>>>(data, 1024, fc1_w, 512, h + 512, 512,
                                            16000, 1024, 1, fc1_b);
  assemble_kernel<<<260, 256, 0, stream>>>(h, cls);
  wtrans_kernel<<<2, 256, 0, stream>>>(w7, w5, w3, wtb);

  for (int layer = 0; layer < 2; ++layer) {
    const float* gg = layer ? l2_g   : l1_g;
    const float* bb = layer ? l2_b   : l1_b;
    const float* qw = layer ? l2_qkv : l1_qkv;
    const float* ow = layer ? l2_ow  : l1_ow;
    const float* ob = layer ? l2_ob  : l1_ob;
    const float* rw = layer ? l2_rw  : l1_rw;

    ln_pad_kernel<<<16384, 256, 0, stream>>>(h, xn, gg, bb);
    gemm128<<<dim3(12, 128), 256, 0, stream>>>(xn, 512, qw, 1536, qkv, 1536,
                                               16384, 512, 2, nullptr);
    landmark_kernel<<<dim3(256, 4), 256, 0, stream>>>(qkv, ql, kl);
    a2_kernel<<<dim3(8, 256), 256, 0, stream>>>(ql, kl, a2b);
    pinv_red1<<<8, 256, 0, stream>>>(a2b, red);
    pinv_red2<<<1, 1, 0, stream>>>(red);
    pinv_init<<<dim3(8, 256), 256, 0, stream>>>(a2b, red, z0);
    float* zc = z0; float* zn = z1;
    for (int it = 0; it < 6; ++it) {
      mmb_kernel<<<dim3(4, 4, 8), 256, 0, stream>>>(a2b, zc, xzb, 256, 1.f);
      axpbi_kernel<<<dim3(8, 256), 256, 0, stream>>>(xzb, tb, -1.f, 7.f);
      mmb_kernel<<<dim3(4, 4, 8), 256, 0, stream>>>(xzb, tb, ub, 256, 1.f);
      axpbi_kernel<<<dim3(8, 256), 256, 0, stream>>>(ub, tb, -1.f, 15.f);
      mmb_kernel<<<dim3(4, 4, 8), 256, 0, stream>>>(xzb, tb, ub, 256, 1.f);
      axpbi_kernel<<<dim3(8, 256), 256, 0, stream>>>(ub, tb, -1.f, 13.f);
      mmb_kernel<<<dim3(4, 4, 8), 256, 0, stream>>>(zc, tb, zn, 256, 0.25f);
      float* sw = zc; zc = zn; zn = sw;
    }
    a3v_mfma<<<dim3(8, CHK), 256, 0, stream>>>(qkv, ql, a3v_pacc, a3v_den);
    a3v_merge_kernel<<<dim3(8, 256), 64, 0, stream>>>(a3v_pacc, a3v_den, a3v);
    mmb_kernel<<<dim3(1, 4, 8), 256, 0, stream>>>(zc, a3v, w2, 64, 1.f);
    a1_kernel<<<dim3(8, 64), 256, 0, stream>>>(qkv, kl, w2, attn);
    resconv_kernel<<<dim3(16384, 2), 256, 0, stream>>>(qkv, rw, attn);
    gemm128<<<dim3(4, 127), 256, 0, stream>>>(attn + (size_t)254 * 512, 512, ow, 512,
                                              h, 512, 16130, 512, 3, ob);
    if (layer == 0) {
      ppeg_kernel<<<dim3((NPIX + 63) / 64, 2), 256, 0, stream>>>(h, qkv, wtb, b7, b5, b3);
      hipMemcpyAsync(h + 512, qkv, (size_t)16129 * 512 * 4,
                     hipMemcpyDeviceToDevice, stream);
    }
  }
  final_kernel<<<1, 256, 0, stream>>>(h, ng, nb, fc2_w, fc2_b, out);
}

// Round 6
// 2035.244 us; speedup vs baseline: 2.8617x; 1.5184x over previous
//
#include <hip/hip_runtime.h>
#include <math.h>

#define NPAD   16384
#define PADR   254
#define NTOK   16130
#define NPIX   16129
#define SG     127
#define DD     512
#define NH     8
#define CHK    64          // key-chunks per head for a3v

typedef __attribute__((ext_vector_type(8))) short bf16x8;
typedef __attribute__((ext_vector_type(4))) float f32x4;

__device__ __forceinline__ ushort f2bf(float f) {
  uint u = __float_as_uint(f);
  u = (u + 0x7fffu + ((u >> 16) & 1u)) >> 16;
  return (ushort)u;
}

// ---------------- weight transpose+cvt: src fp32 [K][N] -> dst bf16 [N][K] ----------------
__global__ __launch_bounds__(256) void wtrans_bf(
    const float* __restrict__ src, ushort* __restrict__ dst, int K, int N)
{
  __shared__ float tile[32][33];
  int tx = threadIdx.x & 31, ty = threadIdx.x >> 5;   // 32 x 8
#pragma unroll
  for (int i = 0; i < 4; ++i) {
    int k = blockIdx.y * 32 + ty + i * 8, n = blockIdx.x * 32 + tx;
    tile[ty + i * 8][tx] = src[(size_t)k * N + n];
  }
  __syncthreads();
#pragma unroll
  for (int i = 0; i < 4; ++i) {
    int n = blockIdx.x * 32 + ty + i * 8, k = blockIdx.y * 32 + tx;
    dst[(size_t)n * K + k] = f2bf(tile[tx][ty + i * 8]);
  }
}

// ---------------- bf16 MFMA GEMM: C fp32 = A_f32 @ Bt_bf16^T ----------------
// A [M][lda] fp32 (converted in staging), Bt [N][ldb=K] bf16 row-major (pre-transposed W).
// 128x128 tile, BK=64, 4 waves (2x2 of 64x64). mode 1: relu(acc+bias); 2: q-scale; 3: C+=acc+bias.
__global__ __launch_bounds__(256) void gemm_bt(
    const float* __restrict__ A, int lda,
    const ushort* __restrict__ Bt, int ldb,
    float* __restrict__ C, int ldc,
    int M, int K, int mode, const float* __restrict__ bias)
{
  const int t = threadIdx.x;
  const int w = t >> 6, l = t & 63, lr = l & 15, lg = l >> 4;
  const int wr = w >> 1, wc = w & 1;
  const int m0 = blockIdx.y * 128, n0 = blockIdx.x * 128;
  __shared__ __align__(16) ushort As[128 * 64];
  __shared__ __align__(16) ushort Bs[128 * 64];
  f32x4 acc[4][4];
#pragma unroll
  for (int i = 0; i < 4; ++i)
#pragma unroll
    for (int j = 0; j < 4; ++j) acc[i][j] = (f32x4){0.f, 0.f, 0.f, 0.f};

  for (int k0 = 0; k0 < K; k0 += 64) {
    __syncthreads();
    // stage A: 128 rows x 4 chunks of 16 floats = 512 tasks, 2/thread
#pragma unroll
    for (int i = 0; i < 2; ++i) {
      int id = t + i * 256;
      int r = id >> 2, db = id & 3;
      const float* src = A + (size_t)(m0 + r) * lda + k0 + db * 16;
      float4 g0 = *(const float4*)(src + 0);
      float4 g1 = *(const float4*)(src + 4);
      float4 g2 = *(const float4*)(src + 8);
      float4 g3 = *(const float4*)(src + 12);
      bf16x8 e0, e1;
      e0[0] = f2bf(g0.x); e0[1] = f2bf(g0.y); e0[2] = f2bf(g0.z); e0[3] = f2bf(g0.w);
      e0[4] = f2bf(g1.x); e0[5] = f2bf(g1.y); e0[6] = f2bf(g1.z); e0[7] = f2bf(g1.w);
      e1[0] = f2bf(g2.x); e1[1] = f2bf(g2.y); e1[2] = f2bf(g2.z); e1[3] = f2bf(g2.w);
      e1[4] = f2bf(g3.x); e1[5] = f2bf(g3.y); e1[6] = f2bf(g3.z); e1[7] = f2bf(g3.w);
      ushort* dst = As + r * 64;
      *(bf16x8*)(dst + (((db * 2 + 0) ^ (r & 7)) << 3)) = e0;
      *(bf16x8*)(dst + (((db * 2 + 1) ^ (r & 7)) << 3)) = e1;
    }
    // stage B (already bf16): 128 rows x 8 blocks = 1024 tasks, 4/thread
#pragma unroll
    for (int i = 0; i < 4; ++i) {
      int id = t + i * 256;
      int r = id >> 3, blk = id & 7;
      bf16x8 v = *(const bf16x8*)(Bt + (size_t)(n0 + r) * ldb + k0 + blk * 8);
      *(bf16x8*)(Bs + r * 64 + ((blk ^ (r & 7)) << 3)) = v;
    }
    __syncthreads();
    bf16x8 af[4][2], bfr[4][2];
#pragma unroll
    for (int rt = 0; rt < 4; ++rt) {
      int row = wr * 64 + rt * 16 + lr;
#pragma unroll
      for (int kc = 0; kc < 2; ++kc)
        af[rt][kc] = *(const bf16x8*)(As + row * 64 + (((kc * 4 + lg) ^ (row & 7)) << 3));
    }
#pragma unroll
    for (int nt = 0; nt < 4; ++nt) {
      int row = wc * 64 + nt * 16 + lr;
#pragma unroll
      for (int kc = 0; kc < 2; ++kc)
        bfr[nt][kc] = *(const bf16x8*)(Bs + row * 64 + (((kc * 4 + lg) ^ (row & 7)) << 3));
    }
#pragma unroll
    for (int rt = 0; rt < 4; ++rt)
#pragma unroll
      for (int nt = 0; nt < 4; ++nt) {
        acc[rt][nt] = __builtin_amdgcn_mfma_f32_16x16x32_bf16(af[rt][0], bfr[nt][0], acc[rt][nt], 0, 0, 0);
        acc[rt][nt] = __builtin_amdgcn_mfma_f32_16x16x32_bf16(af[rt][1], bfr[nt][1], acc[rt][nt], 0, 0, 0);
      }
  }
#pragma unroll
  for (int rt = 0; rt < 4; ++rt) {
#pragma unroll
    for (int r = 0; r < 4; ++r) {
      int gi = m0 + wr * 64 + rt * 16 + lg * 4 + r;
      if (gi >= M) continue;
#pragma unroll
      for (int nt = 0; nt < 4; ++nt) {
        int gj = n0 + wc * 64 + nt * 16 + lr;
        float d = acc[rt][nt][r];
        if (mode == 1) d = fmaxf(d + bias[gj], 0.f);
        else if (mode == 2) { if (gj < 512) d *= 0.125f; }
        else if (mode == 3) d += C[(size_t)gi * ldc + gj] + bias[gj];
        C[(size_t)gi * ldc + gj] = d;
      }
    }
  }
}

// ---------------- fused Newton-step matmul: D = A@B (bf16 MFMA), C = f(A[ij], D) ----------
// batched 8 heads of 256x256. B transposed during staging. modes:
// 0: C=D ; 1: C=7A-D ; 2: C=15A-D ; 3: C=0.25*(13A-D)
__global__ __launch_bounds__(256) void nmm_kernel(
    const float* __restrict__ A, const float* __restrict__ B,
    float* __restrict__ C, int mode)
{
  const int h_ = blockIdx.z;
  const int m0 = blockIdx.y * 64, n0 = blockIdx.x * 64;
  const float* Ah = A + (size_t)h_ * 65536;
  const float* Bh = B + (size_t)h_ * 65536;
  float* Ch = C + (size_t)h_ * 65536;
  const int t = threadIdx.x, w = t >> 6, l = t & 63, lr = l & 15, lg = l >> 4;
  __shared__ __align__(16) ushort Xs[64 * 64];
  __shared__ __align__(16) ushort Ys[64 * 64];
  f32x4 acc[4];
#pragma unroll
  for (int nt = 0; nt < 4; ++nt) acc[nt] = (f32x4){0.f, 0.f, 0.f, 0.f};

  for (int k0 = 0; k0 < 256; k0 += 64) {
    __syncthreads();
    // stage A rows (direct): 64 rows x 4 chunks of 16 -> 256 tasks, 1/thread
    {
      int r = t >> 2, db = t & 3;
      const float* src = Ah + (size_t)(m0 + r) * 256 + k0 + db * 16;
      float4 g0 = *(const float4*)(src + 0);
      float4 g1 = *(const float4*)(src + 4);
      float4 g2 = *(const float4*)(src + 8);
      float4 g3 = *(const float4*)(src + 12);
      bf16x8 e0, e1;
      e0[0] = f2bf(g0.x); e0[1] = f2bf(g0.y); e0[2] = f2bf(g0.z); e0[3] = f2bf(g0.w);
      e0[4] = f2bf(g1.x); e0[5] = f2bf(g1.y); e0[6] = f2bf(g1.z); e0[7] = f2bf(g1.w);
      e1[0] = f2bf(g2.x); e1[1] = f2bf(g2.y); e1[2] = f2bf(g2.z); e1[3] = f2bf(g2.w);
      e1[4] = f2bf(g3.x); e1[5] = f2bf(g3.y); e1[6] = f2bf(g3.z); e1[7] = f2bf(g3.w);
      ushort* dst = Xs + r * 64;
      *(bf16x8*)(dst + (((db * 2 + 0) ^ (r & 7)) << 3)) = e0;
      *(bf16x8*)(dst + (((db * 2 + 1) ^ (r & 7)) << 3)) = e1;
    }
    // stage B transposed: 64 k-rows x 16 float4 = 1024 tasks, 4/thread
#pragma unroll
    for (int i = 0; i < 4; ++i) {
      int id = t + i * 256;
      int k = id >> 4, q = id & 15;
      float4 v = *(const float4*)(Bh + (size_t)(k0 + k) * 256 + n0 + q * 4);
      int kb = k >> 3, ke = k & 7;
      Ys[(q * 4 + 0) * 64 + ((kb ^ ((q * 4 + 0) & 7)) << 3) + ke] = f2bf(v.x);
      Ys[(q * 4 + 1) * 64 + ((kb ^ ((q * 4 + 1) & 7)) << 3) + ke] = f2bf(v.y);
      Ys[(q * 4 + 2) * 64 + ((kb ^ ((q * 4 + 2) & 7)) << 3) + ke] = f2bf(v.z);
      Ys[(q * 4 + 3) * 64 + ((kb ^ ((q * 4 + 3) & 7)) << 3) + ke] = f2bf(v.w);
    }
    __syncthreads();
    int arow = w * 16 + lr;
    bf16x8 af0 = *(const bf16x8*)(Xs + arow * 64 + (((0 + lg) ^ (arow & 7)) << 3));
    bf16x8 af1 = *(const bf16x8*)(Xs + arow * 64 + (((4 + lg) ^ (arow & 7)) << 3));
#pragma unroll
    for (int nt = 0; nt < 4; ++nt) {
      int brow = nt * 16 + lr;
      bf16x8 bf0 = *(const bf16x8*)(Ys + brow * 64 + (((0 + lg) ^ (brow & 7)) << 3));
      bf16x8 bf1 = *(const bf16x8*)(Ys + brow * 64 + (((4 + lg) ^ (brow & 7)) << 3));
      acc[nt] = __builtin_amdgcn_mfma_f32_16x16x32_bf16(af0, bf0, acc[nt], 0, 0, 0);
      acc[nt] = __builtin_amdgcn_mfma_f32_16x16x32_bf16(af1, bf1, acc[nt], 0, 0, 0);
    }
  }
#pragma unroll
  for (int nt = 0; nt < 4; ++nt) {
#pragma unroll
    for (int r = 0; r < 4; ++r) {
      int gi = m0 + w * 16 + lg * 4 + r;
      int gj = n0 + nt * 16 + lr;
      float d = acc[nt][r];
      if (mode == 1)      d = 7.f * Ah[(size_t)gi * 256 + gj] - d;
      else if (mode == 2) d = 15.f * Ah[(size_t)gi * 256 + gj] - d;
      else if (mode == 3) d = 0.25f * (13.f * Ah[(size_t)gi * 256 + gj] - d);
      Ch[(size_t)gi * 256 + gj] = d;
    }
  }
}

// ---------------- assemble: h[0]=cls, h[16001+i]=h[1+i] (i<129) ----------------
__global__ __launch_bounds__(256) void assemble_kernel(float* __restrict__ h,
                                                       const float* __restrict__ cls)
{
  int idx = blockIdx.x * 256 + threadIdx.x;
  if (idx < 512) { h[idx] = cls[idx]; return; }
  idx -= 512;
  int i = idx >> 9, c = idx & 511;
  h[(size_t)(16001 + i) * DD + c] = h[(size_t)(1 + i) * DD + c];
}

// ---------------- LayerNorm rows of h -> xn (front-padded, rows<PADR zeroed) ----------------
__global__ __launch_bounds__(256) void ln_pad_kernel(
    const float* __restrict__ h, float* __restrict__ xn,
    const float* __restrict__ g, const float* __restrict__ b)
{
  int row = blockIdx.x;
  int t = threadIdx.x;
  if (row < PADR) {
    xn[(size_t)row * DD + t] = 0.f;
    xn[(size_t)row * DD + t + 256] = 0.f;
    return;
  }
  const float* x = h + (size_t)(row - PADR) * DD;
  __shared__ float red[256];
  float v0 = x[t], v1 = x[t + 256];
  red[t] = v0 + v1;
  __syncthreads();
  for (int s = 128; s > 0; s >>= 1) { if (t < s) red[t] += red[t + s]; __syncthreads(); }
  float mu = red[0] * (1.f / 512.f);
  __syncthreads();
  float d0 = v0 - mu, d1 = v1 - mu;
  red[t] = d0 * d0 + d1 * d1;
  __syncthreads();
  for (int s = 128; s > 0; s >>= 1) { if (t < s) red[t] += red[t + s]; __syncthreads(); }
  float rs = rsqrtf(red[0] * (1.f / 512.f) + 1e-5f);
  float* o = xn + (size_t)row * DD;
  o[t]       = d0 * rs * g[t] + b[t];
  o[t + 256] = d1 * rs * g[t + 256] + b[t + 256];
}

// ---------------- landmarks ----------------
__global__ __launch_bounds__(256) void landmark_kernel(
    const float* __restrict__ qkv, float* __restrict__ ql, float* __restrict__ kl)
{
  int i = blockIdx.x;
  int c = blockIdx.y * 256 + threadIdx.x;
  const float* p = qkv + (size_t)(i * 64) * 1536 + c;
  float s = 0.f;
  for (int j = 0; j < 64; ++j) s += p[(size_t)j * 1536];
  s *= (1.f / 64.f);
  if (c < 512) ql[(size_t)i * 512 + c] = s;
  else         kl[(size_t)i * 512 + (c - 512)] = s;
}

// ---------------- a2 = softmax(ql . kl^T) per head ----------------
__global__ __launch_bounds__(256) void a2_kernel(
    const float* __restrict__ ql, const float* __restrict__ kl, float* __restrict__ a2)
{
  int h_ = blockIdx.x, i = blockIdx.y;
  int t = threadIdx.x;
  __shared__ float q[64];
  __shared__ float red[256];
  if (t < 64) q[t] = ql[(size_t)i * 512 + h_ * 64 + t];
  __syncthreads();
  const float* kr = kl + (size_t)t * 512 + h_ * 64;
  float s = 0.f;
#pragma unroll
  for (int d = 0; d < 64; ++d) s = fmaf(q[d], kr[d], s);
  red[t] = s;
  __syncthreads();
  for (int st = 128; st > 0; st >>= 1) { if (t < st) red[t] = fmaxf(red[t], red[t + st]); __syncthreads(); }
  float mx = red[0];
  __syncthreads();
  float e = __expf(s - mx);
  red[t] = e;
  __syncthreads();
  for (int st = 128; st > 0; st >>= 1) { if (t < st) red[t] += red[t + st]; __syncthreads(); }
  a2[((size_t)h_ * 256 + i) * 256 + t] = e / red[0];
}

// ---------------- pinv init reductions ----------------
__global__ __launch_bounds__(256) void pinv_red1(const float* __restrict__ a2, float* __restrict__ red)
{
  int h_ = blockIdx.x, t = threadIdx.x;
  const float* X = a2 + (size_t)h_ * 65536;
  float rs = 0.f, cs = 0.f;
  for (int j = 0; j < 256; ++j) rs += fabsf(X[(size_t)t * 256 + j]);
  for (int i = 0; i < 256; ++i) cs += fabsf(X[(size_t)i * 256 + t]);
  __shared__ float r1[256], r2[256];
  r1[t] = rs; r2[t] = cs;
  __syncthreads();
  for (int s = 128; s > 0; s >>= 1) {
    if (t < s) { r1[t] = fmaxf(r1[t], r1[t + s]); r2[t] = fmaxf(r2[t], r2[t + s]); }
    __syncthreads();
  }
  if (t == 0) { red[h_ * 2] = r1[0]; red[h_ * 2 + 1] = r2[0]; }
}
__global__ void pinv_red2(float* __restrict__ red)
{
  float mr = 0.f, mc = 0.f;
  for (int h_ = 0; h_ < 8; ++h_) { mr = fmaxf(mr, red[h_ * 2]); mc = fmaxf(mc, red[h_ * 2 + 1]); }
  red[16] = 1.f / (mr * mc);
}
__global__ __launch_bounds__(256) void pinv_init(
    const float* __restrict__ a2, const float* __restrict__ red, float* __restrict__ z)
{
  int h_ = blockIdx.x, i = blockIdx.y, j = threadIdx.x;
  float inv = red[16];
  z[((size_t)h_ * 256 + i) * 256 + j] = a2[((size_t)h_ * 256 + j) * 256 + i] * inv;
}

// ---------------- batched matmul per head: C = alpha*(A @ B), A 256x256, B 256xN ----------------
__global__ __launch_bounds__(256) void mmb_kernel(
    const float* __restrict__ A, const float* __restrict__ B, float* __restrict__ C,
    int N, float alpha)
{
  int h_ = blockIdx.z;
  const float* Ah = A + (size_t)h_ * 256 * 256;
  const float* Bh = B + (size_t)h_ * 256 * N;
  float* Ch = C + (size_t)h_ * 256 * N;
  int m0 = blockIdx.y * 64, n0 = blockIdx.x * 64;
  __shared__ float As[16][68];
  __shared__ float Bs[16][68];
  int tid = threadIdx.x, tx = tid & 15, ty = tid >> 4;
  float acc[4][4];
#pragma unroll
  for (int i = 0; i < 4; ++i)
#pragma unroll
    for (int j = 0; j < 4; ++j) acc[i][j] = 0.f;
  for (int k0 = 0; k0 < 256; k0 += 16) {
    {
      int row = tid >> 2, k4 = (tid & 3) << 2;
      float4 v = *(const float4*)(Ah + (size_t)(m0 + row) * 256 + k0 + k4);
      As[k4 + 0][row] = v.x; As[k4 + 1][row] = v.y;
      As[k4 + 2][row] = v.z; As[k4 + 3][row] = v.w;
    }
    {
      int row = tid >> 4, c4 = (tid & 15) << 2;
      *(float4*)&Bs[row][c4] = *(const float4*)(Bh + (size_t)(k0 + row) * N + n0 + c4);
    }
    __syncthreads();
#pragma unroll
    for (int k = 0; k < 16; ++k) {
      float a[4], b[4];
      *(float4*)a = *(const float4*)&As[k][ty * 4];
      *(float4*)b = *(const float4*)&Bs[k][tx * 4];
#pragma unroll
      for (int i = 0; i < 4; ++i)
#pragma unroll
        for (int j = 0; j < 4; ++j) acc[i][j] = fmaf(a[i], b[j], acc[i][j]);
    }
    __syncthreads();
  }
#pragma unroll
  for (int i = 0; i < 4; ++i) {
    float4 r;
    r.x = alpha * acc[i][0]; r.y = alpha * acc[i][1];
    r.z = alpha * acc[i][2]; r.w = alpha * acc[i][3];
    *(float4*)(Ch + (size_t)(m0 + ty * 4 + i) * N + n0 + tx * 4) = r;
  }
}

// ---------------- a3@v partials via bf16 MFMA flash (no-max exp, ones-column den) ----------
__global__ __launch_bounds__(256) void a3v_mfma(
    const float* __restrict__ qkv, const float* __restrict__ ql,
    float* __restrict__ pacc, float* __restrict__ den)
{
  const int h_ = blockIdx.x;
  const int ch = blockIdx.y;
  const int t  = threadIdx.x;
  const int w  = t >> 6;
  const int l  = t & 63;
  const int lr = l & 15;
  const int lg = l >> 4;

  __shared__ __align__(16) ushort kls[64 * 64];
  __shared__ __align__(16) ushort vls[80 * 64];
  __shared__ __align__(16) ushort pls[4][64 * 64];

  bf16x8 qf[4][2];
#pragma unroll
  for (int rt = 0; rt < 4; ++rt)
#pragma unroll
    for (int dc = 0; dc < 2; ++dc) {
      const float* p = ql + (size_t)(64 * w + rt * 16 + lr) * 512 + h_ * 64 + dc * 32 + lg * 8;
      float4 f0 = *(const float4*)p;
      float4 f1 = *(const float4*)(p + 4);
      bf16x8 v;
      v[0] = f2bf(f0.x); v[1] = f2bf(f0.y); v[2] = f2bf(f0.z); v[3] = f2bf(f0.w);
      v[4] = f2bf(f1.x); v[5] = f2bf(f1.y); v[6] = f2bf(f1.z); v[7] = f2bf(f1.w);
      qf[rt][dc] = v;
    }

  if (t < 128) {
    int rr = t >> 3, cb = t & 7;
    ushort val = (rr == 0) ? (ushort)0x3f80 : (ushort)0;
    bf16x8 vv;
#pragma unroll
    for (int k = 0; k < 8; ++k) vv[k] = (short)val;
    *(bf16x8*)(vls + (64 + rr) * 64 + ((cb ^ (rr & 7)) << 3)) = vv;
  }

  f32x4 acc[4][5];
#pragma unroll
  for (int rt = 0; rt < 4; ++rt)
#pragma unroll
    for (int dt = 0; dt < 5; ++dt) acc[rt][dt] = (f32x4){0.f, 0.f, 0.f, 0.f};

  const int j0base = ch * 256;
  for (int jt = 0; jt < 4; ++jt) {
    const int j0 = j0base + jt * 64;
    __syncthreads();
    {
      int r = t >> 2, db = t & 3;
      const float* src = qkv + (size_t)(j0 + r) * 1536 + 512 + h_ * 64 + db * 16;
      float4 g0 = *(const float4*)(src + 0);
      float4 g1 = *(const float4*)(src + 4);
      float4 g2 = *(const float4*)(src + 8);
      float4 g3 = *(const float4*)(src + 12);
      bf16x8 e0, e1;
      e0[0] = f2bf(g0.x); e0[1] = f2bf(g0.y); e0[2] = f2bf(g0.z); e0[3] = f2bf(g0.w);
      e0[4] = f2bf(g1.x); e0[5] = f2bf(g1.y); e0[6] = f2bf(g1.z); e0[7] = f2bf(g1.w);
      e1[0] = f2bf(g2.x); e1[1] = f2bf(g2.y); e1[2] = f2bf(g2.z); e1[3] = f2bf(g2.w);
      e1[4] = f2bf(g3.x); e1[5] = f2bf(g3.y); e1[6] = f2bf(g3.z); e1[7] = f2bf(g3.w);
      ushort* base = kls + r * 64;
      *(bf16x8*)(base + (((db * 2 + 0) ^ (r & 7)) << 3)) = e0;
      *(bf16x8*)(base + (((db * 2 + 1) ^ (r & 7)) << 3)) = e1;
    }
    {
      int d = t & 63, jg = t >> 6;
#pragma unroll
      for (int half = 0; half < 2; ++half) {
        int jb = jg + half * 4;
        bf16x8 e;
#pragma unroll
        for (int jj = 0; jj < 8; ++jj)
          e[jj] = f2bf(qkv[(size_t)(j0 + jb * 8 + jj) * 1536 + 1024 + h_ * 64 + d]);
        *(bf16x8*)(vls + d * 64 + ((jb ^ (d & 7)) << 3)) = e;
      }
    }
    __syncthreads();

    ushort* pw = pls[w];
#pragma unroll
    for (int sjt = 0; sjt < 4; ++sjt) {
      const int krow = sjt * 16 + lr;
      bf16x8 kf0 = *(const bf16x8*)(kls + krow * 64 + (((0 * 4 + lg) ^ (lr & 7)) << 3));
      bf16x8 kf1 = *(const bf16x8*)(kls + krow * 64 + (((1 * 4 + lg) ^ (lr & 7)) << 3));
#pragma unroll
      for (int rt = 0; rt < 4; ++rt) {
        f32x4 s = (f32x4){0.f, 0.f, 0.f, 0.f};
        s = __builtin_amdgcn_mfma_f32_16x16x32_bf16(qf[rt][0], kf0, s, 0, 0, 0);
        s = __builtin_amdgcn_mfma_f32_16x16x32_bf16(qf[rt][1], kf1, s, 0, 0, 0);
#pragma unroll
        for (int r = 0; r < 4; ++r) {
          int i  = rt * 16 + lg * 4 + r;
          int jj = sjt * 16 + lr;
          pw[i * 64 + ((((jj >> 3) ^ (i & 7)) << 3)) + (jj & 7)] = (short)f2bf(__expf(s[r]));
        }
      }
    }
    bf16x8 pf[4][2];
#pragma unroll
    for (int rt = 0; rt < 4; ++rt)
#pragma unroll
      for (int jc = 0; jc < 2; ++jc)
        pf[rt][jc] = *(const bf16x8*)(pw + (rt * 16 + lr) * 64 + (((jc * 4 + lg) ^ (lr & 7)) << 3));
#pragma unroll
    for (int dt = 0; dt < 5; ++dt) {
      const int vrow = dt * 16 + lr;
      bf16x8 vf0 = *(const bf16x8*)(vls + vrow * 64 + (((0 * 4 + lg) ^ (lr & 7)) << 3));
      bf16x8 vf1 = *(const bf16x8*)(vls + vrow * 64 + (((1 * 4 + lg) ^ (lr & 7)) << 3));
#pragma unroll
      for (int rt = 0; rt < 4; ++rt) {
        acc[rt][dt] = __builtin_amdgcn_mfma_f32_16x16x32_bf16(pf[rt][0], vf0, acc[rt][dt], 0, 0, 0);
        acc[rt][dt] = __builtin_amdgcn_mfma_f32_16x16x32_bf16(pf[rt][1], vf1, acc[rt][dt], 0, 0, 0);
      }
    }
  }

  const size_t pbase = (size_t)(h_ * CHK + ch) * 256;
#pragma unroll
  for (int rt = 0; rt < 4; ++rt) {
    int i = 64 * w + rt * 16 + lg * 4;
#pragma unroll
    for (int dt = 0; dt < 4; ++dt)
#pragma unroll
      for (int r = 0; r < 4; ++r)
        pacc[(pbase + i + r) * 64 + dt * 16 + lr] = acc[rt][dt][r];
    if (lr == 0) {
#pragma unroll
      for (int r = 0; r < 4; ++r)
        den[pbase + i + r] = acc[rt][4][r];
    }
  }
}

// ---------------- merge a3v partials ----------------
__global__ __launch_bounds__(64) void a3v_merge_kernel(
    const float* __restrict__ pacc, const float* __restrict__ den, float* __restrict__ a3v)
{
  int h_ = blockIdx.x, i = blockIdx.y, d = threadIdx.x;
  float S = 0.f, o = 0.f;
  for (int c = 0; c < CHK; ++c) {
    size_t b = (size_t)(h_ * CHK + c) * 256 + i;
    o += pacc[b * 64 + d];
    S += den[b];
  }
  a3v[((size_t)h_ * 256 + i) * 64 + d] = o / S;
}

// ---------------- out = softmax(q . kl^T) @ w2, fused ----------------
__global__ __launch_bounds__(256) void a1_kernel(
    const float* __restrict__ qkv, const float* __restrict__ kl,
    const float* __restrict__ w2, float* __restrict__ attn)
{
  int h_ = blockIdx.x;
  int r = blockIdx.y * 256 + threadIdx.x;
  int t = threadIdx.x;
  __shared__ float klt[128][64];
  __shared__ float wt[128][64];
  float qr[64];
#pragma unroll
  for (int d4 = 0; d4 < 16; ++d4)
    *(float4*)&qr[d4 * 4] = *(const float4*)(qkv + (size_t)r * 1536 + h_ * 64 + d4 * 4);
  float m = -1e30f, s = 0.f;
  float acc[64];
#pragma unroll
  for (int d = 0; d < 64; ++d) acc[d] = 0.f;
  for (int jh = 0; jh < 2; ++jh) {
    __syncthreads();
#pragma unroll
    for (int l = 0; l < 8; ++l) {
      int idx = t + l * 256;
      int rr = idx >> 4, c4 = (idx & 15) << 2;
      *(float4*)&klt[rr][c4] = *(const float4*)(kl + (size_t)(jh * 128 + rr) * 512 + h_ * 64 + c4);
      *(float4*)&wt[rr][c4]  = *(const float4*)(w2 + ((size_t)h_ * 256 + jh * 128 + rr) * 64 + c4);
    }
    __syncthreads();
    for (int j = 0; j < 128; ++j) {
      float sc = 0.f;
#pragma unroll
      for (int d4 = 0; d4 < 16; ++d4) {
        float4 kv = *(const float4*)&klt[j][d4 * 4];
        sc = fmaf(qr[d4*4+0], kv.x, sc); sc = fmaf(qr[d4*4+1], kv.y, sc);
        sc = fmaf(qr[d4*4+2], kv.z, sc); sc = fmaf(qr[d4*4+3], kv.w, sc);
      }
      if (sc <= m) {
        float p = __expf(sc - m);
        s += p;
#pragma unroll
        for (int d4 = 0; d4 < 16; ++d4) {
          float4 vv = *(const float4*)&wt[j][d4 * 4];
          acc[d4*4+0] = fmaf(p, vv.x, acc[d4*4+0]);
          acc[d4*4+1] = fmaf(p, vv.y, acc[d4*4+1]);
          acc[d4*4+2] = fmaf(p, vv.z, acc[d4*4+2]);
          acc[d4*4+3] = fmaf(p, vv.w, acc[d4*4+3]);
        }
      } else {
        float corr = __expf(m - sc);
        m = sc;
        s = fmaf(s, corr, 1.f);
#pragma unroll
        for (int d4 = 0; d4 < 16; ++d4) {
          float4 vv = *(const float4*)&wt[j][d4 * 4];
          acc[d4*4+0] = fmaf(acc[d4*4+0], corr, vv.x);
          acc[d4*4+1] = fmaf(acc[d4*4+1], corr, vv.y);
          acc[d4*4+2] = fmaf(acc[d4*4+2], corr, vv.z);
          acc[d4*4+3] = fmaf(acc[d4*4+3], corr, vv.w);
        }
      }
    }
  }
  float inv = 1.f / s;
  float* op = attn + (size_t)r * 512 + h_ * 64;
#pragma unroll
  for (int d4 = 0; d4 < 16; ++d4) {
    float4 o;
    o.x = acc[d4*4+0] * inv; o.y = acc[d4*4+1] * inv;
    o.z = acc[d4*4+2] * inv; o.w = acc[d4*4+3] * inv;
    *(float4*)(op + d4 * 4) = o;
  }
}

// ---------------- depthwise res conv over sequence (kernel 33), adds into attn ----------------
__global__ __launch_bounds__(256) void resconv_kernel(
    const float* __restrict__ qkv, const float* __restrict__ rw, float* __restrict__ attn)
{
  int r = blockIdx.x;
  int c = blockIdx.y * 256 + threadIdx.x;
  int h_ = c >> 6;
  float s = 0.f;
#pragma unroll
  for (int tp = 0; tp < 33; ++tp) {
    int rr = r + tp - 16;
    if (rr >= 0 && rr < NPAD)
      s = fmaf(qkv[(size_t)rr * 1536 + 1024 + c], rw[h_ * 33 + tp], s);
  }
  attn[(size_t)r * 512 + c] += s;
}

// ---------------- weight transpose for ppeg: wt[k*512+c] ----------------
__global__ __launch_bounds__(256) void wtrans_kernel(
    const float* __restrict__ w7, const float* __restrict__ w5,
    const float* __restrict__ w3, float* __restrict__ wt)
{
  int c = blockIdx.x * 256 + threadIdx.x;
  for (int k = 0; k < 49; ++k) wt[(size_t)k * 512 + c]        = w7[(size_t)c * 49 + k];
  for (int k = 0; k < 25; ++k) wt[(size_t)(49 + k) * 512 + c] = w5[(size_t)c * 25 + k];
  for (int k = 0; k < 9;  ++k) wt[(size_t)(74 + k) * 512 + c] = w3[(size_t)c * 9 + k];
}

// ---------------- PPEG: weights staged in LDS (85KB), 256 ch x 64 px per block ----------
__global__ __launch_bounds__(256) void ppeg_kernel(
    const float* __restrict__ h, float* __restrict__ tmp,
    const float* __restrict__ wt,
    const float* __restrict__ b7, const float* __restrict__ b5,
    const float* __restrict__ b3)
{
  __shared__ float wl[83 * 256];
  const int t = threadIdx.x;
  const int c = blockIdx.y * 256 + t;
#pragma unroll
  for (int k = 0; k < 83; ++k)
    wl[k * 256 + t] = wt[(size_t)k * 512 + c];
  const float bsum = b7[c] + b5[c] + b3[c];
  __syncthreads();

  const int p0 = blockIdx.x * 64;
  for (int i = 0; i < 64; ++i) {
    int p = p0 + i;
    if (p >= NPIX) break;
    int y = p / SG, x = p - y * SG;
    float a7 = 0.f, a5 = 0.f, a3 = 0.f;
    if (y >= 3 && y <= SG - 4 && x >= 3 && x <= SG - 4) {
#pragma unroll
      for (int ky = 0; ky < 7; ++ky)
#pragma unroll
        for (int kx = 0; kx < 7; ++kx) {
          float v = h[(size_t)(1 + (y + ky - 3) * SG + (x + kx - 3)) * DD + c];
          a7 = fmaf(v, wl[(ky * 7 + kx) * 256 + t], a7);
          if (ky >= 1 && ky <= 5 && kx >= 1 && kx <= 5)
            a5 = fmaf(v, wl[(49 + (ky - 1) * 5 + (kx - 1)) * 256 + t], a5);
          if (ky >= 2 && ky <= 4 && kx >= 2 && kx <= 4)
            a3 = fmaf(v, wl[(74 + (ky - 2) * 3 + (kx - 2)) * 256 + t], a3);
        }
    } else {
#pragma unroll
      for (int ky = 0; ky < 7; ++ky) {
        int yy = y + ky - 3;
        bool oky = (yy >= 0 && yy < SG);
#pragma unroll
        for (int kx = 0; kx < 7; ++kx) {
          int xx = x + kx - 3;
          float v = (oky && xx >= 0 && xx < SG)
                        ? h[(size_t)(1 + yy * SG + xx) * DD + c] : 0.f;
          a7 = fmaf(v, wl[(ky * 7 + kx) * 256 + t], a7);
          if (ky >= 1 && ky <= 5 && kx >= 1 && kx <= 5)
            a5 = fmaf(v, wl[(49 + (ky - 1) * 5 + (kx - 1)) * 256 + t], a5);
          if (ky >= 2 && ky <= 4 && kx >= 2 && kx <= 4)
            a3 = fmaf(v, wl[(74 + (ky - 2) * 3 + (kx - 2)) * 256 + t], a3);
        }
      }
    }
    tmp[(size_t)p * DD + c] = h[(size_t)(1 + p) * DD + c] + bsum + a7 + a5 + a3;
  }
}

// ---------------- final: LN(row0) -> fc2 -> softmax/argmax ----------------
__global__ __launch_bounds__(256) void final_kernel(
    const float* __restrict__ h, const float* __restrict__ g, const float* __restrict__ b,
    const float* __restrict__ w, const float* __restrict__ bias, float* __restrict__ out)
{
  __shared__ float red[256];
  int t = threadIdx.x;
  float v0 = h[t], v1 = h[t + 256];
  red[t] = v0 + v1;
  __syncthreads();
  for (int s = 128; s > 0; s >>= 1) { if (t < s) red[t] += red[t + s]; __syncthreads(); }
  float mu = red[0] * (1.f / 512.f);
  __syncthreads();
  float d0 = v0 - mu, d1 = v1 - mu;
  red[t] = d0 * d0 + d1 * d1;
  __syncthreads();
  for (int s = 128; s > 0; s >>= 1) { if (t < s) red[t] += red[t + s]; __syncthreads(); }
  float rs = rsqrtf(red[0] * (1.f / 512.f) + 1e-5f);
  __syncthreads();
  float x0 = d0 * rs * g[t] + b[t];
  float x1 = d1 * rs * g[t + 256] + b[t + 256];
  red[t] = x0 * w[t * 2] + x1 * w[(t + 256) * 2];
  __syncthreads();
  for (int s = 128; s > 0; s >>= 1) { if (t < s) red[t] += red[t + s]; __syncthreads(); }
  float l0 = red[0] + bias[0];
  __syncthreads();
  red[t] = x0 * w[t * 2 + 1] + x1 * w[(t + 256) * 2 + 1];
  __syncthreads();
  for (int s = 128; s > 0; s >>= 1) { if (t < s) red[t] += red[t + s]; __syncthreads(); }
  float l1 = red[0] + bias[1];
  if (t == 0) {
    out[0] = l0; out[1] = l1;
    float mx = fmaxf(l0, l1);
    float e0 = __expf(l0 - mx), e1 = __expf(l1 - mx);
    float inv = 1.f / (e0 + e1);
    out[2] = e0 * inv; out[3] = e1 * inv;
    out[4] = (l1 > l0) ? 1.f : 0.f;
  }
}

extern "C" void kernel_launch(void* const* d_in, const int* in_sizes, int n_in,
                              void* d_out, int out_size, void* d_ws, size_t ws_size,
                              hipStream_t stream)
{
  const float* data   = (const float*)d_in[0];
  const float* fc1_w  = (const float*)d_in[1];
  const float* fc1_b  = (const float*)d_in[2];
  const float* cls    = (const float*)d_in[3];
  const float* l1_g   = (const float*)d_in[4];
  const float* l1_b   = (const float*)d_in[5];
  const float* l1_qkv = (const float*)d_in[6];
  const float* l1_ow  = (const float*)d_in[7];
  const float* l1_ob  = (const float*)d_in[8];
  const float* l1_rw  = (const float*)d_in[9];
  const float* w7     = (const float*)d_in[10];
  const float* b7     = (const float*)d_in[11];
  const float* w5     = (const float*)d_in[12];
  const float* b5     = (const float*)d_in[13];
  const float* w3     = (const float*)d_in[14];
  const float* b3     = (const float*)d_in[15];
  const float* l2_g   = (const float*)d_in[16];
  const float* l2_b   = (const float*)d_in[17];
  const float* l2_qkv = (const float*)d_in[18];
  const float* l2_ow  = (const float*)d_in[19];
  const float* l2_ob  = (const float*)d_in[20];
  const float* l2_rw  = (const float*)d_in[21];
  const float* ng     = (const float*)d_in[22];
  const float* nb     = (const float*)d_in[23];
  const float* fc2_w  = (const float*)d_in[24];
  const float* fc2_b  = (const float*)d_in[25];
  float* out = (float*)d_out;

  float* ws   = (float*)d_ws;
  float* h    = ws;
  float* xn   = h    + (size_t)16384 * 512;
  float* qkv  = xn   + (size_t)16384 * 512;
  float* attn = qkv  + (size_t)16384 * 1536;
  float* ql   = attn + (size_t)16384 * 512;
  float* kl   = ql   + 256 * 512;
  float* a2b  = kl   + 256 * 512;
  float* z0   = a2b  + 8 * 256 * 256;
  float* z1   = z0   + 8 * 256 * 256;
  float* xzb  = z1   + 8 * 256 * 256;
  float* tb   = xzb  + 8 * 256 * 256;
  float* ub   = tb   + 8 * 256 * 256;
  float* a3v  = ub   + 8 * 256 * 256;
  float* w2   = a3v  + 8 * 256 * 64;
  float* pacc = w2   + 8 * 256 * 64;           // dead region: bf16 weights carved here
  float* pms  = pacc + (size_t)8 * 32 * 256 * 64;
  float* red  = pms  + (size_t)8 * 32 * 256 * 2;
  float* wtb  = red  + 32;                       // ppeg weights fp32 (83*512)

  // bf16 transposed weights, carved from dead pacc region (2.62M ushorts << 16.8M floats)
  ushort* fc1_wt  = (ushort*)pacc;
  ushort* qkv_wt0 = fc1_wt + 512 * 1024;
  ushort* qkv_wt1 = qkv_wt0 + 1536 * 512;
  ushort* out_wt0 = qkv_wt1 + 1536 * 512;
  ushort* out_wt1 = out_wt0 + 512 * 512;

  // a3v MFMA partial buffers (alias xn scratch / pms as before)
  float* a3v_pacc = xn;
  float* a3v_den  = pms;

  // weight prep (bf16 transposes) + fc1 + assemble
  wtrans_bf<<<dim3(16, 32), 256, 0, stream>>>(fc1_w, fc1_wt, 1024, 512);
  wtrans_bf<<<dim3(48, 16), 256, 0, stream>>>(l1_qkv, qkv_wt0, 512, 1536);
  wtrans_bf<<<dim3(48, 16), 256, 0, stream>>>(l2_qkv, qkv_wt1, 512, 1536);
  wtrans_bf<<<dim3(16, 16), 256, 0, stream>>>(l1_ow, out_wt0, 512, 512);
  wtrans_bf<<<dim3(16, 16), 256, 0, stream>>>(l2_ow, out_wt1, 512, 512);
  wtrans_kernel<<<2, 256, 0, stream>>>(w7, w5, w3, wtb);

  gemm_bt<<<dim3(4, 125), 256, 0, stream>>>(data, 1024, fc1_wt, 1024, h + 512, 512,
                                            16000, 1024, 1, fc1_b);
  assemble_kernel<<<260, 256, 0, stream>>>(h, cls);

  for (int layer = 0; layer < 2; ++layer) {
    const float* gg = layer ? l2_g   : l1_g;
    const float* bb = layer ? l2_b   : l1_b;
    const ushort* qw = layer ? qkv_wt1 : qkv_wt0;
    const ushort* ow = layer ? out_wt1 : out_wt0;
    const float* ob = layer ? l2_ob  : l1_ob;
    const float* rw = layer ? l2_rw  : l1_rw;

    ln_pad_kernel<<<16384, 256, 0, stream>>>(h, xn, gg, bb);
    gemm_bt<<<dim3(12, 128), 256, 0, stream>>>(xn, 512, qw, 512, qkv, 1536,
                                               16384, 512, 2, nullptr);
    landmark_kernel<<<dim3(256, 4), 256, 0, stream>>>(qkv, ql, kl);
    a2_kernel<<<dim3(8, 256), 256, 0, stream>>>(ql, kl, a2b);
    pinv_red1<<<8, 256, 0, stream>>>(a2b, red);
    pinv_red2<<<1, 1, 0, stream>>>(red);
    pinv_init<<<dim3(8, 256), 256, 0, stream>>>(a2b, red, z0);
    float* zc = z0; float* zn = z1;
    for (int it = 0; it < 6; ++it) {
      nmm_kernel<<<dim3(4, 4, 8), 256, 0, stream>>>(a2b, zc, xzb, 0);  // xz = a2@z
      nmm_kernel<<<dim3(4, 4, 8), 256, 0, stream>>>(xzb, xzb, tb, 1);  // u1 = 7xz - xz@xz
      nmm_kernel<<<dim3(4, 4, 8), 256, 0, stream>>>(xzb, tb, ub, 2);   // u2 = 15xz - xz@u1
      nmm_kernel<<<dim3(4, 4, 8), 256, 0, stream>>>(zc, ub, zn, 3);    // z' = .25(13z - z@u2)
      float* sw = zc; zc = zn; zn = sw;
    }
    a3v_mfma<<<dim3(8, CHK), 256, 0, stream>>>(qkv, ql, a3v_pacc, a3v_den);
    a3v_merge_kernel<<<dim3(8, 256), 64, 0, stream>>>(a3v_pacc, a3v_den, a3v);
    mmb_kernel<<<dim3(1, 4, 8), 256, 0, stream>>>(zc, a3v, w2, 64, 1.f);
    a1_kernel<<<dim3(8, 64), 256, 0, stream>>>(qkv, kl, w2, attn);
    resconv_kernel<<<dim3(16384, 2), 256, 0, stream>>>(qkv, rw, attn);
    gemm_bt<<<dim3(4, 127), 256, 0, stream>>>(attn + (size_t)254 * 512, 512, ow, 512,
                                              h, 512, 16130, 512, 3, ob);
    if (layer == 0) {
      ppeg_kernel<<<dim3((NPIX + 63) / 64, 2), 256, 0, stream>>>(h, qkv, wtb, b7, b5, b3);
      hipMemcpyAsync(h + 512, qkv, (size_t)16129 * 512 * 4,
                     hipMemcpyDeviceToDevice, stream);
    }
  }
  final_kernel<<<1, 256, 0, stream>>>(h, ng, nb, fc2_w, fc2_b, out);
}

// Round 7
// 1709.412 us; speedup vs baseline: 3.4071x; 1.1906x over previous
//
#include <hip/hip_runtime.h>
#include <math.h>

#define NPAD   16384
#define PADR   254
#define NTOK   16130
#define NPIX   16129
#define SG     127
#define DD     512
#define NH     8
#define CHK    64          // key-chunks per head for a3v

typedef __attribute__((ext_vector_type(8))) short bf16x8;
typedef __attribute__((ext_vector_type(4))) float f32x4;

__device__ __forceinline__ ushort f2bf(float f) {
  uint u = __float_as_uint(f);
  u = (u + 0x7fffu + ((u >> 16) & 1u)) >> 16;
  return (ushort)u;
}

// ---------------- weight transpose+cvt: src fp32 [K][N] -> dst bf16 [N][K] ----------------
__global__ __launch_bounds__(256) void wtrans_bf(
    const float* __restrict__ src, ushort* __restrict__ dst, int K, int N)
{
  __shared__ float tile[32][33];
  int tx = threadIdx.x & 31, ty = threadIdx.x >> 5;   // 32 x 8
#pragma unroll
  for (int i = 0; i < 4; ++i) {
    int k = blockIdx.y * 32 + ty + i * 8, n = blockIdx.x * 32 + tx;
    tile[ty + i * 8][tx] = src[(size_t)k * N + n];
  }
  __syncthreads();
#pragma unroll
  for (int i = 0; i < 4; ++i) {
    int n = blockIdx.x * 32 + ty + i * 8, k = blockIdx.y * 32 + tx;
    dst[(size_t)n * K + k] = f2bf(tile[tx][ty + i * 8]);
  }
}

// ---------------- bf16 MFMA GEMM: C fp32 = A_f32 @ Bt_bf16^T ----------------
// A [M][lda] fp32 (converted in staging), Bt [N][ldb=K] bf16 row-major (pre-transposed W).
// 128x128 tile, BK=64, 4 waves (2x2 of 64x64). mode 1: relu(acc+bias); 2: q-scale; 3: C+=acc+bias.
__global__ __launch_bounds__(256) void gemm_bt(
    const float* __restrict__ A, int lda,
    const ushort* __restrict__ Bt, int ldb,
    float* __restrict__ C, int ldc,
    int M, int K, int mode, const float* __restrict__ bias)
{
  const int t = threadIdx.x;
  const int w = t >> 6, l = t & 63, lr = l & 15, lg = l >> 4;
  const int wr = w >> 1, wc = w & 1;
  const int m0 = blockIdx.y * 128, n0 = blockIdx.x * 128;
  __shared__ __align__(16) ushort As[128 * 64];
  __shared__ __align__(16) ushort Bs[128 * 64];
  f32x4 acc[4][4];
#pragma unroll
  for (int i = 0; i < 4; ++i)
#pragma unroll
    for (int j = 0; j < 4; ++j) acc[i][j] = (f32x4){0.f, 0.f, 0.f, 0.f};

  for (int k0 = 0; k0 < K; k0 += 64) {
    __syncthreads();
    // stage A: 128 rows x 4 chunks of 16 floats = 512 tasks, 2/thread
#pragma unroll
    for (int i = 0; i < 2; ++i) {
      int id = t + i * 256;
      int r = id >> 2, db = id & 3;
      const float* src = A + (size_t)(m0 + r) * lda + k0 + db * 16;
      float4 g0 = *(const float4*)(src + 0);
      float4 g1 = *(const float4*)(src + 4);
      float4 g2 = *(const float4*)(src + 8);
      float4 g3 = *(const float4*)(src + 12);
      bf16x8 e0, e1;
      e0[0] = f2bf(g0.x); e0[1] = f2bf(g0.y); e0[2] = f2bf(g0.z); e0[3] = f2bf(g0.w);
      e0[4] = f2bf(g1.x); e0[5] = f2bf(g1.y); e0[6] = f2bf(g1.z); e0[7] = f2bf(g1.w);
      e1[0] = f2bf(g2.x); e1[1] = f2bf(g2.y); e1[2] = f2bf(g2.z); e1[3] = f2bf(g2.w);
      e1[4] = f2bf(g3.x); e1[5] = f2bf(g3.y); e1[6] = f2bf(g3.z); e1[7] = f2bf(g3.w);
      ushort* dst = As + r * 64;
      *(bf16x8*)(dst + (((db * 2 + 0) ^ (r & 7)) << 3)) = e0;
      *(bf16x8*)(dst + (((db * 2 + 1) ^ (r & 7)) << 3)) = e1;
    }
    // stage B (already bf16): 128 rows x 8 blocks = 1024 tasks, 4/thread
#pragma unroll
    for (int i = 0; i < 4; ++i) {
      int id = t + i * 256;
      int r = id >> 3, blk = id & 7;
      bf16x8 v = *(const bf16x8*)(Bt + (size_t)(n0 + r) * ldb + k0 + blk * 8);
      *(bf16x8*)(Bs + r * 64 + ((blk ^ (r & 7)) << 3)) = v;
    }
    __syncthreads();
    bf16x8 af[4][2], bfr[4][2];
#pragma unroll
    for (int rt = 0; rt < 4; ++rt) {
      int row = wr * 64 + rt * 16 + lr;
#pragma unroll
      for (int kc = 0; kc < 2; ++kc)
        af[rt][kc] = *(const bf16x8*)(As + row * 64 + (((kc * 4 + lg) ^ (row & 7)) << 3));
    }
#pragma unroll
    for (int nt = 0; nt < 4; ++nt) {
      int row = wc * 64 + nt * 16 + lr;
#pragma unroll
      for (int kc = 0; kc < 2; ++kc)
        bfr[nt][kc] = *(const bf16x8*)(Bs + row * 64 + (((kc * 4 + lg) ^ (row & 7)) << 3));
    }
#pragma unroll
    for (int rt = 0; rt < 4; ++rt)
#pragma unroll
      for (int nt = 0; nt < 4; ++nt) {
        acc[rt][nt] = __builtin_amdgcn_mfma_f32_16x16x32_bf16(af[rt][0], bfr[nt][0], acc[rt][nt], 0, 0, 0);
        acc[rt][nt] = __builtin_amdgcn_mfma_f32_16x16x32_bf16(af[rt][1], bfr[nt][1], acc[rt][nt], 0, 0, 0);
      }
  }
#pragma unroll
  for (int rt = 0; rt < 4; ++rt) {
#pragma unroll
    for (int r = 0; r < 4; ++r) {
      int gi = m0 + wr * 64 + rt * 16 + lg * 4 + r;
      if (gi >= M) continue;
#pragma unroll
      for (int nt = 0; nt < 4; ++nt) {
        int gj = n0 + wc * 64 + nt * 16 + lr;
        float d = acc[rt][nt][r];
        if (mode == 1) d = fmaxf(d + bias[gj], 0.f);
        else if (mode == 2) { if (gj < 512) d *= 0.125f; }
        else if (mode == 3) d += C[(size_t)gi * ldc + gj] + bias[gj];
        C[(size_t)gi * ldc + gj] = d;
      }
    }
  }
}

// ---------------- fused Newton-step matmul: D = A@B (bf16 MFMA), C = f(A[ij], D) ----------
// batched 8 heads of 256x256. B transposed during staging. modes:
// 0: C=D ; 1: C=7A-D ; 2: C=15A-D ; 3: C=0.25*(13A-D)
__global__ __launch_bounds__(256) void nmm_kernel(
    const float* __restrict__ A, const float* __restrict__ B,
    float* __restrict__ C, int mode)
{
  const int h_ = blockIdx.z;
  const int m0 = blockIdx.y * 64, n0 = blockIdx.x * 64;
  const float* Ah = A + (size_t)h_ * 65536;
  const float* Bh = B + (size_t)h_ * 65536;
  float* Ch = C + (size_t)h_ * 65536;
  const int t = threadIdx.x, w = t >> 6, l = t & 63, lr = l & 15, lg = l >> 4;
  __shared__ __align__(16) ushort Xs[64 * 64];
  __shared__ __align__(16) ushort Ys[64 * 64];
  f32x4 acc[4];
#pragma unroll
  for (int nt = 0; nt < 4; ++nt) acc[nt] = (f32x4){0.f, 0.f, 0.f, 0.f};

  for (int k0 = 0; k0 < 256; k0 += 64) {
    __syncthreads();
    // stage A rows (direct): 64 rows x 4 chunks of 16 -> 256 tasks, 1/thread
    {
      int r = t >> 2, db = t & 3;
      const float* src = Ah + (size_t)(m0 + r) * 256 + k0 + db * 16;
      float4 g0 = *(const float4*)(src + 0);
      float4 g1 = *(const float4*)(src + 4);
      float4 g2 = *(const float4*)(src + 8);
      float4 g3 = *(const float4*)(src + 12);
      bf16x8 e0, e1;
      e0[0] = f2bf(g0.x); e0[1] = f2bf(g0.y); e0[2] = f2bf(g0.z); e0[3] = f2bf(g0.w);
      e0[4] = f2bf(g1.x); e0[5] = f2bf(g1.y); e0[6] = f2bf(g1.z); e0[7] = f2bf(g1.w);
      e1[0] = f2bf(g2.x); e1[1] = f2bf(g2.y); e1[2] = f2bf(g2.z); e1[3] = f2bf(g2.w);
      e1[4] = f2bf(g3.x); e1[5] = f2bf(g3.y); e1[6] = f2bf(g3.z); e1[7] = f2bf(g3.w);
      ushort* dst = Xs + r * 64;
      *(bf16x8*)(dst + (((db * 2 + 0) ^ (r & 7)) << 3)) = e0;
      *(bf16x8*)(dst + (((db * 2 + 1) ^ (r & 7)) << 3)) = e1;
    }
    // stage B transposed: 64 k-rows x 16 float4 = 1024 tasks, 4/thread
#pragma unroll
    for (int i = 0; i < 4; ++i) {
      int id = t + i * 256;
      int k = id >> 4, q = id & 15;
      float4 v = *(const float4*)(Bh + (size_t)(k0 + k) * 256 + n0 + q * 4);
      int kb = k >> 3, ke = k & 7;
      Ys[(q * 4 + 0) * 64 + ((kb ^ ((q * 4 + 0) & 7)) << 3) + ke] = f2bf(v.x);
      Ys[(q * 4 + 1) * 64 + ((kb ^ ((q * 4 + 1) & 7)) << 3) + ke] = f2bf(v.y);
      Ys[(q * 4 + 2) * 64 + ((kb ^ ((q * 4 + 2) & 7)) << 3) + ke] = f2bf(v.z);
      Ys[(q * 4 + 3) * 64 + ((kb ^ ((q * 4 + 3) & 7)) << 3) + ke] = f2bf(v.w);
    }
    __syncthreads();
    int arow = w * 16 + lr;
    bf16x8 af0 = *(const bf16x8*)(Xs + arow * 64 + (((0 + lg) ^ (arow & 7)) << 3));
    bf16x8 af1 = *(const bf16x8*)(Xs + arow * 64 + (((4 + lg) ^ (arow & 7)) << 3));
#pragma unroll
    for (int nt = 0; nt < 4; ++nt) {
      int brow = nt * 16 + lr;
      bf16x8 bf0 = *(const bf16x8*)(Ys + brow * 64 + (((0 + lg) ^ (brow & 7)) << 3));
      bf16x8 bf1 = *(const bf16x8*)(Ys + brow * 64 + (((4 + lg) ^ (brow & 7)) << 3));
      acc[nt] = __builtin_amdgcn_mfma_f32_16x16x32_bf16(af0, bf0, acc[nt], 0, 0, 0);
      acc[nt] = __builtin_amdgcn_mfma_f32_16x16x32_bf16(af1, bf1, acc[nt], 0, 0, 0);
    }
  }
#pragma unroll
  for (int nt = 0; nt < 4; ++nt) {
#pragma unroll
    for (int r = 0; r < 4; ++r) {
      int gi = m0 + w * 16 + lg * 4 + r;
      int gj = n0 + nt * 16 + lr;
      float d = acc[nt][r];
      if (mode == 1)      d = 7.f * Ah[(size_t)gi * 256 + gj] - d;
      else if (mode == 2) d = 15.f * Ah[(size_t)gi * 256 + gj] - d;
      else if (mode == 3) d = 0.25f * (13.f * Ah[(size_t)gi * 256 + gj] - d);
      Ch[(size_t)gi * 256 + gj] = d;
    }
  }
}

// ---------------- assemble: h[0]=cls, h[16001+i]=h[1+i] (i<129) ----------------
__global__ __launch_bounds__(256) void assemble_kernel(float* __restrict__ h,
                                                       const float* __restrict__ cls)
{
  int idx = blockIdx.x * 256 + threadIdx.x;
  if (idx < 512) { h[idx] = cls[idx]; return; }
  idx -= 512;
  int i = idx >> 9, c = idx & 511;
  h[(size_t)(16001 + i) * DD + c] = h[(size_t)(1 + i) * DD + c];
}

// ---------------- LayerNorm rows of h -> xn (front-padded, rows<PADR zeroed) ----------------
__global__ __launch_bounds__(256) void ln_pad_kernel(
    const float* __restrict__ h, float* __restrict__ xn,
    const float* __restrict__ g, const float* __restrict__ b)
{
  int row = blockIdx.x;
  int t = threadIdx.x;
  if (row < PADR) {
    xn[(size_t)row * DD + t] = 0.f;
    xn[(size_t)row * DD + t + 256] = 0.f;
    return;
  }
  const float* x = h + (size_t)(row - PADR) * DD;
  __shared__ float red[256];
  float v0 = x[t], v1 = x[t + 256];
  red[t] = v0 + v1;
  __syncthreads();
  for (int s = 128; s > 0; s >>= 1) { if (t < s) red[t] += red[t + s]; __syncthreads(); }
  float mu = red[0] * (1.f / 512.f);
  __syncthreads();
  float d0 = v0 - mu, d1 = v1 - mu;
  red[t] = d0 * d0 + d1 * d1;
  __syncthreads();
  for (int s = 128; s > 0; s >>= 1) { if (t < s) red[t] += red[t + s]; __syncthreads(); }
  float rs = rsqrtf(red[0] * (1.f / 512.f) + 1e-5f);
  float* o = xn + (size_t)row * DD;
  o[t]       = d0 * rs * g[t] + b[t];
  o[t + 256] = d1 * rs * g[t + 256] + b[t + 256];
}

// ---------------- landmarks ----------------
__global__ __launch_bounds__(256) void landmark_kernel(
    const float* __restrict__ qkv, float* __restrict__ ql, float* __restrict__ kl)
{
  int i = blockIdx.x;
  int c = blockIdx.y * 256 + threadIdx.x;
  const float* p = qkv + (size_t)(i * 64) * 1536 + c;
  float s = 0.f;
  for (int j = 0; j < 64; ++j) s += p[(size_t)j * 1536];
  s *= (1.f / 64.f);
  if (c < 512) ql[(size_t)i * 512 + c] = s;
  else         kl[(size_t)i * 512 + (c - 512)] = s;
}

// ---------------- a2 = softmax(ql . kl^T) per head ----------------
__global__ __launch_bounds__(256) void a2_kernel(
    const float* __restrict__ ql, const float* __restrict__ kl, float* __restrict__ a2)
{
  int h_ = blockIdx.x, i = blockIdx.y;
  int t = threadIdx.x;
  __shared__ float q[64];
  __shared__ float red[256];
  if (t < 64) q[t] = ql[(size_t)i * 512 + h_ * 64 + t];
  __syncthreads();
  const float* kr = kl + (size_t)t * 512 + h_ * 64;
  float s = 0.f;
#pragma unroll
  for (int d = 0; d < 64; ++d) s = fmaf(q[d], kr[d], s);
  red[t] = s;
  __syncthreads();
  for (int st = 128; st > 0; st >>= 1) { if (t < st) red[t] = fmaxf(red[t], red[t + st]); __syncthreads(); }
  float mx = red[0];
  __syncthreads();
  float e = __expf(s - mx);
  red[t] = e;
  __syncthreads();
  for (int st = 128; st > 0; st >>= 1) { if (t < st) red[t] += red[t + st]; __syncthreads(); }
  a2[((size_t)h_ * 256 + i) * 256 + t] = e / red[0];
}

// ---------------- pinv init reductions ----------------
__global__ __launch_bounds__(256) void pinv_red1(const float* __restrict__ a2, float* __restrict__ red)
{
  int h_ = blockIdx.x, t = threadIdx.x;
  const float* X = a2 + (size_t)h_ * 65536;
  float rs = 0.f, cs = 0.f;
  for (int j = 0; j < 256; ++j) rs += fabsf(X[(size_t)t * 256 + j]);
  for (int i = 0; i < 256; ++i) cs += fabsf(X[(size_t)i * 256 + t]);
  __shared__ float r1[256], r2[256];
  r1[t] = rs; r2[t] = cs;
  __syncthreads();
  for (int s = 128; s > 0; s >>= 1) {
    if (t < s) { r1[t] = fmaxf(r1[t], r1[t + s]); r2[t] = fmaxf(r2[t], r2[t + s]); }
    __syncthreads();
  }
  if (t == 0) { red[h_ * 2] = r1[0]; red[h_ * 2 + 1] = r2[0]; }
}
__global__ void pinv_red2(float* __restrict__ red)
{
  float mr = 0.f, mc = 0.f;
  for (int h_ = 0; h_ < 8; ++h_) { mr = fmaxf(mr, red[h_ * 2]); mc = fmaxf(mc, red[h_ * 2 + 1]); }
  red[16] = 1.f / (mr * mc);
}
__global__ __launch_bounds__(256) void pinv_init(
    const float* __restrict__ a2, const float* __restrict__ red, float* __restrict__ z)
{
  int h_ = blockIdx.x, i = blockIdx.y, j = threadIdx.x;
  float inv = red[16];
  z[((size_t)h_ * 256 + i) * 256 + j] = a2[((size_t)h_ * 256 + j) * 256 + i] * inv;
}

// ---------------- batched matmul per head: C = alpha*(A @ B), A 256x256, B 256xN ----------------
__global__ __launch_bounds__(256) void mmb_kernel(
    const float* __restrict__ A, const float* __restrict__ B, float* __restrict__ C,
    int N, float alpha)
{
  int h_ = blockIdx.z;
  const float* Ah = A + (size_t)h_ * 256 * 256;
  const float* Bh = B + (size_t)h_ * 256 * N;
  float* Ch = C + (size_t)h_ * 256 * N;
  int m0 = blockIdx.y * 64, n0 = blockIdx.x * 64;
  __shared__ float As[16][68];
  __shared__ float Bs[16][68];
  int tid = threadIdx.x, tx = tid & 15, ty = tid >> 4;
  float acc[4][4];
#pragma unroll
  for (int i = 0; i < 4; ++i)
#pragma unroll
    for (int j = 0; j < 4; ++j) acc[i][j] = 0.f;
  for (int k0 = 0; k0 < 256; k0 += 16) {
    {
      int row = tid >> 2, k4 = (tid & 3) << 2;
      float4 v = *(const float4*)(Ah + (size_t)(m0 + row) * 256 + k0 + k4);
      As[k4 + 0][row] = v.x; As[k4 + 1][row] = v.y;
      As[k4 + 2][row] = v.z; As[k4 + 3][row] = v.w;
    }
    {
      int row = tid >> 4, c4 = (tid & 15) << 2;
      *(float4*)&Bs[row][c4] = *(const float4*)(Bh + (size_t)(k0 + row) * N + n0 + c4);
    }
    __syncthreads();
#pragma unroll
    for (int k = 0; k < 16; ++k) {
      float a[4], b[4];
      *(float4*)a = *(const float4*)&As[k][ty * 4];
      *(float4*)b = *(const float4*)&Bs[k][tx * 4];
#pragma unroll
      for (int i = 0; i < 4; ++i)
#pragma unroll
        for (int j = 0; j < 4; ++j) acc[i][j] = fmaf(a[i], b[j], acc[i][j]);
    }
    __syncthreads();
  }
#pragma unroll
  for (int i = 0; i < 4; ++i) {
    float4 r;
    r.x = alpha * acc[i][0]; r.y = alpha * acc[i][1];
    r.z = alpha * acc[i][2]; r.w = alpha * acc[i][3];
    *(float4*)(Ch + (size_t)(m0 + ty * 4 + i) * N + n0 + tx * 4) = r;
  }
}

// ---------------- a3@v partials via bf16 MFMA flash (no-max exp, ones-column den) ----------
__global__ __launch_bounds__(256) void a3v_mfma(
    const float* __restrict__ qkv, const float* __restrict__ ql,
    float* __restrict__ pacc, float* __restrict__ den)
{
  const int h_ = blockIdx.x;
  const int ch = blockIdx.y;
  const int t  = threadIdx.x;
  const int w  = t >> 6;
  const int l  = t & 63;
  const int lr = l & 15;
  const int lg = l >> 4;

  __shared__ __align__(16) ushort kls[64 * 64];
  __shared__ __align__(16) ushort vls[80 * 64];
  __shared__ __align__(16) ushort pls[4][64 * 64];

  bf16x8 qf[4][2];
#pragma unroll
  for (int rt = 0; rt < 4; ++rt)
#pragma unroll
    for (int dc = 0; dc < 2; ++dc) {
      const float* p = ql + (size_t)(64 * w + rt * 16 + lr) * 512 + h_ * 64 + dc * 32 + lg * 8;
      float4 f0 = *(const float4*)p;
      float4 f1 = *(const float4*)(p + 4);
      bf16x8 v;
      v[0] = f2bf(f0.x); v[1] = f2bf(f0.y); v[2] = f2bf(f0.z); v[3] = f2bf(f0.w);
      v[4] = f2bf(f1.x); v[5] = f2bf(f1.y); v[6] = f2bf(f1.z); v[7] = f2bf(f1.w);
      qf[rt][dc] = v;
    }

  if (t < 128) {
    int rr = t >> 3, cb = t & 7;
    ushort val = (rr == 0) ? (ushort)0x3f80 : (ushort)0;
    bf16x8 vv;
#pragma unroll
    for (int k = 0; k < 8; ++k) vv[k] = (short)val;
    *(bf16x8*)(vls + (64 + rr) * 64 + ((cb ^ (rr & 7)) << 3)) = vv;
  }

  f32x4 acc[4][5];
#pragma unroll
  for (int rt = 0; rt < 4; ++rt)
#pragma unroll
    for (int dt = 0; dt < 5; ++dt) acc[rt][dt] = (f32x4){0.f, 0.f, 0.f, 0.f};

  const int j0base = ch * 256;
  for (int jt = 0; jt < 4; ++jt) {
    const int j0 = j0base + jt * 64;
    __syncthreads();
    {
      int r = t >> 2, db = t & 3;
      const float* src = qkv + (size_t)(j0 + r) * 1536 + 512 + h_ * 64 + db * 16;
      float4 g0 = *(const float4*)(src + 0);
      float4 g1 = *(const float4*)(src + 4);
      float4 g2 = *(const float4*)(src + 8);
      float4 g3 = *(const float4*)(src + 12);
      bf16x8 e0, e1;
      e0[0] = f2bf(g0.x); e0[1] = f2bf(g0.y); e0[2] = f2bf(g0.z); e0[3] = f2bf(g0.w);
      e0[4] = f2bf(g1.x); e0[5] = f2bf(g1.y); e0[6] = f2bf(g1.z); e0[7] = f2bf(g1.w);
      e1[0] = f2bf(g2.x); e1[1] = f2bf(g2.y); e1[2] = f2bf(g2.z); e1[3] = f2bf(g2.w);
      e1[4] = f2bf(g3.x); e1[5] = f2bf(g3.y); e1[6] = f2bf(g3.z); e1[7] = f2bf(g3.w);
      ushort* base = kls + r * 64;
      *(bf16x8*)(base + (((db * 2 + 0) ^ (r & 7)) << 3)) = e0;
      *(bf16x8*)(base + (((db * 2 + 1) ^ (r & 7)) << 3)) = e1;
    }
    {
      int d = t & 63, jg = t >> 6;
#pragma unroll
      for (int half = 0; half < 2; ++half) {
        int jb = jg + half * 4;
        bf16x8 e;
#pragma unroll
        for (int jj = 0; jj < 8; ++jj)
          e[jj] = f2bf(qkv[(size_t)(j0 + jb * 8 + jj) * 1536 + 1024 + h_ * 64 + d]);
        *(bf16x8*)(vls + d * 64 + ((jb ^ (d & 7)) << 3)) = e;
      }
    }
    __syncthreads();

    ushort* pw = pls[w];
#pragma unroll
    for (int sjt = 0; sjt < 4; ++sjt) {
      const int krow = sjt * 16 + lr;
      bf16x8 kf0 = *(const bf16x8*)(kls + krow * 64 + (((0 * 4 + lg) ^ (lr & 7)) << 3));
      bf16x8 kf1 = *(const bf16x8*)(kls + krow * 64 + (((1 * 4 + lg) ^ (lr & 7)) << 3));
#pragma unroll
      for (int rt = 0; rt < 4; ++rt) {
        f32x4 s = (f32x4){0.f, 0.f, 0.f, 0.f};
        s = __builtin_amdgcn_mfma_f32_16x16x32_bf16(qf[rt][0], kf0, s, 0, 0, 0);
        s = __builtin_amdgcn_mfma_f32_16x16x32_bf16(qf[rt][1], kf1, s, 0, 0, 0);
#pragma unroll
        for (int r = 0; r < 4; ++r) {
          int i  = rt * 16 + lg * 4 + r;
          int jj = sjt * 16 + lr;
          pw[i * 64 + ((((jj >> 3) ^ (i & 7)) << 3)) + (jj & 7)] = (short)f2bf(__expf(s[r]));
        }
      }
    }
    bf16x8 pf[4][2];
#pragma unroll
    for (int rt = 0; rt < 4; ++rt)
#pragma unroll
      for (int jc = 0; jc < 2; ++jc)
        pf[rt][jc] = *(const bf16x8*)(pw + (rt * 16 + lr) * 64 + (((jc * 4 + lg) ^ (lr & 7)) << 3));
#pragma unroll
    for (int dt = 0; dt < 5; ++dt) {
      const int vrow = dt * 16 + lr;
      bf16x8 vf0 = *(const bf16x8*)(vls + vrow * 64 + (((0 * 4 + lg) ^ (lr & 7)) << 3));
      bf16x8 vf1 = *(const bf16x8*)(vls + vrow * 64 + (((1 * 4 + lg) ^ (lr & 7)) << 3));
#pragma unroll
      for (int rt = 0; rt < 4; ++rt) {
        acc[rt][dt] = __builtin_amdgcn_mfma_f32_16x16x32_bf16(pf[rt][0], vf0, acc[rt][dt], 0, 0, 0);
        acc[rt][dt] = __builtin_amdgcn_mfma_f32_16x16x32_bf16(pf[rt][1], vf1, acc[rt][dt], 0, 0, 0);
      }
    }
  }

  const size_t pbase = (size_t)(h_ * CHK + ch) * 256;
#pragma unroll
  for (int rt = 0; rt < 4; ++rt) {
    int i = 64 * w + rt * 16 + lg * 4;
#pragma unroll
    for (int dt = 0; dt < 4; ++dt)
#pragma unroll
      for (int r = 0; r < 4; ++r)
        pacc[(pbase + i + r) * 64 + dt * 16 + lr] = acc[rt][dt][r];
    if (lr == 0) {
#pragma unroll
      for (int r = 0; r < 4; ++r)
        den[pbase + i + r] = acc[rt][4][r];
    }
  }
}

// ---------------- merge a3v partials ----------------
__global__ __launch_bounds__(64) void a3v_merge_kernel(
    const float* __restrict__ pacc, const float* __restrict__ den, float* __restrict__ a3v)
{
  int h_ = blockIdx.x, i = blockIdx.y, d = threadIdx.x;
  float S = 0.f, o = 0.f;
  for (int c = 0; c < CHK; ++c) {
    size_t b = (size_t)(h_ * CHK + c) * 256 + i;
    o += pacc[b * 64 + d];
    S += den[b];
  }
  a3v[((size_t)h_ * 256 + i) * 64 + d] = o / S;
}

// ---------------- a1: out = softmax(q . kl^T) @ w2 via bf16 MFMA (no-max exp, ones-col den)
// grid (8 heads, 64 row-blocks); 256 threads = 4 waves; wave w owns 64 query rows.
// Accumulate over 4 landmark-chunks in registers; normalize via shfl-broadcast denominator.
__global__ __launch_bounds__(256) void a1_mfma(
    const float* __restrict__ qkv, const float* __restrict__ kl,
    const float* __restrict__ w2, float* __restrict__ attn)
{
  const int h_ = blockIdx.x;
  const int rb = blockIdx.y;
  const int t  = threadIdx.x;
  const int w  = t >> 6, l = t & 63, lr = l & 15, lg = l >> 4;

  __shared__ __align__(16) ushort kls[64 * 64];     // kl tile [j][d]
  __shared__ __align__(16) ushort wls[80 * 64];     // w2^T tile [d][j] + ones rows
  __shared__ __align__(16) ushort pls[4][64 * 64];  // per-wave P

  // Q fragments: global row = rb*256 + w*64 + rt*16 + lr
  bf16x8 qf[4][2];
#pragma unroll
  for (int rt = 0; rt < 4; ++rt)
#pragma unroll
    for (int dc = 0; dc < 2; ++dc) {
      const float* p = qkv + (size_t)(rb * 256 + w * 64 + rt * 16 + lr) * 1536 + h_ * 64 + dc * 32 + lg * 8;
      float4 f0 = *(const float4*)p;
      float4 f1 = *(const float4*)(p + 4);
      bf16x8 v;
      v[0] = f2bf(f0.x); v[1] = f2bf(f0.y); v[2] = f2bf(f0.z); v[3] = f2bf(f0.w);
      v[4] = f2bf(f1.x); v[5] = f2bf(f1.y); v[6] = f2bf(f1.z); v[7] = f2bf(f1.w);
      qf[rt][dc] = v;
    }

  // ones rows of wls (row 64 = 1.0, rows 65..79 = 0)
  if (t < 128) {
    int rr = t >> 3, cb = t & 7;
    ushort val = (rr == 0) ? (ushort)0x3f80 : (ushort)0;
    bf16x8 vv;
#pragma unroll
    for (int k = 0; k < 8; ++k) vv[k] = (short)val;
    *(bf16x8*)(wls + (64 + rr) * 64 + ((cb ^ (rr & 7)) << 3)) = vv;
  }

  f32x4 acc[4][5];
#pragma unroll
  for (int rt = 0; rt < 4; ++rt)
#pragma unroll
    for (int dt = 0; dt < 5; ++dt) acc[rt][dt] = (f32x4){0.f, 0.f, 0.f, 0.f};

  for (int kc = 0; kc < 4; ++kc) {
    const int j0 = kc * 64;
    __syncthreads();
    // stage kl tile (fp32 -> bf16, swizzled)
    {
      int r = t >> 2, db = t & 3;
      const float* src = kl + (size_t)(j0 + r) * 512 + h_ * 64 + db * 16;
      float4 g0 = *(const float4*)(src + 0);
      float4 g1 = *(const float4*)(src + 4);
      float4 g2 = *(const float4*)(src + 8);
      float4 g3 = *(const float4*)(src + 12);
      bf16x8 e0, e1;
      e0[0] = f2bf(g0.x); e0[1] = f2bf(g0.y); e0[2] = f2bf(g0.z); e0[3] = f2bf(g0.w);
      e0[4] = f2bf(g1.x); e0[5] = f2bf(g1.y); e0[6] = f2bf(g1.z); e0[7] = f2bf(g1.w);
      e1[0] = f2bf(g2.x); e1[1] = f2bf(g2.y); e1[2] = f2bf(g2.z); e1[3] = f2bf(g2.w);
      e1[4] = f2bf(g3.x); e1[5] = f2bf(g3.y); e1[6] = f2bf(g3.z); e1[7] = f2bf(g3.w);
      ushort* base = kls + r * 64;
      *(bf16x8*)(base + (((db * 2 + 0) ^ (r & 7)) << 3)) = e0;
      *(bf16x8*)(base + (((db * 2 + 1) ^ (r & 7)) << 3)) = e1;
    }
    // stage w2^T tile: d = t&63, two 8-key blocks
    {
      int d = t & 63, jg = t >> 6;
#pragma unroll
      for (int half = 0; half < 2; ++half) {
        int jb = jg + half * 4;
        bf16x8 e;
#pragma unroll
        for (int jj = 0; jj < 8; ++jj)
          e[jj] = f2bf(w2[((size_t)h_ * 256 + j0 + jb * 8 + jj) * 64 + d]);
        *(bf16x8*)(wls + d * 64 + ((jb ^ (d & 7)) << 3)) = e;
      }
    }
    __syncthreads();

    // QK^T -> exp -> P
    ushort* pw = pls[w];
#pragma unroll
    for (int sjt = 0; sjt < 4; ++sjt) {
      const int krow = sjt * 16 + lr;
      bf16x8 kf0 = *(const bf16x8*)(kls + krow * 64 + (((0 * 4 + lg) ^ (lr & 7)) << 3));
      bf16x8 kf1 = *(const bf16x8*)(kls + krow * 64 + (((1 * 4 + lg) ^ (lr & 7)) << 3));
#pragma unroll
      for (int rt = 0; rt < 4; ++rt) {
        f32x4 s = (f32x4){0.f, 0.f, 0.f, 0.f};
        s = __builtin_amdgcn_mfma_f32_16x16x32_bf16(qf[rt][0], kf0, s, 0, 0, 0);
        s = __builtin_amdgcn_mfma_f32_16x16x32_bf16(qf[rt][1], kf1, s, 0, 0, 0);
#pragma unroll
        for (int r = 0; r < 4; ++r) {
          int i  = rt * 16 + lg * 4 + r;
          int jj = sjt * 16 + lr;
          pw[i * 64 + ((((jj >> 3) ^ (i & 7)) << 3)) + (jj & 7)] = (short)f2bf(__expf(s[r]));
        }
      }
    }
    // P fragments, then P @ [W | 1]
    bf16x8 pf[4][2];
#pragma unroll
    for (int rt = 0; rt < 4; ++rt)
#pragma unroll
      for (int jc = 0; jc < 2; ++jc)
        pf[rt][jc] = *(const bf16x8*)(pw + (rt * 16 + lr) * 64 + (((jc * 4 + lg) ^ (lr & 7)) << 3));
#pragma unroll
    for (int dt = 0; dt < 5; ++dt) {
      const int vrow = dt * 16 + lr;
      bf16x8 vf0 = *(const bf16x8*)(wls + vrow * 64 + (((0 * 4 + lg) ^ (lr & 7)) << 3));
      bf16x8 vf1 = *(const bf16x8*)(wls + vrow * 64 + (((1 * 4 + lg) ^ (lr & 7)) << 3));
#pragma unroll
      for (int rt = 0; rt < 4; ++rt) {
        acc[rt][dt] = __builtin_amdgcn_mfma_f32_16x16x32_bf16(pf[rt][0], vf0, acc[rt][dt], 0, 0, 0);
        acc[rt][dt] = __builtin_amdgcn_mfma_f32_16x16x32_bf16(pf[rt][1], vf1, acc[rt][dt], 0, 0, 0);
      }
    }
  }

  // normalize (den broadcast from lr==0 lane of same row-group) and write
#pragma unroll
  for (int rt = 0; rt < 4; ++rt) {
#pragma unroll
    for (int r = 0; r < 4; ++r) {
      float dn = __shfl(acc[rt][4][r], l & 48);
      float inv = 1.f / dn;
      int gr = rb * 256 + w * 64 + rt * 16 + lg * 4 + r;
      float* op = attn + (size_t)gr * 512 + h_ * 64;
#pragma unroll
      for (int dt = 0; dt < 4; ++dt)
        op[dt * 16 + lr] = acc[rt][dt][r] * inv;
    }
  }
}

// ---------------- depthwise res conv over sequence (kernel 33), adds into attn ----------------
__global__ __launch_bounds__(256) void resconv_kernel(
    const float* __restrict__ qkv, const float* __restrict__ rw, float* __restrict__ attn)
{
  int r = blockIdx.x;
  int c = blockIdx.y * 256 + threadIdx.x;
  int h_ = c >> 6;
  float s = 0.f;
#pragma unroll
  for (int tp = 0; tp < 33; ++tp) {
    int rr = r + tp - 16;
    if (rr >= 0 && rr < NPAD)
      s = fmaf(qkv[(size_t)rr * 1536 + 1024 + c], rw[h_ * 33 + tp], s);
  }
  attn[(size_t)r * 512 + c] += s;
}

// ---------------- weight transpose for ppeg: wt[k*512+c] ----------------
__global__ __launch_bounds__(256) void wtrans_kernel(
    const float* __restrict__ w7, const float* __restrict__ w5,
    const float* __restrict__ w3, float* __restrict__ wt)
{
  int c = blockIdx.x * 256 + threadIdx.x;
  for (int k = 0; k < 49; ++k) wt[(size_t)k * 512 + c]        = w7[(size_t)c * 49 + k];
  for (int k = 0; k < 25; ++k) wt[(size_t)(49 + k) * 512 + c] = w5[(size_t)c * 25 + k];
  for (int k = 0; k < 9;  ++k) wt[(size_t)(74 + k) * 512 + c] = w3[(size_t)c * 9 + k];
}

// ---------------- PPEG: weights staged in LDS (85KB), 256 ch x 64 px per block ----------
__global__ __launch_bounds__(256) void ppeg_kernel(
    const float* __restrict__ h, float* __restrict__ tmp,
    const float* __restrict__ wt,
    const float* __restrict__ b7, const float* __restrict__ b5,
    const float* __restrict__ b3)
{
  __shared__ float wl[83 * 256];
  const int t = threadIdx.x;
  const int c = blockIdx.y * 256 + t;
#pragma unroll
  for (int k = 0; k < 83; ++k)
    wl[k * 256 + t] = wt[(size_t)k * 512 + c];
  const float bsum = b7[c] + b5[c] + b3[c];
  __syncthreads();

  const int p0 = blockIdx.x * 64;
  for (int i = 0; i < 64; ++i) {
    int p = p0 + i;
    if (p >= NPIX) break;
    int y = p / SG, x = p - y * SG;
    float a7 = 0.f, a5 = 0.f, a3 = 0.f;
    if (y >= 3 && y <= SG - 4 && x >= 3 && x <= SG - 4) {
#pragma unroll
      for (int ky = 0; ky < 7; ++ky)
#pragma unroll
        for (int kx = 0; kx < 7; ++kx) {
          float v = h[(size_t)(1 + (y + ky - 3) * SG + (x + kx - 3)) * DD + c];
          a7 = fmaf(v, wl[(ky * 7 + kx) * 256 + t], a7);
          if (ky >= 1 && ky <= 5 && kx >= 1 && kx <= 5)
            a5 = fmaf(v, wl[(49 + (ky - 1) * 5 + (kx - 1)) * 256 + t], a5);
          if (ky >= 2 && ky <= 4 && kx >= 2 && kx <= 4)
            a3 = fmaf(v, wl[(74 + (ky - 2) * 3 + (kx - 2)) * 256 + t], a3);
        }
    } else {
#pragma unroll
      for (int ky = 0; ky < 7; ++ky) {
        int yy = y + ky - 3;
        bool oky = (yy >= 0 && yy < SG);
#pragma unroll
        for (int kx = 0; kx < 7; ++kx) {
          int xx = x + kx - 3;
          float v = (oky && xx >= 0 && xx < SG)
                        ? h[(size_t)(1 + yy * SG + xx) * DD + c] : 0.f;
          a7 = fmaf(v, wl[(ky * 7 + kx) * 256 + t], a7);
          if (ky >= 1 && ky <= 5 && kx >= 1 && kx <= 5)
            a5 = fmaf(v, wl[(49 + (ky - 1) * 5 + (kx - 1)) * 256 + t], a5);
          if (ky >= 2 && ky <= 4 && kx >= 2 && kx <= 4)
            a3 = fmaf(v, wl[(74 + (ky - 2) * 3 + (kx - 2)) * 256 + t], a3);
        }
      }
    }
    tmp[(size_t)p * DD + c] = h[(size_t)(1 + p) * DD + c] + bsum + a7 + a5 + a3;
  }
}

// ---------------- final: LN(row0) -> fc2 -> softmax/argmax ----------------
__global__ __launch_bounds__(256) void final_kernel(
    const float* __restrict__ h, const float* __restrict__ g, const float* __restrict__ b,
    const float* __restrict__ w, const float* __restrict__ bias, float* __restrict__ out)
{
  __shared__ float red[256];
  int t = threadIdx.x;
  float v0 = h[t], v1 = h[t + 256];
  red[t] = v0 + v1;
  __syncthreads();
  for (int s = 128; s > 0; s >>= 1) { if (t < s) red[t] += red[t + s]; __syncthreads(); }
  float mu = red[0] * (1.f / 512.f);
  __syncthreads();
  float d0 = v0 - mu, d1 = v1 - mu;
  red[t] = d0 * d0 + d1 * d1;
  __syncthreads();
  for (int s = 128; s > 0; s >>= 1) { if (t < s) red[t] += red[t + s]; __syncthreads(); }
  float rs = rsqrtf(red[0] * (1.f / 512.f) + 1e-5f);
  __syncthreads();
  float x0 = d0 * rs * g[t] + b[t];
  float x1 = d1 * rs * g[t + 256] + b[t + 256];
  red[t] = x0 * w[t * 2] + x1 * w[(t + 256) * 2];
  __syncthreads();
  for (int s = 128; s > 0; s >>= 1) { if (t < s) red[t] += red[t + s]; __syncthreads(); }
  float l0 = red[0] + bias[0];
  __syncthreads();
  red[t] = x0 * w[t * 2 + 1] + x1 * w[(t + 256) * 2 + 1];
  __syncthreads();
  for (int s = 128; s > 0; s >>= 1) { if (t < s) red[t] += red[t + s]; __syncthreads(); }
  float l1 = red[0] + bias[1];
  if (t == 0) {
    out[0] = l0; out[1] = l1;
    float mx = fmaxf(l0, l1);
    float e0 = __expf(l0 - mx), e1 = __expf(l1 - mx);
    float inv = 1.f / (e0 + e1);
    out[2] = e0 * inv; out[3] = e1 * inv;
    out[4] = (l1 > l0) ? 1.f : 0.f;
  }
}

extern "C" void kernel_launch(void* const* d_in, const int* in_sizes, int n_in,
                              void* d_out, int out_size, void* d_ws, size_t ws_size,
                              hipStream_t stream)
{
  const float* data   = (const float*)d_in[0];
  const float* fc1_w  = (const float*)d_in[1];
  const float* fc1_b  = (const float*)d_in[2];
  const float* cls    = (const float*)d_in[3];
  const float* l1_g   = (const float*)d_in[4];
  const float* l1_b   = (const float*)d_in[5];
  const float* l1_qkv = (const float*)d_in[6];
  const float* l1_ow  = (const float*)d_in[7];
  const float* l1_ob  = (const float*)d_in[8];
  const float* l1_rw  = (const float*)d_in[9];
  const float* w7     = (const float*)d_in[10];
  const float* b7     = (const float*)d_in[11];
  const float* w5     = (const float*)d_in[12];
  const float* b5     = (const float*)d_in[13];
  const float* w3     = (const float*)d_in[14];
  const float* b3     = (const float*)d_in[15];
  const float* l2_g   = (const float*)d_in[16];
  const float* l2_b   = (const float*)d_in[17];
  const float* l2_qkv = (const float*)d_in[18];
  const float* l2_ow  = (const float*)d_in[19];
  const float* l2_ob  = (const float*)d_in[20];
  const float* l2_rw  = (const float*)d_in[21];
  const float* ng     = (const float*)d_in[22];
  const float* nb     = (const float*)d_in[23];
  const float* fc2_w  = (const float*)d_in[24];
  const float* fc2_b  = (const float*)d_in[25];
  float* out = (float*)d_out;

  float* ws   = (float*)d_ws;
  float* h    = ws;
  float* xn   = h    + (size_t)16384 * 512;
  float* qkv  = xn   + (size_t)16384 * 512;
  float* attn = qkv  + (size_t)16384 * 1536;
  float* ql   = attn + (size_t)16384 * 512;
  float* kl   = ql   + 256 * 512;
  float* a2b  = kl   + 256 * 512;
  float* z0   = a2b  + 8 * 256 * 256;
  float* z1   = z0   + 8 * 256 * 256;
  float* xzb  = z1   + 8 * 256 * 256;
  float* tb   = xzb  + 8 * 256 * 256;
  float* ub   = tb   + 8 * 256 * 256;
  float* a3v  = ub   + 8 * 256 * 256;
  float* w2   = a3v  + 8 * 256 * 64;
  float* pacc = w2   + 8 * 256 * 64;           // dead region: bf16 weights carved here
  float* pms  = pacc + (size_t)8 * 32 * 256 * 64;
  float* red  = pms  + (size_t)8 * 32 * 256 * 2;
  float* wtb  = red  + 32;                       // ppeg weights fp32 (83*512)

  // bf16 transposed weights, carved from dead pacc region (2.62M ushorts << 16.8M floats)
  ushort* fc1_wt  = (ushort*)pacc;
  ushort* qkv_wt0 = fc1_wt + 512 * 1024;
  ushort* qkv_wt1 = qkv_wt0 + 1536 * 512;
  ushort* out_wt0 = qkv_wt1 + 1536 * 512;
  ushort* out_wt1 = out_wt0 + 512 * 512;

  // a3v MFMA partial buffers (alias xn scratch / pms as before)
  float* a3v_pacc = xn;
  float* a3v_den  = pms;

  // weight prep (bf16 transposes) + fc1 + assemble
  wtrans_bf<<<dim3(16, 32), 256, 0, stream>>>(fc1_w, fc1_wt, 1024, 512);
  wtrans_bf<<<dim3(48, 16), 256, 0, stream>>>(l1_qkv, qkv_wt0, 512, 1536);
  wtrans_bf<<<dim3(48, 16), 256, 0, stream>>>(l2_qkv, qkv_wt1, 512, 1536);
  wtrans_bf<<<dim3(16, 16), 256, 0, stream>>>(l1_ow, out_wt0, 512, 512);
  wtrans_bf<<<dim3(16, 16), 256, 0, stream>>>(l2_ow, out_wt1, 512, 512);
  wtrans_kernel<<<2, 256, 0, stream>>>(w7, w5, w3, wtb);

  gemm_bt<<<dim3(4, 125), 256, 0, stream>>>(data, 1024, fc1_wt, 1024, h + 512, 512,
                                            16000, 1024, 1, fc1_b);
  assemble_kernel<<<260, 256, 0, stream>>>(h, cls);

  for (int layer = 0; layer < 2; ++layer) {
    const float* gg = layer ? l2_g   : l1_g;
    const float* bb = layer ? l2_b   : l1_b;
    const ushort* qw = layer ? qkv_wt1 : qkv_wt0;
    const ushort* ow = layer ? out_wt1 : out_wt0;
    const float* ob = layer ? l2_ob  : l1_ob;
    const float* rw = layer ? l2_rw  : l1_rw;

    ln_pad_kernel<<<16384, 256, 0, stream>>>(h, xn, gg, bb);
    gemm_bt<<<dim3(12, 128), 256, 0, stream>>>(xn, 512, qw, 512, qkv, 1536,
                                               16384, 512, 2, nullptr);
    landmark_kernel<<<dim3(256, 4), 256, 0, stream>>>(qkv, ql, kl);
    a2_kernel<<<dim3(8, 256), 256, 0, stream>>>(ql, kl, a2b);
    pinv_red1<<<8, 256, 0, stream>>>(a2b, red);
    pinv_red2<<<1, 1, 0, stream>>>(red);
    pinv_init<<<dim3(8, 256), 256, 0, stream>>>(a2b, red, z0);
    float* zc = z0; float* zn = z1;
    for (int it = 0; it < 6; ++it) {
      nmm_kernel<<<dim3(4, 4, 8), 256, 0, stream>>>(a2b, zc, xzb, 0);  // xz = a2@z
      nmm_kernel<<<dim3(4, 4, 8), 256, 0, stream>>>(xzb, xzb, tb, 1);  // u1 = 7xz - xz@xz
      nmm_kernel<<<dim3(4, 4, 8), 256, 0, stream>>>(xzb, tb, ub, 2);   // u2 = 15xz - xz@u1
      nmm_kernel<<<dim3(4, 4, 8), 256, 0, stream>>>(zc, ub, zn, 3);    // z' = .25(13z - z@u2)
      float* sw = zc; zc = zn; zn = sw;
    }
    a3v_mfma<<<dim3(8, CHK), 256, 0, stream>>>(qkv, ql, a3v_pacc, a3v_den);
    a3v_merge_kernel<<<dim3(8, 256), 64, 0, stream>>>(a3v_pacc, a3v_den, a3v);
    mmb_kernel<<<dim3(1, 4, 8), 256, 0, stream>>>(zc, a3v, w2, 64, 1.f);
    a1_mfma<<<dim3(8, 64), 256, 0, stream>>>(qkv, kl, w2, attn);
    resconv_kernel<<<dim3(16384, 2), 256, 0, stream>>>(qkv, rw, attn);
    gemm_bt<<<dim3(4, 127), 256, 0, stream>>>(attn + (size_t)254 * 512, 512, ow, 512,
                                              h, 512, 16130, 512, 3, ob);
    if (layer == 0) {
      ppeg_kernel<<<dim3((NPIX + 63) / 64, 2), 256, 0, stream>>>(h, qkv, wtb, b7, b5, b3);
      hipMemcpyAsync(h + 512, qkv, (size_t)16129 * 512 * 4,
                     hipMemcpyDeviceToDevice, stream);
    }
  }
  final_kernel<<<1, 256, 0, stream>>>(h, ng, nb, fc2_w, fc2_b, out);
}

// Round 10
// 1632.728 us; speedup vs baseline: 3.5672x; 1.0470x over previous
//
#include <hip/hip_runtime.h>
#include <math.h>

#define NPAD   16384
#define PADR   254
#define NTOK   16130
#define NPIX   16129
#define SG     127
#define DD     512
#define NH     8
#define CHK    64          // key-chunks per head for a3v

typedef __attribute__((ext_vector_type(8))) short bf16x8;
typedef __attribute__((ext_vector_type(4))) float f32x4;

__device__ __forceinline__ ushort f2bf(float f) {
  uint u = __float_as_uint(f);
  u = (u + 0x7fffu + ((u >> 16) & 1u)) >> 16;
  return (ushort)u;
}

// ---------------- weight transpose+cvt: src fp32 [K][N] -> dst bf16 [N][K] ----------------
__global__ __launch_bounds__(256) void wtrans_bf(
    const float* __restrict__ src, ushort* __restrict__ dst, int K, int N)
{
  __shared__ float tile[32][33];
  int tx = threadIdx.x & 31, ty = threadIdx.x >> 5;   // 32 x 8
#pragma unroll
  for (int i = 0; i < 4; ++i) {
    int k = blockIdx.y * 32 + ty + i * 8, n = blockIdx.x * 32 + tx;
    tile[ty + i * 8][tx] = src[(size_t)k * N + n];
  }
  __syncthreads();
#pragma unroll
  for (int i = 0; i < 4; ++i) {
    int n = blockIdx.x * 32 + ty + i * 8, k = blockIdx.y * 32 + tx;
    dst[(size_t)n * K + k] = f2bf(tile[tx][ty + i * 8]);
  }
}

// ---------------- bf16 MFMA GEMM: C fp32 = A_f32 @ Bt_bf16^T ----------------
// A [M][lda] fp32 (converted in staging), Bt [N][ldb=K] bf16 row-major (pre-transposed W).
// 128x128 tile, BK=64, 4 waves (2x2 of 64x64). mode 1: relu(acc+bias); 2: q-scale; 3: C+=acc+bias.
__global__ __launch_bounds__(256) void gemm_bt(
    const float* __restrict__ A, int lda,
    const ushort* __restrict__ Bt, int ldb,
    float* __restrict__ C, int ldc,
    int M, int K, int mode, const float* __restrict__ bias)
{
  const int t = threadIdx.x;
  const int w = t >> 6, l = t & 63, lr = l & 15, lg = l >> 4;
  const int wr = w >> 1, wc = w & 1;
  const int m0 = blockIdx.y * 128, n0 = blockIdx.x * 128;
  __shared__ __align__(16) ushort As[128 * 64];
  __shared__ __align__(16) ushort Bs[128 * 64];
  f32x4 acc[4][4];
#pragma unroll
  for (int i = 0; i < 4; ++i)
#pragma unroll
    for (int j = 0; j < 4; ++j) acc[i][j] = (f32x4){0.f, 0.f, 0.f, 0.f};

  for (int k0 = 0; k0 < K; k0 += 64) {
    __syncthreads();
    // stage A: 128 rows x 4 chunks of 16 floats = 512 tasks, 2/thread
#pragma unroll
    for (int i = 0; i < 2; ++i) {
      int id = t + i * 256;
      int r = id >> 2, db = id & 3;
      const float* src = A + (size_t)(m0 + r) * lda + k0 + db * 16;
      float4 g0 = *(const float4*)(src + 0);
      float4 g1 = *(const float4*)(src + 4);
      float4 g2 = *(const float4*)(src + 8);
      float4 g3 = *(const float4*)(src + 12);
      bf16x8 e0, e1;
      e0[0] = f2bf(g0.x); e0[1] = f2bf(g0.y); e0[2] = f2bf(g0.z); e0[3] = f2bf(g0.w);
      e0[4] = f2bf(g1.x); e0[5] = f2bf(g1.y); e0[6] = f2bf(g1.z); e0[7] = f2bf(g1.w);
      e1[0] = f2bf(g2.x); e1[1] = f2bf(g2.y); e1[2] = f2bf(g2.z); e1[3] = f2bf(g2.w);
      e1[4] = f2bf(g3.x); e1[5] = f2bf(g3.y); e1[6] = f2bf(g3.z); e1[7] = f2bf(g3.w);
      ushort* dst = As + r * 64;
      *(bf16x8*)(dst + (((db * 2 + 0) ^ (r & 7)) << 3)) = e0;
      *(bf16x8*)(dst + (((db * 2 + 1) ^ (r & 7)) << 3)) = e1;
    }
    // stage B (already bf16): 128 rows x 8 blocks = 1024 tasks, 4/thread
#pragma unroll
    for (int i = 0; i < 4; ++i) {
      int id = t + i * 256;
      int r = id >> 3, blk = id & 7;
      bf16x8 v = *(const bf16x8*)(Bt + (size_t)(n0 + r) * ldb + k0 + blk * 8);
      *(bf16x8*)(Bs + r * 64 + ((blk ^ (r & 7)) << 3)) = v;
    }
    __syncthreads();
    bf16x8 af[4][2], bfr[4][2];
#pragma unroll
    for (int rt = 0; rt < 4; ++rt) {
      int row = wr * 64 + rt * 16 + lr;
#pragma unroll
      for (int kc = 0; kc < 2; ++kc)
        af[rt][kc] = *(const bf16x8*)(As + row * 64 + (((kc * 4 + lg) ^ (row & 7)) << 3));
    }
#pragma unroll
    for (int nt = 0; nt < 4; ++nt) {
      int row = wc * 64 + nt * 16 + lr;
#pragma unroll
      for (int kc = 0; kc < 2; ++kc)
        bfr[nt][kc] = *(const bf16x8*)(Bs + row * 64 + (((kc * 4 + lg) ^ (row & 7)) << 3));
    }
#pragma unroll
    for (int rt = 0; rt < 4; ++rt)
#pragma unroll
      for (int nt = 0; nt < 4; ++nt) {
        acc[rt][nt] = __builtin_amdgcn_mfma_f32_16x16x32_bf16(af[rt][0], bfr[nt][0], acc[rt][nt], 0, 0, 0);
        acc[rt][nt] = __builtin_amdgcn_mfma_f32_16x16x32_bf16(af[rt][1], bfr[nt][1], acc[rt][nt], 0, 0, 0);
      }
  }
#pragma unroll
  for (int rt = 0; rt < 4; ++rt) {
#pragma unroll
    for (int r = 0; r < 4; ++r) {
      int gi = m0 + wr * 64 + rt * 16 + lg * 4 + r;
      if (gi >= M) continue;
#pragma unroll
      for (int nt = 0; nt < 4; ++nt) {
        int gj = n0 + wc * 64 + nt * 16 + lr;
        float d = acc[rt][nt][r];
        if (mode == 1) d = fmaxf(d + bias[gj], 0.f);
        else if (mode == 2) { if (gj < 512) d *= 0.125f; }
        else if (mode == 3) d += C[(size_t)gi * ldc + gj] + bias[gj];
        C[(size_t)gi * ldc + gj] = d;
      }
    }
  }
}

// ---------------- fused Newton-step matmul: D = A@B (bf16 MFMA), C = f(A[ij], D) ----------
// batched 8 heads of 256x256. B transposed during staging. modes:
// 0: C=D ; 1: C=7A-D ; 2: C=15A-D ; 3: C=0.25*(13A-D)
__global__ __launch_bounds__(256) void nmm_kernel(
    const float* __restrict__ A, const float* __restrict__ B,
    float* __restrict__ C, int mode)
{
  const int h_ = blockIdx.z;
  const int m0 = blockIdx.y * 64, n0 = blockIdx.x * 64;
  const float* Ah = A + (size_t)h_ * 65536;
  const float* Bh = B + (size_t)h_ * 65536;
  float* Ch = C + (size_t)h_ * 65536;
  const int t = threadIdx.x, w = t >> 6, l = t & 63, lr = l & 15, lg = l >> 4;
  __shared__ __align__(16) ushort Xs[64 * 64];
  __shared__ __align__(16) ushort Ys[64 * 64];
  f32x4 acc[4];
#pragma unroll
  for (int nt = 0; nt < 4; ++nt) acc[nt] = (f32x4){0.f, 0.f, 0.f, 0.f};

  for (int k0 = 0; k0 < 256; k0 += 64) {
    __syncthreads();
    // stage A rows (direct): 64 rows x 4 chunks of 16 -> 256 tasks, 1/thread
    {
      int r = t >> 2, db = t & 3;
      const float* src = Ah + (size_t)(m0 + r) * 256 + k0 + db * 16;
      float4 g0 = *(const float4*)(src + 0);
      float4 g1 = *(const float4*)(src + 4);
      float4 g2 = *(const float4*)(src + 8);
      float4 g3 = *(const float4*)(src + 12);
      bf16x8 e0, e1;
      e0[0] = f2bf(g0.x); e0[1] = f2bf(g0.y); e0[2] = f2bf(g0.z); e0[3] = f2bf(g0.w);
      e0[4] = f2bf(g1.x); e0[5] = f2bf(g1.y); e0[6] = f2bf(g1.z); e0[7] = f2bf(g1.w);
      e1[0] = f2bf(g2.x); e1[1] = f2bf(g2.y); e1[2] = f2bf(g2.z); e1[3] = f2bf(g2.w);
      e1[4] = f2bf(g3.x); e1[5] = f2bf(g3.y); e1[6] = f2bf(g3.z); e1[7] = f2bf(g3.w);
      ushort* dst = Xs + r * 64;
      *(bf16x8*)(dst + (((db * 2 + 0) ^ (r & 7)) << 3)) = e0;
      *(bf16x8*)(dst + (((db * 2 + 1) ^ (r & 7)) << 3)) = e1;
    }
    // stage B transposed: 64 k-rows x 16 float4 = 1024 tasks, 4/thread
#pragma unroll
    for (int i = 0; i < 4; ++i) {
      int id = t + i * 256;
      int k = id >> 4, q = id & 15;
      float4 v = *(const float4*)(Bh + (size_t)(k0 + k) * 256 + n0 + q * 4);
      int kb = k >> 3, ke = k & 7;
      Ys[(q * 4 + 0) * 64 + ((kb ^ ((q * 4 + 0) & 7)) << 3) + ke] = f2bf(v.x);
      Ys[(q * 4 + 1) * 64 + ((kb ^ ((q * 4 + 1) & 7)) << 3) + ke] = f2bf(v.y);
      Ys[(q * 4 + 2) * 64 + ((kb ^ ((q * 4 + 2) & 7)) << 3) + ke] = f2bf(v.z);
      Ys[(q * 4 + 3) * 64 + ((kb ^ ((q * 4 + 3) & 7)) << 3) + ke] = f2bf(v.w);
    }
    __syncthreads();
    int arow = w * 16 + lr;
    bf16x8 af0 = *(const bf16x8*)(Xs + arow * 64 + (((0 + lg) ^ (arow & 7)) << 3));
    bf16x8 af1 = *(const bf16x8*)(Xs + arow * 64 + (((4 + lg) ^ (arow & 7)) << 3));
#pragma unroll
    for (int nt = 0; nt < 4; ++nt) {
      int brow = nt * 16 + lr;
      bf16x8 bf0 = *(const bf16x8*)(Ys + brow * 64 + (((0 + lg) ^ (brow & 7)) << 3));
      bf16x8 bf1 = *(const bf16x8*)(Ys + brow * 64 + (((4 + lg) ^ (brow & 7)) << 3));
      acc[nt] = __builtin_amdgcn_mfma_f32_16x16x32_bf16(af0, bf0, acc[nt], 0, 0, 0);
      acc[nt] = __builtin_amdgcn_mfma_f32_16x16x32_bf16(af1, bf1, acc[nt], 0, 0, 0);
    }
  }
#pragma unroll
  for (int nt = 0; nt < 4; ++nt) {
#pragma unroll
    for (int r = 0; r < 4; ++r) {
      int gi = m0 + w * 16 + lg * 4 + r;
      int gj = n0 + nt * 16 + lr;
      float d = acc[nt][r];
      if (mode == 1)      d = 7.f * Ah[(size_t)gi * 256 + gj] - d;
      else if (mode == 2) d = 15.f * Ah[(size_t)gi * 256 + gj] - d;
      else if (mode == 3) d = 0.25f * (13.f * Ah[(size_t)gi * 256 + gj] - d);
      Ch[(size_t)gi * 256 + gj] = d;
    }
  }
}

// ---------------- assemble: h[0]=cls, h[16001+i]=h[1+i] (i<129) ----------------
__global__ __launch_bounds__(256) void assemble_kernel(float* __restrict__ h,
                                                       const float* __restrict__ cls)
{
  int idx = blockIdx.x * 256 + threadIdx.x;
  if (idx < 512) { h[idx] = cls[idx]; return; }
  idx -= 512;
  int i = idx >> 9, c = idx & 511;
  h[(size_t)(16001 + i) * DD + c] = h[(size_t)(1 + i) * DD + c];
}

// ---------------- LayerNorm rows of h -> xn (front-padded, rows<PADR zeroed) ----------------
__global__ __launch_bounds__(256) void ln_pad_kernel(
    const float* __restrict__ h, float* __restrict__ xn,
    const float* __restrict__ g, const float* __restrict__ b)
{
  int row = blockIdx.x;
  int t = threadIdx.x;
  if (row < PADR) {
    xn[(size_t)row * DD + t] = 0.f;
    xn[(size_t)row * DD + t + 256] = 0.f;
    return;
  }
  const float* x = h + (size_t)(row - PADR) * DD;
  __shared__ float red[256];
  float v0 = x[t], v1 = x[t + 256];
  red[t] = v0 + v1;
  __syncthreads();
  for (int s = 128; s > 0; s >>= 1) { if (t < s) red[t] += red[t + s]; __syncthreads(); }
  float mu = red[0] * (1.f / 512.f);
  __syncthreads();
  float d0 = v0 - mu, d1 = v1 - mu;
  red[t] = d0 * d0 + d1 * d1;
  __syncthreads();
  for (int s = 128; s > 0; s >>= 1) { if (t < s) red[t] += red[t + s]; __syncthreads(); }
  float rs = rsqrtf(red[0] * (1.f / 512.f) + 1e-5f);
  float* o = xn + (size_t)row * DD;
  o[t]       = d0 * rs * g[t] + b[t];
  o[t + 256] = d1 * rs * g[t + 256] + b[t + 256];
}

// ---------------- landmarks ----------------
__global__ __launch_bounds__(256) void landmark_kernel(
    const float* __restrict__ qkv, float* __restrict__ ql, float* __restrict__ kl)
{
  int i = blockIdx.x;
  int c = blockIdx.y * 256 + threadIdx.x;
  const float* p = qkv + (size_t)(i * 64) * 1536 + c;
  float s = 0.f;
  for (int j = 0; j < 64; ++j) s += p[(size_t)j * 1536];
  s *= (1.f / 64.f);
  if (c < 512) ql[(size_t)i * 512 + c] = s;
  else         kl[(size_t)i * 512 + (c - 512)] = s;
}

// ---------------- a2 = softmax(ql . kl^T) per head ----------------
__global__ __launch_bounds__(256) void a2_kernel(
    const float* __restrict__ ql, const float* __restrict__ kl, float* __restrict__ a2)
{
  int h_ = blockIdx.x, i = blockIdx.y;
  int t = threadIdx.x;
  __shared__ float q[64];
  __shared__ float red[256];
  if (t < 64) q[t] = ql[(size_t)i * 512 + h_ * 64 + t];
  __syncthreads();
  const float* kr = kl + (size_t)t * 512 + h_ * 64;
  float s = 0.f;
#pragma unroll
  for (int d = 0; d < 64; ++d) s = fmaf(q[d], kr[d], s);
  red[t] = s;
  __syncthreads();
  for (int st = 128; st > 0; st >>= 1) { if (t < st) red[t] = fmaxf(red[t], red[t + st]); __syncthreads(); }
  float mx = red[0];
  __syncthreads();
  float e = __expf(s - mx);
  red[t] = e;
  __syncthreads();
  for (int st = 128; st > 0; st >>= 1) { if (t < st) red[t] += red[t + st]; __syncthreads(); }
  a2[((size_t)h_ * 256 + i) * 256 + t] = e / red[0];
}

// ---------------- pinv init reductions ----------------
__global__ __launch_bounds__(256) void pinv_red1(const float* __restrict__ a2, float* __restrict__ red)
{
  int h_ = blockIdx.x, t = threadIdx.x;
  const float* X = a2 + (size_t)h_ * 65536;
  float rs = 0.f, cs = 0.f;
  for (int j = 0; j < 256; ++j) rs += fabsf(X[(size_t)t * 256 + j]);
  for (int i = 0; i < 256; ++i) cs += fabsf(X[(size_t)i * 256 + t]);
  __shared__ float r1[256], r2[256];
  r1[t] = rs; r2[t] = cs;
  __syncthreads();
  for (int s = 128; s > 0; s >>= 1) {
    if (t < s) { r1[t] = fmaxf(r1[t], r1[t + s]); r2[t] = fmaxf(r2[t], r2[t + s]); }
    __syncthreads();
  }
  if (t == 0) { red[h_ * 2] = r1[0]; red[h_ * 2 + 1] = r2[0]; }
}
__global__ void pinv_red2(float* __restrict__ red)
{
  float mr = 0.f, mc = 0.f;
  for (int h_ = 0; h_ < 8; ++h_) { mr = fmaxf(mr, red[h_ * 2]); mc = fmaxf(mc, red[h_ * 2 + 1]); }
  red[16] = 1.f / (mr * mc);
}
__global__ __launch_bounds__(256) void pinv_init(
    const float* __restrict__ a2, const float* __restrict__ red, float* __restrict__ z)
{
  int h_ = blockIdx.x, i = blockIdx.y, j = threadIdx.x;
  float inv = red[16];
  z[((size_t)h_ * 256 + i) * 256 + j] = a2[((size_t)h_ * 256 + j) * 256 + i] * inv;
}

// ---------------- batched matmul per head: C = alpha*(A @ B), A 256x256, B 256xN ----------------
__global__ __launch_bounds__(256) void mmb_kernel(
    const float* __restrict__ A, const float* __restrict__ B, float* __restrict__ C,
    int N, float alpha)
{
  int h_ = blockIdx.z;
  const float* Ah = A + (size_t)h_ * 256 * 256;
  const float* Bh = B + (size_t)h_ * 256 * N;
  float* Ch = C + (size_t)h_ * 256 * N;
  int m0 = blockIdx.y * 64, n0 = blockIdx.x * 64;
  __shared__ float As[16][68];
  __shared__ float Bs[16][68];
  int tid = threadIdx.x, tx = tid & 15, ty = tid >> 4;
  float acc[4][4];
#pragma unroll
  for (int i = 0; i < 4; ++i)
#pragma unroll
    for (int j = 0; j < 4; ++j) acc[i][j] = 0.f;
  for (int k0 = 0; k0 < 256; k0 += 16) {
    {
      int row = tid >> 2, k4 = (tid & 3) << 2;
      float4 v = *(const float4*)(Ah + (size_t)(m0 + row) * 256 + k0 + k4);
      As[k4 + 0][row] = v.x; As[k4 + 1][row] = v.y;
      As[k4 + 2][row] = v.z; As[k4 + 3][row] = v.w;
    }
    {
      int row = tid >> 4, c4 = (tid & 15) << 2;
      *(float4*)&Bs[row][c4] = *(const float4*)(Bh + (size_t)(k0 + row) * N + n0 + c4);
    }
    __syncthreads();
#pragma unroll
    for (int k = 0; k < 16; ++k) {
      float a[4], b[4];
      *(float4*)a = *(const float4*)&As[k][ty * 4];
      *(float4*)b = *(const float4*)&Bs[k][tx * 4];
#pragma unroll
      for (int i = 0; i < 4; ++i)
#pragma unroll
        for (int j = 0; j < 4; ++j) acc[i][j] = fmaf(a[i], b[j], acc[i][j]);
    }
    __syncthreads();
  }
#pragma unroll
  for (int i = 0; i < 4; ++i) {
    float4 r;
    r.x = alpha * acc[i][0]; r.y = alpha * acc[i][1];
    r.z = alpha * acc[i][2]; r.w = alpha * acc[i][3];
    *(float4*)(Ch + (size_t)(m0 + ty * 4 + i) * N + n0 + tx * 4) = r;
  }
}

// ---------------- a3@v partials via bf16 MFMA flash (no-max exp, ones-column den) ----------
__global__ __launch_bounds__(256) void a3v_mfma(
    const float* __restrict__ qkv, const float* __restrict__ ql,
    float* __restrict__ pacc, float* __restrict__ den)
{
  const int h_ = blockIdx.x;
  const int ch = blockIdx.y;
  const int t  = threadIdx.x;
  const int w  = t >> 6;
  const int l  = t & 63;
  const int lr = l & 15;
  const int lg = l >> 4;

  __shared__ __align__(16) ushort kls[64 * 64];
  __shared__ __align__(16) ushort vls[80 * 64];
  __shared__ __align__(16) ushort pls[4][64 * 64];

  bf16x8 qf[4][2];
#pragma unroll
  for (int rt = 0; rt < 4; ++rt)
#pragma unroll
    for (int dc = 0; dc < 2; ++dc) {
      const float* p = ql + (size_t)(64 * w + rt * 16 + lr) * 512 + h_ * 64 + dc * 32 + lg * 8;
      float4 f0 = *(const float4*)p;
      float4 f1 = *(const float4*)(p + 4);
      bf16x8 v;
      v[0] = f2bf(f0.x); v[1] = f2bf(f0.y); v[2] = f2bf(f0.z); v[3] = f2bf(f0.w);
      v[4] = f2bf(f1.x); v[5] = f2bf(f1.y); v[6] = f2bf(f1.z); v[7] = f2bf(f1.w);
      qf[rt][dc] = v;
    }

  if (t < 128) {
    int rr = t >> 3, cb = t & 7;
    ushort val = (rr == 0) ? (ushort)0x3f80 : (ushort)0;
    bf16x8 vv;
#pragma unroll
    for (int k = 0; k < 8; ++k) vv[k] = (short)val;
    *(bf16x8*)(vls + (64 + rr) * 64 + ((cb ^ (rr & 7)) << 3)) = vv;
  }

  f32x4 acc[4][5];
#pragma unroll
  for (int rt = 0; rt < 4; ++rt)
#pragma unroll
    for (int dt = 0; dt < 5; ++dt) acc[rt][dt] = (f32x4){0.f, 0.f, 0.f, 0.f};

  const int j0base = ch * 256;
  for (int jt = 0; jt < 4; ++jt) {
    const int j0 = j0base + jt * 64;
    __syncthreads();
    {
      int r = t >> 2, db = t & 3;
      const float* src = qkv + (size_t)(j0 + r) * 1536 + 512 + h_ * 64 + db * 16;
      float4 g0 = *(const float4*)(src + 0);
      float4 g1 = *(const float4*)(src + 4);
      float4 g2 = *(const float4*)(src + 8);
      float4 g3 = *(const float4*)(src + 12);
      bf16x8 e0, e1;
      e0[0] = f2bf(g0.x); e0[1] = f2bf(g0.y); e0[2] = f2bf(g0.z); e0[3] = f2bf(g0.w);
      e0[4] = f2bf(g1.x); e0[5] = f2bf(g1.y); e0[6] = f2bf(g1.z); e0[7] = f2bf(g1.w);
      e1[0] = f2bf(g2.x); e1[1] = f2bf(g2.y); e1[2] = f2bf(g2.z); e1[3] = f2bf(g2.w);
      e1[4] = f2bf(g3.x); e1[5] = f2bf(g3.y); e1[6] = f2bf(g3.z); e1[7] = f2bf(g3.w);
      ushort* base = kls + r * 64;
      *(bf16x8*)(base + (((db * 2 + 0) ^ (r & 7)) << 3)) = e0;
      *(bf16x8*)(base + (((db * 2 + 1) ^ (r & 7)) << 3)) = e1;
    }
    {
      int d = t & 63, jg = t >> 6;
#pragma unroll
      for (int half = 0; half < 2; ++half) {
        int jb = jg + half * 4;
        bf16x8 e;
#pragma unroll
        for (int jj = 0; jj < 8; ++jj)
          e[jj] = f2bf(qkv[(size_t)(j0 + jb * 8 + jj) * 1536 + 1024 + h_ * 64 + d]);
        *(bf16x8*)(vls + d * 64 + ((jb ^ (d & 7)) << 3)) = e;
      }
    }
    __syncthreads();

    ushort* pw = pls[w];
#pragma unroll
    for (int sjt = 0; sjt < 4; ++sjt) {
      const int krow = sjt * 16 + lr;
      bf16x8 kf0 = *(const bf16x8*)(kls + krow * 64 + (((0 * 4 + lg) ^ (lr & 7)) << 3));
      bf16x8 kf1 = *(const bf16x8*)(kls + krow * 64 + (((1 * 4 + lg) ^ (lr & 7)) << 3));
#pragma unroll
      for (int rt = 0; rt < 4; ++rt) {
        f32x4 s = (f32x4){0.f, 0.f, 0.f, 0.f};
        s = __builtin_amdgcn_mfma_f32_16x16x32_bf16(qf[rt][0], kf0, s, 0, 0, 0);
        s = __builtin_amdgcn_mfma_f32_16x16x32_bf16(qf[rt][1], kf1, s, 0, 0, 0);
#pragma unroll
        for (int r = 0; r < 4; ++r) {
          int i  = rt * 16 + lg * 4 + r;
          int jj = sjt * 16 + lr;
          pw[i * 64 + ((((jj >> 3) ^ (i & 7)) << 3)) + (jj & 7)] = (short)f2bf(__expf(s[r]));
        }
      }
    }
    bf16x8 pf[4][2];
#pragma unroll
    for (int rt = 0; rt < 4; ++rt)
#pragma unroll
      for (int jc = 0; jc < 2; ++jc)
        pf[rt][jc] = *(const bf16x8*)(pw + (rt * 16 + lr) * 64 + (((jc * 4 + lg) ^ (lr & 7)) << 3));
#pragma unroll
    for (int dt = 0; dt < 5; ++dt) {
      const int vrow = dt * 16 + lr;
      bf16x8 vf0 = *(const bf16x8*)(vls + vrow * 64 + (((0 * 4 + lg) ^ (lr & 7)) << 3));
      bf16x8 vf1 = *(const bf16x8*)(vls + vrow * 64 + (((1 * 4 + lg) ^ (lr & 7)) << 3));
#pragma unroll
      for (int rt = 0; rt < 4; ++rt) {
        acc[rt][dt] = __builtin_amdgcn_mfma_f32_16x16x32_bf16(pf[rt][0], vf0, acc[rt][dt], 0, 0, 0);
        acc[rt][dt] = __builtin_amdgcn_mfma_f32_16x16x32_bf16(pf[rt][1], vf1, acc[rt][dt], 0, 0, 0);
      }
    }
  }

  const size_t pbase = (size_t)(h_ * CHK + ch) * 256;
#pragma unroll
  for (int rt = 0; rt < 4; ++rt) {
    int i = 64 * w + rt * 16 + lg * 4;
#pragma unroll
    for (int dt = 0; dt < 4; ++dt)
#pragma unroll
      for (int r = 0; r < 4; ++r)
        pacc[(pbase + i + r) * 64 + dt * 16 + lr] = acc[rt][dt][r];
    if (lr == 0) {
#pragma unroll
      for (int r = 0; r < 4; ++r)
        den[pbase + i + r] = acc[rt][4][r];
    }
  }
}

// ---------------- merge a3v partials ----------------
__global__ __launch_bounds__(64) void a3v_merge_kernel(
    const float* __restrict__ pacc, const float* __restrict__ den, float* __restrict__ a3v)
{
  int h_ = blockIdx.x, i = blockIdx.y, d = threadIdx.x;
  float S = 0.f, o = 0.f;
  for (int c = 0; c < CHK; ++c) {
    size_t b = (size_t)(h_ * CHK + c) * 256 + i;
    o += pacc[b * 64 + d];
    S += den[b];
  }
  a3v[((size_t)h_ * 256 + i) * 64 + d] = o / S;
}

// ---------------- a1: out = softmax(q . kl^T) @ w2 via bf16 MFMA ----------------
__global__ __launch_bounds__(256) void a1_mfma(
    const float* __restrict__ qkv, const float* __restrict__ kl,
    const float* __restrict__ w2, float* __restrict__ attn)
{
  const int h_ = blockIdx.x;
  const int rb = blockIdx.y;
  const int t  = threadIdx.x;
  const int w  = t >> 6, l = t & 63, lr = l & 15, lg = l >> 4;

  __shared__ __align__(16) ushort kls[64 * 64];
  __shared__ __align__(16) ushort wls[80 * 64];
  __shared__ __align__(16) ushort pls[4][64 * 64];

  bf16x8 qf[4][2];
#pragma unroll
  for (int rt = 0; rt < 4; ++rt)
#pragma unroll
    for (int dc = 0; dc < 2; ++dc) {
      const float* p = qkv + (size_t)(rb * 256 + w * 64 + rt * 16 + lr) * 1536 + h_ * 64 + dc * 32 + lg * 8;
      float4 f0 = *(const float4*)p;
      float4 f1 = *(const float4*)(p + 4);
      bf16x8 v;
      v[0] = f2bf(f0.x); v[1] = f2bf(f0.y); v[2] = f2bf(f0.z); v[3] = f2bf(f0.w);
      v[4] = f2bf(f1.x); v[5] = f2bf(f1.y); v[6] = f2bf(f1.z); v[7] = f2bf(f1.w);
      qf[rt][dc] = v;
    }

  if (t < 128) {
    int rr = t >> 3, cb = t & 7;
    ushort val = (rr == 0) ? (ushort)0x3f80 : (ushort)0;
    bf16x8 vv;
#pragma unroll
    for (int k = 0; k < 8; ++k) vv[k] = (short)val;
    *(bf16x8*)(wls + (64 + rr) * 64 + ((cb ^ (rr & 7)) << 3)) = vv;
  }

  f32x4 acc[4][5];
#pragma unroll
  for (int rt = 0; rt < 4; ++rt)
#pragma unroll
    for (int dt = 0; dt < 5; ++dt) acc[rt][dt] = (f32x4){0.f, 0.f, 0.f, 0.f};

  for (int kc = 0; kc < 4; ++kc) {
    const int j0 = kc * 64;
    __syncthreads();
    {
      int r = t >> 2, db = t & 3;
      const float* src = kl + (size_t)(j0 + r) * 512 + h_ * 64 + db * 16;
      float4 g0 = *(const float4*)(src + 0);
      float4 g1 = *(const float4*)(src + 4);
      float4 g2 = *(const float4*)(src + 8);
      float4 g3 = *(const float4*)(src + 12);
      bf16x8 e0, e1;
      e0[0] = f2bf(g0.x); e0[1] = f2bf(g0.y); e0[2] = f2bf(g0.z); e0[3] = f2bf(g0.w);
      e0[4] = f2bf(g1.x); e0[5] = f2bf(g1.y); e0[6] = f2bf(g1.z); e0[7] = f2bf(g1.w);
      e1[0] = f2bf(g2.x); e1[1] = f2bf(g2.y); e1[2] = f2bf(g2.z); e1[3] = f2bf(g2.w);
      e1[4] = f2bf(g3.x); e1[5] = f2bf(g3.y); e1[6] = f2bf(g3.z); e1[7] = f2bf(g3.w);
      ushort* base = kls + r * 64;
      *(bf16x8*)(base + (((db * 2 + 0) ^ (r & 7)) << 3)) = e0;
      *(bf16x8*)(base + (((db * 2 + 1) ^ (r & 7)) << 3)) = e1;
    }
    {
      int d = t & 63, jg = t >> 6;
#pragma unroll
      for (int half = 0; half < 2; ++half) {
        int jb = jg + half * 4;
        bf16x8 e;
#pragma unroll
        for (int jj = 0; jj < 8; ++jj)
          e[jj] = f2bf(w2[((size_t)h_ * 256 + j0 + jb * 8 + jj) * 64 + d]);
        *(bf16x8*)(wls + d * 64 + ((jb ^ (d & 7)) << 3)) = e;
      }
    }
    __syncthreads();

    ushort* pw = pls[w];
#pragma unroll
    for (int sjt = 0; sjt < 4; ++sjt) {
      const int krow = sjt * 16 + lr;
      bf16x8 kf0 = *(const bf16x8*)(kls + krow * 64 + (((0 * 4 + lg) ^ (lr & 7)) << 3));
      bf16x8 kf1 = *(const bf16x8*)(kls + krow * 64 + (((1 * 4 + lg) ^ (lr & 7)) << 3));
#pragma unroll
      for (int rt = 0; rt < 4; ++rt) {
        f32x4 s = (f32x4){0.f, 0.f, 0.f, 0.f};
        s = __builtin_amdgcn_mfma_f32_16x16x32_bf16(qf[rt][0], kf0, s, 0, 0, 0);
        s = __builtin_amdgcn_mfma_f32_16x16x32_bf16(qf[rt][1], kf1, s, 0, 0, 0);
#pragma unroll
        for (int r = 0; r < 4; ++r) {
          int i  = rt * 16 + lg * 4 + r;
          int jj = sjt * 16 + lr;
          pw[i * 64 + ((((jj >> 3) ^ (i & 7)) << 3)) + (jj & 7)] = (short)f2bf(__expf(s[r]));
        }
      }
    }
    bf16x8 pf[4][2];
#pragma unroll
    for (int rt = 0; rt < 4; ++rt)
#pragma unroll
      for (int jc = 0; jc < 2; ++jc)
        pf[rt][jc] = *(const bf16x8*)(pw + (rt * 16 + lr) * 64 + (((jc * 4 + lg) ^ (lr & 7)) << 3));
#pragma unroll
    for (int dt = 0; dt < 5; ++dt) {
      const int vrow = dt * 16 + lr;
      bf16x8 vf0 = *(const bf16x8*)(wls + vrow * 64 + (((0 * 4 + lg) ^ (lr & 7)) << 3));
      bf16x8 vf1 = *(const bf16x8*)(wls + vrow * 64 + (((1 * 4 + lg) ^ (lr & 7)) << 3));
#pragma unroll
      for (int rt = 0; rt < 4; ++rt) {
        acc[rt][dt] = __builtin_amdgcn_mfma_f32_16x16x32_bf16(pf[rt][0], vf0, acc[rt][dt], 0, 0, 0);
        acc[rt][dt] = __builtin_amdgcn_mfma_f32_16x16x32_bf16(pf[rt][1], vf1, acc[rt][dt], 0, 0, 0);
      }
    }
  }

#pragma unroll
  for (int rt = 0; rt < 4; ++rt) {
#pragma unroll
    for (int r = 0; r < 4; ++r) {
      float dn = __shfl(acc[rt][4][r], l & 48);
      float inv = 1.f / dn;
      int gr = rb * 256 + w * 64 + rt * 16 + lg * 4 + r;
      float* op = attn + (size_t)gr * 512 + h_ * 64;
#pragma unroll
      for (int dt = 0; dt < 4; ++dt)
        op[dt * 16 + lr] = acc[rt][dt][r] * inv;
    }
  }
}

// ---------------- depthwise res conv over sequence (kernel 33), adds into attn ----------------
__global__ __launch_bounds__(256) void resconv_kernel(
    const float* __restrict__ qkv, const float* __restrict__ rw, float* __restrict__ attn)
{
  int r = blockIdx.x;
  int c = blockIdx.y * 256 + threadIdx.x;
  int h_ = c >> 6;
  float s = 0.f;
#pragma unroll
  for (int tp = 0; tp < 33; ++tp) {
    int rr = r + tp - 16;
    if (rr >= 0 && rr < NPAD)
      s = fmaf(qkv[(size_t)rr * 1536 + 1024 + c], rw[h_ * 33 + tp], s);
  }
  attn[(size_t)r * 512 + c] += s;
}

// ---------------- weight transpose for ppeg: wt[k*512+c] ----------------
__global__ __launch_bounds__(256) void wtrans_kernel(
    const float* __restrict__ w7, const float* __restrict__ w5,
    const float* __restrict__ w3, float* __restrict__ wt)
{
  int c = blockIdx.x * 256 + threadIdx.x;
  for (int k = 0; k < 49; ++k) wt[(size_t)k * 512 + c]        = w7[(size_t)c * 49 + k];
  for (int k = 0; k < 25; ++k) wt[(size_t)(49 + k) * 512 + c] = w5[(size_t)c * 25 + k];
  for (int k = 0; k < 9;  ++k) wt[(size_t)(74 + k) * 512 + c] = w3[(size_t)c * 9 + k];
}

// ---------------- PPEG: 128 ch x 2-px-parallel per block, weights in 42.5KB LDS ----------
// grid (ceil(NPIX/64), 4); 3 blocks/CU (vs 1 at 85KB). ppar = t>>7 is wave-uniform.
// Writes tmp[p*DD+c] (round-7 proven data flow: tmp=qkv scratch, memcpy back after).
__global__ __launch_bounds__(256) void ppeg_kernel(
    const float* __restrict__ h, float* __restrict__ tmp,
    const float* __restrict__ wt,
    const float* __restrict__ b7, const float* __restrict__ b5,
    const float* __restrict__ b3)
{
  __shared__ float wl[83 * 128];           // 42,496 B
  const int t = threadIdx.x;
  const int tc = t & 127;
  const int ppar = t >> 7;
  const int c = blockIdx.y * 128 + tc;
  for (int idx = t; idx < 83 * 128; idx += 256)
    wl[idx] = wt[(size_t)(idx >> 7) * 512 + blockIdx.y * 128 + (idx & 127)];
  const float bsum = b7[c] + b5[c] + b3[c];
  __syncthreads();

  const int p0 = blockIdx.x * 64;
  for (int i = 0; i < 32; ++i) {
    int p = p0 + i * 2 + ppar;
    if (p >= NPIX) break;                  // wave-uniform (ppar uniform per wave)
    int y = p / SG, x = p - y * SG;
    float a7 = 0.f, a5 = 0.f, a3 = 0.f;
    if (y >= 3 && y <= SG - 4 && x >= 3 && x <= SG - 4) {
#pragma unroll
      for (int ky = 0; ky < 7; ++ky)
#pragma unroll
        for (int kx = 0; kx < 7; ++kx) {
          float v = h[(size_t)(1 + (y + ky - 3) * SG + (x + kx - 3)) * DD + c];
          a7 = fmaf(v, wl[(ky * 7 + kx) * 128 + tc], a7);
          if (ky >= 1 && ky <= 5 && kx >= 1 && kx <= 5)
            a5 = fmaf(v, wl[(49 + (ky - 1) * 5 + (kx - 1)) * 128 + tc], a5);
          if (ky >= 2 && ky <= 4 && kx >= 2 && kx <= 4)
            a3 = fmaf(v, wl[(74 + (ky - 2) * 3 + (kx - 2)) * 128 + tc], a3);
        }
    } else {
#pragma unroll
      for (int ky = 0; ky < 7; ++ky) {
        int yy = y + ky - 3;
        bool oky = (yy >= 0 && yy < SG);
#pragma unroll
        for (int kx = 0; kx < 7; ++kx) {
          int xx = x + kx - 3;
          float v = (oky && xx >= 0 && xx < SG)
                        ? h[(size_t)(1 + yy * SG + xx) * DD + c] : 0.f;
          a7 = fmaf(v, wl[(ky * 7 + kx) * 128 + tc], a7);
          if (ky >= 1 && ky <= 5 && kx >= 1 && kx <= 5)
            a5 = fmaf(v, wl[(49 + (ky - 1) * 5 + (kx - 1)) * 128 + tc], a5);
          if (ky >= 2 && ky <= 4 && kx >= 2 && kx <= 4)
            a3 = fmaf(v, wl[(74 + (ky - 2) * 3 + (kx - 2)) * 128 + tc], a3);
        }
      }
    }
    tmp[(size_t)p * DD + c] = h[(size_t)(1 + p) * DD + c] + bsum + a7 + a5 + a3;
  }
}

// ---------------- final: LN(row0) -> fc2 -> softmax/argmax ----------------
__global__ __launch_bounds__(256) void final_kernel(
    const float* __restrict__ h, const float* __restrict__ g, const float* __restrict__ b,
    const float* __restrict__ w, const float* __restrict__ bias, float* __restrict__ out)
{
  __shared__ float red[256];
  int t = threadIdx.x;
  float v0 = h[t], v1 = h[t + 256];
  red[t] = v0 + v1;
  __syncthreads();
  for (int s = 128; s > 0; s >>= 1) { if (t < s) red[t] += red[t + s]; __syncthreads(); }
  float mu = red[0] * (1.f / 512.f);
  __syncthreads();
  float d0 = v0 - mu, d1 = v1 - mu;
  red[t] = d0 * d0 + d1 * d1;
  __syncthreads();
  for (int s = 128; s > 0; s >>= 1) { if (t < s) red[t] += red[t + s]; __syncthreads(); }
  float rs = rsqrtf(red[0] * (1.f / 512.f) + 1e-5f);
  __syncthreads();
  float x0 = d0 * rs * g[t] + b[t];
  float x1 = d1 * rs * g[t + 256] + b[t + 256];
  red[t] = x0 * w[t * 2] + x1 * w[(t + 256) * 2];
  __syncthreads();
  for (int s = 128; s > 0; s >>= 1) { if (t < s) red[t] += red[t + s]; __syncthreads(); }
  float l0 = red[0] + bias[0];
  __syncthreads();
  red[t] = x0 * w[t * 2 + 1] + x1 * w[(t + 256) * 2 + 1];
  __syncthreads();
  for (int s = 128; s > 0; s >>= 1) { if (t < s) red[t] += red[t + s]; __syncthreads(); }
  float l1 = red[0] + bias[1];
  if (t == 0) {
    out[0] = l0; out[1] = l1;
    float mx = fmaxf(l0, l1);
    float e0 = __expf(l0 - mx), e1 = __expf(l1 - mx);
    float inv = 1.f / (e0 + e1);
    out[2] = e0 * inv; out[3] = e1 * inv;
    out[4] = (l1 > l0) ? 1.f : 0.f;
  }
}

extern "C" void kernel_launch(void* const* d_in, const int* in_sizes, int n_in,
                              void* d_out, int out_size, void* d_ws, size_t ws_size,
                              hipStream_t stream)
{
  const float* data   = (const float*)d_in[0];
  const float* fc1_w  = (const float*)d_in[1];
  const float* fc1_b  = (const float*)d_in[2];
  const float* cls    = (const float*)d_in[3];
  const float* l1_g   = (const float*)d_in[4];
  const float* l1_b   = (const float*)d_in[5];
  const float* l1_qkv = (const float*)d_in[6];
  const float* l1_ow  = (const float*)d_in[7];
  const float* l1_ob  = (const float*)d_in[8];
  const float* l1_rw  = (const float*)d_in[9];
  const float* w7     = (const float*)d_in[10];
  const float* b7     = (const float*)d_in[11];
  const float* w5     = (const float*)d_in[12];
  const float* b5     = (const float*)d_in[13];
  const float* w3     = (const float*)d_in[14];
  const float* b3     = (const float*)d_in[15];
  const float* l2_g   = (const float*)d_in[16];
  const float* l2_b   = (const float*)d_in[17];
  const float* l2_qkv = (const float*)d_in[18];
  const float* l2_ow  = (const float*)d_in[19];
  const float* l2_ob  = (const float*)d_in[20];
  const float* l2_rw  = (const float*)d_in[21];
  const float* ng     = (const float*)d_in[22];
  const float* nb     = (const float*)d_in[23];
  const float* fc2_w  = (const float*)d_in[24];
  const float* fc2_b  = (const float*)d_in[25];
  float* out = (float*)d_out;

  float* ws   = (float*)d_ws;
  float* h    = ws;
  float* xn   = h    + (size_t)16384 * 512;
  float* qkv  = xn   + (size_t)16384 * 512;
  float* attn = qkv  + (size_t)16384 * 1536;
  float* ql   = attn + (size_t)16384 * 512;
  float* kl   = ql   + 256 * 512;
  float* a2b  = kl   + 256 * 512;
  float* z0   = a2b  + 8 * 256 * 256;
  float* z1   = z0   + 8 * 256 * 256;
  float* xzb  = z1   + 8 * 256 * 256;
  float* tb   = xzb  + 8 * 256 * 256;
  float* ub   = tb   + 8 * 256 * 256;
  float* a3v  = ub   + 8 * 256 * 256;
  float* w2   = a3v  + 8 * 256 * 64;
  float* pacc = w2   + 8 * 256 * 64;           // dead region: 4,194,304 floats (16 MiB)
  float* pms  = pacc + (size_t)8 * 32 * 256 * 64;
  float* red  = pms  + (size_t)8 * 32 * 256 * 2;
  float* wtb  = red  + 32;                       // ppeg weights fp32 (83*512)

  // bf16 transposed weights at start of pacc region: 2.62M ushorts = 1.31M floats
  // (fits in 4.19M-float pacc region; NOTE round-8/9 bug: pacc is 4.19M FLOATS
  //  = 16.78 MB, not 16.78M floats — no room for an 8.26M-float hb here)
  ushort* fc1_wt  = (ushort*)pacc;
  ushort* qkv_wt0 = fc1_wt + 512 * 1024;
  ushort* qkv_wt1 = qkv_wt0 + 1536 * 512;
  ushort* out_wt0 = qkv_wt1 + 1536 * 512;
  ushort* out_wt1 = out_wt0 + 512 * 512;

  // a3v MFMA partial buffers (alias xn scratch / pms)
  float* a3v_pacc = xn;
  float* a3v_den  = pms;

  // weight prep (bf16 transposes) + fc1 + assemble
  wtrans_bf<<<dim3(16, 32), 256, 0, stream>>>(fc1_w, fc1_wt, 1024, 512);
  wtrans_bf<<<dim3(48, 16), 256, 0, stream>>>(l1_qkv, qkv_wt0, 512, 1536);
  wtrans_bf<<<dim3(48, 16), 256, 0, stream>>>(l2_qkv, qkv_wt1, 512, 1536);
  wtrans_bf<<<dim3(16, 16), 256, 0, stream>>>(l1_ow, out_wt0, 512, 512);
  wtrans_bf<<<dim3(16, 16), 256, 0, stream>>>(l2_ow, out_wt1, 512, 512);
  wtrans_kernel<<<2, 256, 0, stream>>>(w7, w5, w3, wtb);

  gemm_bt<<<dim3(4, 125), 256, 0, stream>>>(data, 1024, fc1_wt, 1024, h + 512, 512,
                                            16000, 1024, 1, fc1_b);
  assemble_kernel<<<260, 256, 0, stream>>>(h, cls);

  for (int layer = 0; layer < 2; ++layer) {
    const float* gg = layer ? l2_g   : l1_g;
    const float* bb = layer ? l2_b   : l1_b;
    const ushort* qw = layer ? qkv_wt1 : qkv_wt0;
    const ushort* ow = layer ? out_wt1 : out_wt0;
    const float* ob = layer ? l2_ob  : l1_ob;
    const float* rw = layer ? l2_rw  : l1_rw;

    ln_pad_kernel<<<16384, 256, 0, stream>>>(h, xn, gg, bb);
    gemm_bt<<<dim3(12, 128), 256, 0, stream>>>(xn, 512, qw, 512, qkv, 1536,
                                               16384, 512, 2, nullptr);
    landmark_kernel<<<dim3(256, 4), 256, 0, stream>>>(qkv, ql, kl);
    a2_kernel<<<dim3(8, 256), 256, 0, stream>>>(ql, kl, a2b);
    pinv_red1<<<8, 256, 0, stream>>>(a2b, red);
    pinv_red2<<<1, 1, 0, stream>>>(red);
    pinv_init<<<dim3(8, 256), 256, 0, stream>>>(a2b, red, z0);
    float* zc = z0; float* zn = z1;
    for (int it = 0; it < 6; ++it) {
      nmm_kernel<<<dim3(4, 4, 8), 256, 0, stream>>>(a2b, zc, xzb, 0);  // xz = a2@z
      nmm_kernel<<<dim3(4, 4, 8), 256, 0, stream>>>(xzb, xzb, tb, 1);  // u1 = 7xz - xz@xz
      nmm_kernel<<<dim3(4, 4, 8), 256, 0, stream>>>(xzb, tb, ub, 2);   // u2 = 15xz - xz@u1
      nmm_kernel<<<dim3(4, 4, 8), 256, 0, stream>>>(zc, ub, zn, 3);    // z' = .25(13z - z@u2)
      float* sw = zc; zc = zn; zn = sw;
    }
    a3v_mfma<<<dim3(8, CHK), 256, 0, stream>>>(qkv, ql, a3v_pacc, a3v_den);
    a3v_merge_kernel<<<dim3(8, 256), 64, 0, stream>>>(a3v_pacc, a3v_den, a3v);
    mmb_kernel<<<dim3(1, 4, 8), 256, 0, stream>>>(zc, a3v, w2, 64, 1.f);
    a1_mfma<<<dim3(8, 64), 256, 0, stream>>>(qkv, kl, w2, attn);
    resconv_kernel<<<dim3(16384, 2), 256, 0, stream>>>(qkv, rw, attn);
    gemm_bt<<<dim3(4, 127), 256, 0, stream>>>(attn + (size_t)254 * 512, 512, ow, 512,
                                              h, 512, 16130, 512, 3, ob);
    if (layer == 0) {
      // ppeg -> qkv scratch (dead until layer-1 recomputes it), memcpy back (round-7 proven)
      ppeg_kernel<<<dim3((NPIX + 63) / 64, 4), 256, 0, stream>>>(h, qkv, wtb, b7, b5, b3);
      hipMemcpyAsync(h + 512, qkv, (size_t)16129 * 512 * 4,
                     hipMemcpyDeviceToDevice, stream);
    }
  }
  final_kernel<<<1, 256, 0, stream>>>(h, ng, nb, fc2_w, fc2_b, out);
}

// Round 11
// 1364.546 us; speedup vs baseline: 4.2682x; 1.1965x over previous
//
#include <hip/hip_runtime.h>
#include <math.h>

#define NPAD   16384
#define PADR   254
#define NTOK   16130
#define NPIX   16129
#define SG     127
#define DD     512
#define NH     8
#define CHK    64          // key-chunks per head for a3v

typedef __attribute__((ext_vector_type(8))) short bf16x8;
typedef __attribute__((ext_vector_type(4))) float f32x4;

__device__ __forceinline__ ushort f2bf(float f) {
  uint u = __float_as_uint(f);
  u = (u + 0x7fffu + ((u >> 16) & 1u)) >> 16;
  return (ushort)u;
}

// ---------------- weight transpose+cvt: src fp32 [K][N] -> dst bf16 [N][K] ----------------
__global__ __launch_bounds__(256) void wtrans_bf(
    const float* __restrict__ src, ushort* __restrict__ dst, int K, int N)
{
  __shared__ float tile[32][33];
  int tx = threadIdx.x & 31, ty = threadIdx.x >> 5;   // 32 x 8
#pragma unroll
  for (int i = 0; i < 4; ++i) {
    int k = blockIdx.y * 32 + ty + i * 8, n = blockIdx.x * 32 + tx;
    tile[ty + i * 8][tx] = src[(size_t)k * N + n];
  }
  __syncthreads();
#pragma unroll
  for (int i = 0; i < 4; ++i) {
    int n = blockIdx.x * 32 + ty + i * 8, k = blockIdx.y * 32 + tx;
    dst[(size_t)n * K + k] = f2bf(tile[tx][ty + i * 8]);
  }
}

// ---------------- bf16 MFMA GEMM: C fp32 = A_f32 @ Bt_bf16^T ----------------
// A [M][lda] fp32 (converted in staging), Bt [N][ldb=K] bf16 row-major (pre-transposed W).
// 128x128 tile, BK=64, 4 waves (2x2 of 64x64). mode 1: relu(acc+bias); 2: q-scale; 3: C+=acc+bias.
__global__ __launch_bounds__(256) void gemm_bt(
    const float* __restrict__ A, int lda,
    const ushort* __restrict__ Bt, int ldb,
    float* __restrict__ C, int ldc,
    int M, int K, int mode, const float* __restrict__ bias)
{
  const int t = threadIdx.x;
  const int w = t >> 6, l = t & 63, lr = l & 15, lg = l >> 4;
  const int wr = w >> 1, wc = w & 1;
  const int m0 = blockIdx.y * 128, n0 = blockIdx.x * 128;
  __shared__ __align__(16) ushort As[128 * 64];
  __shared__ __align__(16) ushort Bs[128 * 64];
  f32x4 acc[4][4];
#pragma unroll
  for (int i = 0; i < 4; ++i)
#pragma unroll
    for (int j = 0; j < 4; ++j) acc[i][j] = (f32x4){0.f, 0.f, 0.f, 0.f};

  for (int k0 = 0; k0 < K; k0 += 64) {
    __syncthreads();
    // stage A: 128 rows x 4 chunks of 16 floats = 512 tasks, 2/thread
#pragma unroll
    for (int i = 0; i < 2; ++i) {
      int id = t + i * 256;
      int r = id >> 2, db = id & 3;
      const float* src = A + (size_t)(m0 + r) * lda + k0 + db * 16;
      float4 g0 = *(const float4*)(src + 0);
      float4 g1 = *(const float4*)(src + 4);
      float4 g2 = *(const float4*)(src + 8);
      float4 g3 = *(const float4*)(src + 12);
      bf16x8 e0, e1;
      e0[0] = f2bf(g0.x); e0[1] = f2bf(g0.y); e0[2] = f2bf(g0.z); e0[3] = f2bf(g0.w);
      e0[4] = f2bf(g1.x); e0[5] = f2bf(g1.y); e0[6] = f2bf(g1.z); e0[7] = f2bf(g1.w);
      e1[0] = f2bf(g2.x); e1[1] = f2bf(g2.y); e1[2] = f2bf(g2.z); e1[3] = f2bf(g2.w);
      e1[4] = f2bf(g3.x); e1[5] = f2bf(g3.y); e1[6] = f2bf(g3.z); e1[7] = f2bf(g3.w);
      ushort* dst = As + r * 64;
      *(bf16x8*)(dst + (((db * 2 + 0) ^ (r & 7)) << 3)) = e0;
      *(bf16x8*)(dst + (((db * 2 + 1) ^ (r & 7)) << 3)) = e1;
    }
    // stage B (already bf16): 128 rows x 8 blocks = 1024 tasks, 4/thread
#pragma unroll
    for (int i = 0; i < 4; ++i) {
      int id = t + i * 256;
      int r = id >> 3, blk = id & 7;
      bf16x8 v = *(const bf16x8*)(Bt + (size_t)(n0 + r) * ldb + k0 + blk * 8);
      *(bf16x8*)(Bs + r * 64 + ((blk ^ (r & 7)) << 3)) = v;
    }
    __syncthreads();
    bf16x8 af[4][2], bfr[4][2];
#pragma unroll
    for (int rt = 0; rt < 4; ++rt) {
      int row = wr * 64 + rt * 16 + lr;
#pragma unroll
      for (int kc = 0; kc < 2; ++kc)
        af[rt][kc] = *(const bf16x8*)(As + row * 64 + (((kc * 4 + lg) ^ (row & 7)) << 3));
    }
#pragma unroll
    for (int nt = 0; nt < 4; ++nt) {
      int row = wc * 64 + nt * 16 + lr;
#pragma unroll
      for (int kc = 0; kc < 2; ++kc)
        bfr[nt][kc] = *(const bf16x8*)(Bs + row * 64 + (((kc * 4 + lg) ^ (row & 7)) << 3));
    }
#pragma unroll
    for (int rt = 0; rt < 4; ++rt)
#pragma unroll
      for (int nt = 0; nt < 4; ++nt) {
        acc[rt][nt] = __builtin_amdgcn_mfma_f32_16x16x32_bf16(af[rt][0], bfr[nt][0], acc[rt][nt], 0, 0, 0);
        acc[rt][nt] = __builtin_amdgcn_mfma_f32_16x16x32_bf16(af[rt][1], bfr[nt][1], acc[rt][nt], 0, 0, 0);
      }
  }
#pragma unroll
  for (int rt = 0; rt < 4; ++rt) {
#pragma unroll
    for (int r = 0; r < 4; ++r) {
      int gi = m0 + wr * 64 + rt * 16 + lg * 4 + r;
      if (gi >= M) continue;
#pragma unroll
      for (int nt = 0; nt < 4; ++nt) {
        int gj = n0 + wc * 64 + nt * 16 + lr;
        float d = acc[rt][nt][r];
        if (mode == 1) d = fmaxf(d + bias[gj], 0.f);
        else if (mode == 2) { if (gj < 512) d *= 0.125f; }
        else if (mode == 3) d += C[(size_t)gi * ldc + gj] + bias[gj];
        C[(size_t)gi * ldc + gj] = d;
      }
    }
  }
}

// ---------------- fused Newton-step matmul: D = A@B (bf16 MFMA), C = f(A[ij], D) ----------
// batched 8 heads of 256x256. B transposed during staging. modes:
// 0: C=D ; 1: C=7A-D ; 2: C=15A-D ; 3: C=0.25*(13A-D)
__global__ __launch_bounds__(256) void nmm_kernel(
    const float* __restrict__ A, const float* __restrict__ B,
    float* __restrict__ C, int mode)
{
  const int h_ = blockIdx.z;
  const int m0 = blockIdx.y * 64, n0 = blockIdx.x * 64;
  const float* Ah = A + (size_t)h_ * 65536;
  const float* Bh = B + (size_t)h_ * 65536;
  float* Ch = C + (size_t)h_ * 65536;
  const int t = threadIdx.x, w = t >> 6, l = t & 63, lr = l & 15, lg = l >> 4;
  __shared__ __align__(16) ushort Xs[64 * 64];
  __shared__ __align__(16) ushort Ys[64 * 64];
  f32x4 acc[4];
#pragma unroll
  for (int nt = 0; nt < 4; ++nt) acc[nt] = (f32x4){0.f, 0.f, 0.f, 0.f};

  for (int k0 = 0; k0 < 256; k0 += 64) {
    __syncthreads();
    // stage A rows (direct): 64 rows x 4 chunks of 16 -> 256 tasks, 1/thread
    {
      int r = t >> 2, db = t & 3;
      const float* src = Ah + (size_t)(m0 + r) * 256 + k0 + db * 16;
      float4 g0 = *(const float4*)(src + 0);
      float4 g1 = *(const float4*)(src + 4);
      float4 g2 = *(const float4*)(src + 8);
      float4 g3 = *(const float4*)(src + 12);
      bf16x8 e0, e1;
      e0[0] = f2bf(g0.x); e0[1] = f2bf(g0.y); e0[2] = f2bf(g0.z); e0[3] = f2bf(g0.w);
      e0[4] = f2bf(g1.x); e0[5] = f2bf(g1.y); e0[6] = f2bf(g1.z); e0[7] = f2bf(g1.w);
      e1[0] = f2bf(g2.x); e1[1] = f2bf(g2.y); e1[2] = f2bf(g2.z); e1[3] = f2bf(g2.w);
      e1[4] = f2bf(g3.x); e1[5] = f2bf(g3.y); e1[6] = f2bf(g3.z); e1[7] = f2bf(g3.w);
      ushort* dst = Xs + r * 64;
      *(bf16x8*)(dst + (((db * 2 + 0) ^ (r & 7)) << 3)) = e0;
      *(bf16x8*)(dst + (((db * 2 + 1) ^ (r & 7)) << 3)) = e1;
    }
    // stage B transposed: 64 k-rows x 16 float4 = 1024 tasks, 4/thread
#pragma unroll
    for (int i = 0; i < 4; ++i) {
      int id = t + i * 256;
      int k = id >> 4, q = id & 15;
      float4 v = *(const float4*)(Bh + (size_t)(k0 + k) * 256 + n0 + q * 4);
      int kb = k >> 3, ke = k & 7;
      Ys[(q * 4 + 0) * 64 + ((kb ^ ((q * 4 + 0) & 7)) << 3) + ke] = f2bf(v.x);
      Ys[(q * 4 + 1) * 64 + ((kb ^ ((q * 4 + 1) & 7)) << 3) + ke] = f2bf(v.y);
      Ys[(q * 4 + 2) * 64 + ((kb ^ ((q * 4 + 2) & 7)) << 3) + ke] = f2bf(v.z);
      Ys[(q * 4 + 3) * 64 + ((kb ^ ((q * 4 + 3) & 7)) << 3) + ke] = f2bf(v.w);
    }
    __syncthreads();
    int arow = w * 16 + lr;
    bf16x8 af0 = *(const bf16x8*)(Xs + arow * 64 + (((0 + lg) ^ (arow & 7)) << 3));
    bf16x8 af1 = *(const bf16x8*)(Xs + arow * 64 + (((4 + lg) ^ (arow & 7)) << 3));
#pragma unroll
    for (int nt = 0; nt < 4; ++nt) {
      int brow = nt * 16 + lr;
      bf16x8 bf0 = *(const bf16x8*)(Ys + brow * 64 + (((0 + lg) ^ (brow & 7)) << 3));
      bf16x8 bf1 = *(const bf16x8*)(Ys + brow * 64 + (((4 + lg) ^ (brow & 7)) << 3));
      acc[nt] = __builtin_amdgcn_mfma_f32_16x16x32_bf16(af0, bf0, acc[nt], 0, 0, 0);
      acc[nt] = __builtin_amdgcn_mfma_f32_16x16x32_bf16(af1, bf1, acc[nt], 0, 0, 0);
    }
  }
#pragma unroll
  for (int nt = 0; nt < 4; ++nt) {
#pragma unroll
    for (int r = 0; r < 4; ++r) {
      int gi = m0 + w * 16 + lg * 4 + r;
      int gj = n0 + nt * 16 + lr;
      float d = acc[nt][r];
      if (mode == 1)      d = 7.f * Ah[(size_t)gi * 256 + gj] - d;
      else if (mode == 2) d = 15.f * Ah[(size_t)gi * 256 + gj] - d;
      else if (mode == 3) d = 0.25f * (13.f * Ah[(size_t)gi * 256 + gj] - d);
      Ch[(size_t)gi * 256 + gj] = d;
    }
  }
}

// ---------------- assemble: h[0]=cls, h[16001+i]=h[1+i] (i<129) ----------------
__global__ __launch_bounds__(256) void assemble_kernel(float* __restrict__ h,
                                                       const float* __restrict__ cls)
{
  int idx = blockIdx.x * 256 + threadIdx.x;
  if (idx < 512) { h[idx] = cls[idx]; return; }
  idx -= 512;
  int i = idx >> 9, c = idx & 511;
  h[(size_t)(16001 + i) * DD + c] = h[(size_t)(1 + i) * DD + c];
}

// ---------------- LayerNorm rows of h -> xn (front-padded, rows<PADR zeroed) ----------------
__global__ __launch_bounds__(256) void ln_pad_kernel(
    const float* __restrict__ h, float* __restrict__ xn,
    const float* __restrict__ g, const float* __restrict__ b)
{
  int row = blockIdx.x;
  int t = threadIdx.x;
  if (row < PADR) {
    xn[(size_t)row * DD + t] = 0.f;
    xn[(size_t)row * DD + t + 256] = 0.f;
    return;
  }
  const float* x = h + (size_t)(row - PADR) * DD;
  __shared__ float red[256];
  float v0 = x[t], v1 = x[t + 256];
  red[t] = v0 + v1;
  __syncthreads();
  for (int s = 128; s > 0; s >>= 1) { if (t < s) red[t] += red[t + s]; __syncthreads(); }
  float mu = red[0] * (1.f / 512.f);
  __syncthreads();
  float d0 = v0 - mu, d1 = v1 - mu;
  red[t] = d0 * d0 + d1 * d1;
  __syncthreads();
  for (int s = 128; s > 0; s >>= 1) { if (t < s) red[t] += red[t + s]; __syncthreads(); }
  float rs = rsqrtf(red[0] * (1.f / 512.f) + 1e-5f);
  float* o = xn + (size_t)row * DD;
  o[t]       = d0 * rs * g[t] + b[t];
  o[t + 256] = d1 * rs * g[t + 256] + b[t + 256];
}

// ---------------- landmarks ----------------
__global__ __launch_bounds__(256) void landmark_kernel(
    const float* __restrict__ qkv, float* __restrict__ ql, float* __restrict__ kl)
{
  int i = blockIdx.x;
  int c = blockIdx.y * 256 + threadIdx.x;
  const float* p = qkv + (size_t)(i * 64) * 1536 + c;
  float s = 0.f;
  for (int j = 0; j < 64; ++j) s += p[(size_t)j * 1536];
  s *= (1.f / 64.f);
  if (c < 512) ql[(size_t)i * 512 + c] = s;
  else         kl[(size_t)i * 512 + (c - 512)] = s;
}

// ---------------- a2 = softmax(ql . kl^T) per head ----------------
__global__ __launch_bounds__(256) void a2_kernel(
    const float* __restrict__ ql, const float* __restrict__ kl, float* __restrict__ a2)
{
  int h_ = blockIdx.x, i = blockIdx.y;
  int t = threadIdx.x;
  __shared__ float q[64];
  __shared__ float red[256];
  if (t < 64) q[t] = ql[(size_t)i * 512 + h_ * 64 + t];
  __syncthreads();
  const float* kr = kl + (size_t)t * 512 + h_ * 64;
  float s = 0.f;
#pragma unroll
  for (int d = 0; d < 64; ++d) s = fmaf(q[d], kr[d], s);
  red[t] = s;
  __syncthreads();
  for (int st = 128; st > 0; st >>= 1) { if (t < st) red[t] = fmaxf(red[t], red[t + st]); __syncthreads(); }
  float mx = red[0];
  __syncthreads();
  float e = __expf(s - mx);
  red[t] = e;
  __syncthreads();
  for (int st = 128; st > 0; st >>= 1) { if (t < st) red[t] += red[t + st]; __syncthreads(); }
  a2[((size_t)h_ * 256 + i) * 256 + t] = e / red[0];
}

// ---------------- pinv init reductions ----------------
__global__ __launch_bounds__(256) void pinv_red1(const float* __restrict__ a2, float* __restrict__ red)
{
  int h_ = blockIdx.x, t = threadIdx.x;
  const float* X = a2 + (size_t)h_ * 65536;
  float rs = 0.f, cs = 0.f;
  for (int j = 0; j < 256; ++j) rs += fabsf(X[(size_t)t * 256 + j]);
  for (int i = 0; i < 256; ++i) cs += fabsf(X[(size_t)i * 256 + t]);
  __shared__ float r1[256], r2[256];
  r1[t] = rs; r2[t] = cs;
  __syncthreads();
  for (int s = 128; s > 0; s >>= 1) {
    if (t < s) { r1[t] = fmaxf(r1[t], r1[t + s]); r2[t] = fmaxf(r2[t], r2[t + s]); }
    __syncthreads();
  }
  if (t == 0) { red[h_ * 2] = r1[0]; red[h_ * 2 + 1] = r2[0]; }
}
__global__ void pinv_red2(float* __restrict__ red)
{
  float mr = 0.f, mc = 0.f;
  for (int h_ = 0; h_ < 8; ++h_) { mr = fmaxf(mr, red[h_ * 2]); mc = fmaxf(mc, red[h_ * 2 + 1]); }
  red[16] = 1.f / (mr * mc);
}
__global__ __launch_bounds__(256) void pinv_init(
    const float* __restrict__ a2, const float* __restrict__ red, float* __restrict__ z)
{
  int h_ = blockIdx.x, i = blockIdx.y, j = threadIdx.x;
  float inv = red[16];
  z[((size_t)h_ * 256 + i) * 256 + j] = a2[((size_t)h_ * 256 + j) * 256 + i] * inv;
}

// ---------------- batched matmul per head: C = alpha*(A @ B), A 256x256, B 256xN ----------------
__global__ __launch_bounds__(256) void mmb_kernel(
    const float* __restrict__ A, const float* __restrict__ B, float* __restrict__ C,
    int N, float alpha)
{
  int h_ = blockIdx.z;
  const float* Ah = A + (size_t)h_ * 256 * 256;
  const float* Bh = B + (size_t)h_ * 256 * N;
  float* Ch = C + (size_t)h_ * 256 * N;
  int m0 = blockIdx.y * 64, n0 = blockIdx.x * 64;
  __shared__ float As[16][68];
  __shared__ float Bs[16][68];
  int tid = threadIdx.x, tx = tid & 15, ty = tid >> 4;
  float acc[4][4];
#pragma unroll
  for (int i = 0; i < 4; ++i)
#pragma unroll
    for (int j = 0; j < 4; ++j) acc[i][j] = 0.f;
  for (int k0 = 0; k0 < 256; k0 += 16) {
    {
      int row = tid >> 2, k4 = (tid & 3) << 2;
      float4 v = *(const float4*)(Ah + (size_t)(m0 + row) * 256 + k0 + k4);
      As[k4 + 0][row] = v.x; As[k4 + 1][row] = v.y;
      As[k4 + 2][row] = v.z; As[k4 + 3][row] = v.w;
    }
    {
      int row = tid >> 4, c4 = (tid & 15) << 2;
      *(float4*)&Bs[row][c4] = *(const float4*)(Bh + (size_t)(k0 + row) * N + n0 + c4);
    }
    __syncthreads();
#pragma unroll
    for (int k = 0; k < 16; ++k) {
      float a[4], b[4];
      *(float4*)a = *(const float4*)&As[k][ty * 4];
      *(float4*)b = *(const float4*)&Bs[k][tx * 4];
#pragma unroll
      for (int i = 0; i < 4; ++i)
#pragma unroll
        for (int j = 0; j < 4; ++j) acc[i][j] = fmaf(a[i], b[j], acc[i][j]);
    }
    __syncthreads();
  }
#pragma unroll
  for (int i = 0; i < 4; ++i) {
    float4 r;
    r.x = alpha * acc[i][0]; r.y = alpha * acc[i][1];
    r.z = alpha * acc[i][2]; r.w = alpha * acc[i][3];
    *(float4*)(Ch + (size_t)(m0 + ty * 4 + i) * N + n0 + tx * 4) = r;
  }
}

// ---------------- a3@v partials via bf16 MFMA flash (no-max exp, ones-column den) ----------
__global__ __launch_bounds__(256) void a3v_mfma(
    const float* __restrict__ qkv, const float* __restrict__ ql,
    float* __restrict__ pacc, float* __restrict__ den)
{
  const int h_ = blockIdx.x;
  const int ch = blockIdx.y;
  const int t  = threadIdx.x;
  const int w  = t >> 6;
  const int l  = t & 63;
  const int lr = l & 15;
  const int lg = l >> 4;

  __shared__ __align__(16) ushort kls[64 * 64];
  __shared__ __align__(16) ushort vls[80 * 64];
  __shared__ __align__(16) ushort pls[4][64 * 64];

  bf16x8 qf[4][2];
#pragma unroll
  for (int rt = 0; rt < 4; ++rt)
#pragma unroll
    for (int dc = 0; dc < 2; ++dc) {
      const float* p = ql + (size_t)(64 * w + rt * 16 + lr) * 512 + h_ * 64 + dc * 32 + lg * 8;
      float4 f0 = *(const float4*)p;
      float4 f1 = *(const float4*)(p + 4);
      bf16x8 v;
      v[0] = f2bf(f0.x); v[1] = f2bf(f0.y); v[2] = f2bf(f0.z); v[3] = f2bf(f0.w);
      v[4] = f2bf(f1.x); v[5] = f2bf(f1.y); v[6] = f2bf(f1.z); v[7] = f2bf(f1.w);
      qf[rt][dc] = v;
    }

  if (t < 128) {
    int rr = t >> 3, cb = t & 7;
    ushort val = (rr == 0) ? (ushort)0x3f80 : (ushort)0;
    bf16x8 vv;
#pragma unroll
    for (int k = 0; k < 8; ++k) vv[k] = (short)val;
    *(bf16x8*)(vls + (64 + rr) * 64 + ((cb ^ (rr & 7)) << 3)) = vv;
  }

  f32x4 acc[4][5];
#pragma unroll
  for (int rt = 0; rt < 4; ++rt)
#pragma unroll
    for (int dt = 0; dt < 5; ++dt) acc[rt][dt] = (f32x4){0.f, 0.f, 0.f, 0.f};

  const int j0base = ch * 256;
  for (int jt = 0; jt < 4; ++jt) {
    const int j0 = j0base + jt * 64;
    __syncthreads();
    {
      int r = t >> 2, db = t & 3;
      const float* src = qkv + (size_t)(j0 + r) * 1536 + 512 + h_ * 64 + db * 16;
      float4 g0 = *(const float4*)(src + 0);
      float4 g1 = *(const float4*)(src + 4);
      float4 g2 = *(const float4*)(src + 8);
      float4 g3 = *(const float4*)(src + 12);
      bf16x8 e0, e1;
      e0[0] = f2bf(g0.x); e0[1] = f2bf(g0.y); e0[2] = f2bf(g0.z); e0[3] = f2bf(g0.w);
      e0[4] = f2bf(g1.x); e0[5] = f2bf(g1.y); e0[6] = f2bf(g1.z); e0[7] = f2bf(g1.w);
      e1[0] = f2bf(g2.x); e1[1] = f2bf(g2.y); e1[2] = f2bf(g2.z); e1[3] = f2bf(g2.w);
      e1[4] = f2bf(g3.x); e1[5] = f2bf(g3.y); e1[6] = f2bf(g3.z); e1[7] = f2bf(g3.w);
      ushort* base = kls + r * 64;
      *(bf16x8*)(base + (((db * 2 + 0) ^ (r & 7)) << 3)) = e0;
      *(bf16x8*)(base + (((db * 2 + 1) ^ (r & 7)) << 3)) = e1;
    }
    {
      int d = t & 63, jg = t >> 6;
#pragma unroll
      for (int half = 0; half < 2; ++half) {
        int jb = jg + half * 4;
        bf16x8 e;
#pragma unroll
        for (int jj = 0; jj < 8; ++jj)
          e[jj] = f2bf(qkv[(size_t)(j0 + jb * 8 + jj) * 1536 + 1024 + h_ * 64 + d]);
        *(bf16x8*)(vls + d * 64 + ((jb ^ (d & 7)) << 3)) = e;
      }
    }
    __syncthreads();

    ushort* pw = pls[w];
#pragma unroll
    for (int sjt = 0; sjt < 4; ++sjt) {
      const int krow = sjt * 16 + lr;
      bf16x8 kf0 = *(const bf16x8*)(kls + krow * 64 + (((0 * 4 + lg) ^ (lr & 7)) << 3));
      bf16x8 kf1 = *(const bf16x8*)(kls + krow * 64 + (((1 * 4 + lg) ^ (lr & 7)) << 3));
#pragma unroll
      for (int rt = 0; rt < 4; ++rt) {
        f32x4 s = (f32x4){0.f, 0.f, 0.f, 0.f};
        s = __builtin_amdgcn_mfma_f32_16x16x32_bf16(qf[rt][0], kf0, s, 0, 0, 0);
        s = __builtin_amdgcn_mfma_f32_16x16x32_bf16(qf[rt][1], kf1, s, 0, 0, 0);
#pragma unroll
        for (int r = 0; r < 4; ++r) {
          int i  = rt * 16 + lg * 4 + r;
          int jj = sjt * 16 + lr;
          pw[i * 64 + ((((jj >> 3) ^ (i & 7)) << 3)) + (jj & 7)] = (short)f2bf(__expf(s[r]));
        }
      }
    }
    bf16x8 pf[4][2];
#pragma unroll
    for (int rt = 0; rt < 4; ++rt)
#pragma unroll
      for (int jc = 0; jc < 2; ++jc)
        pf[rt][jc] = *(const bf16x8*)(pw + (rt * 16 + lr) * 64 + (((jc * 4 + lg) ^ (lr & 7)) << 3));
#pragma unroll
    for (int dt = 0; dt < 5; ++dt) {
      const int vrow = dt * 16 + lr;
      bf16x8 vf0 = *(const bf16x8*)(vls + vrow * 64 + (((0 * 4 + lg) ^ (lr & 7)) << 3));
      bf16x8 vf1 = *(const bf16x8*)(vls + vrow * 64 + (((1 * 4 + lg) ^ (lr & 7)) << 3));
#pragma unroll
      for (int rt = 0; rt < 4; ++rt) {
        acc[rt][dt] = __builtin_amdgcn_mfma_f32_16x16x32_bf16(pf[rt][0], vf0, acc[rt][dt], 0, 0, 0);
        acc[rt][dt] = __builtin_amdgcn_mfma_f32_16x16x32_bf16(pf[rt][1], vf1, acc[rt][dt], 0, 0, 0);
      }
    }
  }

  const size_t pbase = (size_t)(h_ * CHK + ch) * 256;
#pragma unroll
  for (int rt = 0; rt < 4; ++rt) {
    int i = 64 * w + rt * 16 + lg * 4;
#pragma unroll
    for (int dt = 0; dt < 4; ++dt)
#pragma unroll
      for (int r = 0; r < 4; ++r)
        pacc[(pbase + i + r) * 64 + dt * 16 + lr] = acc[rt][dt][r];
    if (lr == 0) {
#pragma unroll
      for (int r = 0; r < 4; ++r)
        den[pbase + i + r] = acc[rt][4][r];
    }
  }
}

// ---------------- merge a3v partials ----------------
__global__ __launch_bounds__(64) void a3v_merge_kernel(
    const float* __restrict__ pacc, const float* __restrict__ den, float* __restrict__ a3v)
{
  int h_ = blockIdx.x, i = blockIdx.y, d = threadIdx.x;
  float S = 0.f, o = 0.f;
  for (int c = 0; c < CHK; ++c) {
    size_t b = (size_t)(h_ * CHK + c) * 256 + i;
    o += pacc[b * 64 + d];
    S += den[b];
  }
  a3v[((size_t)h_ * 256 + i) * 64 + d] = o / S;
}

// ---------------- a1: out = softmax(q . kl^T) @ w2 via bf16 MFMA ----------------
__global__ __launch_bounds__(256) void a1_mfma(
    const float* __restrict__ qkv, const float* __restrict__ kl,
    const float* __restrict__ w2, float* __restrict__ attn)
{
  const int h_ = blockIdx.x;
  const int rb = blockIdx.y;
  const int t  = threadIdx.x;
  const int w  = t >> 6, l = t & 63, lr = l & 15, lg = l >> 4;

  __shared__ __align__(16) ushort kls[64 * 64];
  __shared__ __align__(16) ushort wls[80 * 64];
  __shared__ __align__(16) ushort pls[4][64 * 64];

  bf16x8 qf[4][2];
#pragma unroll
  for (int rt = 0; rt < 4; ++rt)
#pragma unroll
    for (int dc = 0; dc < 2; ++dc) {
      const float* p = qkv + (size_t)(rb * 256 + w * 64 + rt * 16 + lr) * 1536 + h_ * 64 + dc * 32 + lg * 8;
      float4 f0 = *(const float4*)p;
      float4 f1 = *(const float4*)(p + 4);
      bf16x8 v;
      v[0] = f2bf(f0.x); v[1] = f2bf(f0.y); v[2] = f2bf(f0.z); v[3] = f2bf(f0.w);
      v[4] = f2bf(f1.x); v[5] = f2bf(f1.y); v[6] = f2bf(f1.z); v[7] = f2bf(f1.w);
      qf[rt][dc] = v;
    }

  if (t < 128) {
    int rr = t >> 3, cb = t & 7;
    ushort val = (rr == 0) ? (ushort)0x3f80 : (ushort)0;
    bf16x8 vv;
#pragma unroll
    for (int k = 0; k < 8; ++k) vv[k] = (short)val;
    *(bf16x8*)(wls + (64 + rr) * 64 + ((cb ^ (rr & 7)) << 3)) = vv;
  }

  f32x4 acc[4][5];
#pragma unroll
  for (int rt = 0; rt < 4; ++rt)
#pragma unroll
    for (int dt = 0; dt < 5; ++dt) acc[rt][dt] = (f32x4){0.f, 0.f, 0.f, 0.f};

  for (int kc = 0; kc < 4; ++kc) {
    const int j0 = kc * 64;
    __syncthreads();
    {
      int r = t >> 2, db = t & 3;
      const float* src = kl + (size_t)(j0 + r) * 512 + h_ * 64 + db * 16;
      float4 g0 = *(const float4*)(src + 0);
      float4 g1 = *(const float4*)(src + 4);
      float4 g2 = *(const float4*)(src + 8);
      float4 g3 = *(const float4*)(src + 12);
      bf16x8 e0, e1;
      e0[0] = f2bf(g0.x); e0[1] = f2bf(g0.y); e0[2] = f2bf(g0.z); e0[3] = f2bf(g0.w);
      e0[4] = f2bf(g1.x); e0[5] = f2bf(g1.y); e0[6] = f2bf(g1.z); e0[7] = f2bf(g1.w);
      e1[0] = f2bf(g2.x); e1[1] = f2bf(g2.y); e1[2] = f2bf(g2.z); e1[3] = f2bf(g2.w);
      e1[4] = f2bf(g3.x); e1[5] = f2bf(g3.y); e1[6] = f2bf(g3.z); e1[7] = f2bf(g3.w);
      ushort* base = kls + r * 64;
      *(bf16x8*)(base + (((db * 2 + 0) ^ (r & 7)) << 3)) = e0;
      *(bf16x8*)(base + (((db * 2 + 1) ^ (r & 7)) << 3)) = e1;
    }
    {
      int d = t & 63, jg = t >> 6;
#pragma unroll
      for (int half = 0; half < 2; ++half) {
        int jb = jg + half * 4;
        bf16x8 e;
#pragma unroll
        for (int jj = 0; jj < 8; ++jj)
          e[jj] = f2bf(w2[((size_t)h_ * 256 + j0 + jb * 8 + jj) * 64 + d]);
        *(bf16x8*)(wls + d * 64 + ((jb ^ (d & 7)) << 3)) = e;
      }
    }
    __syncthreads();

    ushort* pw = pls[w];
#pragma unroll
    for (int sjt = 0; sjt < 4; ++sjt) {
      const int krow = sjt * 16 + lr;
      bf16x8 kf0 = *(const bf16x8*)(kls + krow * 64 + (((0 * 4 + lg) ^ (lr & 7)) << 3));
      bf16x8 kf1 = *(const bf16x8*)(kls + krow * 64 + (((1 * 4 + lg) ^ (lr & 7)) << 3));
#pragma unroll
      for (int rt = 0; rt < 4; ++rt) {
        f32x4 s = (f32x4){0.f, 0.f, 0.f, 0.f};
        s = __builtin_amdgcn_mfma_f32_16x16x32_bf16(qf[rt][0], kf0, s, 0, 0, 0);
        s = __builtin_amdgcn_mfma_f32_16x16x32_bf16(qf[rt][1], kf1, s, 0, 0, 0);
#pragma unroll
        for (int r = 0; r < 4; ++r) {
          int i  = rt * 16 + lg * 4 + r;
          int jj = sjt * 16 + lr;
          pw[i * 64 + ((((jj >> 3) ^ (i & 7)) << 3)) + (jj & 7)] = (short)f2bf(__expf(s[r]));
        }
      }
    }
    bf16x8 pf[4][2];
#pragma unroll
    for (int rt = 0; rt < 4; ++rt)
#pragma unroll
      for (int jc = 0; jc < 2; ++jc)
        pf[rt][jc] = *(const bf16x8*)(pw + (rt * 16 + lr) * 64 + (((jc * 4 + lg) ^ (lr & 7)) << 3));
#pragma unroll
    for (int dt = 0; dt < 5; ++dt) {
      const int vrow = dt * 16 + lr;
      bf16x8 vf0 = *(const bf16x8*)(wls + vrow * 64 + (((0 * 4 + lg) ^ (lr & 7)) << 3));
      bf16x8 vf1 = *(const bf16x8*)(wls + vrow * 64 + (((1 * 4 + lg) ^ (lr & 7)) << 3));
#pragma unroll
      for (int rt = 0; rt < 4; ++rt) {
        acc[rt][dt] = __builtin_amdgcn_mfma_f32_16x16x32_bf16(pf[rt][0], vf0, acc[rt][dt], 0, 0, 0);
        acc[rt][dt] = __builtin_amdgcn_mfma_f32_16x16x32_bf16(pf[rt][1], vf1, acc[rt][dt], 0, 0, 0);
      }
    }
  }

#pragma unroll
  for (int rt = 0; rt < 4; ++rt) {
#pragma unroll
    for (int r = 0; r < 4; ++r) {
      float dn = __shfl(acc[rt][4][r], l & 48);
      float inv = 1.f / dn;
      int gr = rb * 256 + w * 64 + rt * 16 + lg * 4 + r;
      float* op = attn + (size_t)gr * 512 + h_ * 64;
#pragma unroll
      for (int dt = 0; dt < 4; ++dt)
        op[dt * 16 + lr] = acc[rt][dt][r] * inv;
    }
  }
}

// ---------------- depthwise res conv (kernel 33): register sliding window ----------------
// Each thread: one channel c, 8 consecutive rows. 40 V loads -> 8 outputs (vs 264 loads).
// grid (2048, 2); XCD-chunked swizzle keeps overlapping windows in the same L2.
__global__ __launch_bounds__(256) void resconv_kernel(
    const float* __restrict__ qkv, const float* __restrict__ rw, float* __restrict__ attn)
{
  const int bid = blockIdx.x;                 // 0..2047 (2048 % 8 == 0 -> bijective)
  const int rb  = (bid & 7) * 256 + (bid >> 3);
  const int r0  = rb * 8;
  const int c   = blockIdx.y * 256 + threadIdx.x;
  const int h_  = c >> 6;

  float wreg[33];
#pragma unroll
  for (int tp = 0; tp < 33; ++tp) wreg[tp] = rw[h_ * 33 + tp];   // wave-uniform broadcast

  float v[40];
#pragma unroll
  for (int k = 0; k < 40; ++k) {
    int rr = r0 - 16 + k;
    v[k] = (rr >= 0 && rr < NPAD) ? qkv[(size_t)rr * 1536 + 1024 + c] : 0.f;
  }
#pragma unroll
  for (int i = 0; i < 8; ++i) {
    float s = 0.f;
#pragma unroll
    for (int tp = 0; tp < 33; ++tp)
      s = fmaf(v[i + tp], wreg[tp], s);
    attn[(size_t)(r0 + i) * 512 + c] += s;
  }
}

// ---------------- weight transpose for ppeg: wt[k*512+c] ----------------
__global__ __launch_bounds__(256) void wtrans_kernel(
    const float* __restrict__ w7, const float* __restrict__ w5,
    const float* __restrict__ w3, float* __restrict__ wt)
{
  int c = blockIdx.x * 256 + threadIdx.x;
  for (int k = 0; k < 49; ++k) wt[(size_t)k * 512 + c]        = w7[(size_t)c * 49 + k];
  for (int k = 0; k < 25; ++k) wt[(size_t)(49 + k) * 512 + c] = w5[(size_t)c * 25 + k];
  for (int k = 0; k < 9;  ++k) wt[(size_t)(74 + k) * 512 + c] = w3[(size_t)c * 9 + k];
}

// ---------------- PPEG: 128 ch x 2-px-parallel per block, weights in 42.5KB LDS ----------
__global__ __launch_bounds__(256) void ppeg_kernel(
    const float* __restrict__ h, float* __restrict__ tmp,
    const float* __restrict__ wt,
    const float* __restrict__ b7, const float* __restrict__ b5,
    const float* __restrict__ b3)
{
  __shared__ float wl[83 * 128];           // 42,496 B
  const int t = threadIdx.x;
  const int tc = t & 127;
  const int ppar = t >> 7;
  const int c = blockIdx.y * 128 + tc;
  for (int idx = t; idx < 83 * 128; idx += 256)
    wl[idx] = wt[(size_t)(idx >> 7) * 512 + blockIdx.y * 128 + (idx & 127)];
  const float bsum = b7[c] + b5[c] + b3[c];
  __syncthreads();

  const int p0 = blockIdx.x * 64;
  for (int i = 0; i < 32; ++i) {
    int p = p0 + i * 2 + ppar;
    if (p >= NPIX) break;                  // wave-uniform (ppar uniform per wave)
    int y = p / SG, x = p - y * SG;
    float a7 = 0.f, a5 = 0.f, a3 = 0.f;
    if (y >= 3 && y <= SG - 4 && x >= 3 && x <= SG - 4) {
#pragma unroll
      for (int ky = 0; ky < 7; ++ky)
#pragma unroll
        for (int kx = 0; kx < 7; ++kx) {
          float v = h[(size_t)(1 + (y + ky - 3) * SG + (x + kx - 3)) * DD + c];
          a7 = fmaf(v, wl[(ky * 7 + kx) * 128 + tc], a7);
          if (ky >= 1 && ky <= 5 && kx >= 1 && kx <= 5)
            a5 = fmaf(v, wl[(49 + (ky - 1) * 5 + (kx - 1)) * 128 + tc], a5);
          if (ky >= 2 && ky <= 4 && kx >= 2 && kx <= 4)
            a3 = fmaf(v, wl[(74 + (ky - 2) * 3 + (kx - 2)) * 128 + tc], a3);
        }
    } else {
#pragma unroll
      for (int ky = 0; ky < 7; ++ky) {
        int yy = y + ky - 3;
        bool oky = (yy >= 0 && yy < SG);
#pragma unroll
        for (int kx = 0; kx < 7; ++kx) {
          int xx = x + kx - 3;
          float v = (oky && xx >= 0 && xx < SG)
                        ? h[(size_t)(1 + yy * SG + xx) * DD + c] : 0.f;
          a7 = fmaf(v, wl[(ky * 7 + kx) * 128 + tc], a7);
          if (ky >= 1 && ky <= 5 && kx >= 1 && kx <= 5)
            a5 = fmaf(v, wl[(49 + (ky - 1) * 5 + (kx - 1)) * 128 + tc], a5);
          if (ky >= 2 && ky <= 4 && kx >= 2 && kx <= 4)
            a3 = fmaf(v, wl[(74 + (ky - 2) * 3 + (kx - 2)) * 128 + tc], a3);
        }
      }
    }
    tmp[(size_t)p * DD + c] = h[(size_t)(1 + p) * DD + c] + bsum + a7 + a5 + a3;
  }
}

// ---------------- final: LN(row0) -> fc2 -> softmax/argmax ----------------
__global__ __launch_bounds__(256) void final_kernel(
    const float* __restrict__ h, const float* __restrict__ g, const float* __restrict__ b,
    const float* __restrict__ w, const float* __restrict__ bias, float* __restrict__ out)
{
  __shared__ float red[256];
  int t = threadIdx.x;
  float v0 = h[t], v1 = h[t + 256];
  red[t] = v0 + v1;
  __syncthreads();
  for (int s = 128; s > 0; s >>= 1) { if (t < s) red[t] += red[t + s]; __syncthreads(); }
  float mu = red[0] * (1.f / 512.f);
  __syncthreads();
  float d0 = v0 - mu, d1 = v1 - mu;
  red[t] = d0 * d0 + d1 * d1;
  __syncthreads();
  for (int s = 128; s > 0; s >>= 1) { if (t < s) red[t] += red[t + s]; __syncthreads(); }
  float rs = rsqrtf(red[0] * (1.f / 512.f) + 1e-5f);
  __syncthreads();
  float x0 = d0 * rs * g[t] + b[t];
  float x1 = d1 * rs * g[t + 256] + b[t + 256];
  red[t] = x0 * w[t * 2] + x1 * w[(t + 256) * 2];
  __syncthreads();
  for (int s = 128; s > 0; s >>= 1) { if (t < s) red[t] += red[t + s]; __syncthreads(); }
  float l0 = red[0] + bias[0];
  __syncthreads();
  red[t] = x0 * w[t * 2 + 1] + x1 * w[(t + 256) * 2 + 1];
  __syncthreads();
  for (int s = 128; s > 0; s >>= 1) { if (t < s) red[t] += red[t + s]; __syncthreads(); }
  float l1 = red[0] + bias[1];
  if (t == 0) {
    out[0] = l0; out[1] = l1;
    float mx = fmaxf(l0, l1);
    float e0 = __expf(l0 - mx), e1 = __expf(l1 - mx);
    float inv = 1.f / (e0 + e1);
    out[2] = e0 * inv; out[3] = e1 * inv;
    out[4] = (l1 > l0) ? 1.f : 0.f;
  }
}

extern "C" void kernel_launch(void* const* d_in, const int* in_sizes, int n_in,
                              void* d_out, int out_size, void* d_ws, size_t ws_size,
                              hipStream_t stream)
{
  const float* data   = (const float*)d_in[0];
  const float* fc1_w  = (const float*)d_in[1];
  const float* fc1_b  = (const float*)d_in[2];
  const float* cls    = (const float*)d_in[3];
  const float* l1_g   = (const float*)d_in[4];
  const float* l1_b   = (const float*)d_in[5];
  const float* l1_qkv = (const float*)d_in[6];
  const float* l1_ow  = (const float*)d_in[7];
  const float* l1_ob  = (const float*)d_in[8];
  const float* l1_rw  = (const float*)d_in[9];
  const float* w7     = (const float*)d_in[10];
  const float* b7     = (const float*)d_in[11];
  const float* w5     = (const float*)d_in[12];
  const float* b5     = (const float*)d_in[13];
  const float* w3     = (const float*)d_in[14];
  const float* b3     = (const float*)d_in[15];
  const float* l2_g   = (const float*)d_in[16];
  const float* l2_b   = (const float*)d_in[17];
  const float* l2_qkv = (const float*)d_in[18];
  const float* l2_ow  = (const float*)d_in[19];
  const float* l2_ob  = (const float*)d_in[20];
  const float* l2_rw  = (const float*)d_in[21];
  const float* ng     = (const float*)d_in[22];
  const float* nb     = (const float*)d_in[23];
  const float* fc2_w  = (const float*)d_in[24];
  const float* fc2_b  = (const float*)d_in[25];
  float* out = (float*)d_out;

  float* ws   = (float*)d_ws;
  float* h    = ws;
  float* xn   = h    + (size_t)16384 * 512;
  float* qkv  = xn   + (size_t)16384 * 512;
  float* attn = qkv  + (size_t)16384 * 1536;
  float* ql   = attn + (size_t)16384 * 512;
  float* kl   = ql   + 256 * 512;
  float* a2b  = kl   + 256 * 512;
  float* z0   = a2b  + 8 * 256 * 256;
  float* z1   = z0   + 8 * 256 * 256;
  float* xzb  = z1   + 8 * 256 * 256;
  float* tb   = xzb  + 8 * 256 * 256;
  float* ub   = tb   + 8 * 256 * 256;
  float* a3v  = ub   + 8 * 256 * 256;
  float* w2   = a3v  + 8 * 256 * 64;
  float* pacc = w2   + 8 * 256 * 64;           // dead region: 4,194,304 floats (16 MiB)
  float* pms  = pacc + (size_t)8 * 32 * 256 * 64;
  float* red  = pms  + (size_t)8 * 32 * 256 * 2;
  float* wtb  = red  + 32;                       // ppeg weights fp32 (83*512)

  // bf16 transposed weights at start of pacc region: 2.62M ushorts = 1.31M floats
  ushort* fc1_wt  = (ushort*)pacc;
  ushort* qkv_wt0 = fc1_wt + 512 * 1024;
  ushort* qkv_wt1 = qkv_wt0 + 1536 * 512;
  ushort* out_wt0 = qkv_wt1 + 1536 * 512;
  ushort* out_wt1 = out_wt0 + 512 * 512;

  // a3v MFMA partial buffers (alias xn scratch / pms)
  float* a3v_pacc = xn;
  float* a3v_den  = pms;

  // weight prep (bf16 transposes) + fc1 + assemble
  wtrans_bf<<<dim3(16, 32), 256, 0, stream>>>(fc1_w, fc1_wt, 1024, 512);
  wtrans_bf<<<dim3(48, 16), 256, 0, stream>>>(l1_qkv, qkv_wt0, 512, 1536);
  wtrans_bf<<<dim3(48, 16), 256, 0, stream>>>(l2_qkv, qkv_wt1, 512, 1536);
  wtrans_bf<<<dim3(16, 16), 256, 0, stream>>>(l1_ow, out_wt0, 512, 512);
  wtrans_bf<<<dim3(16, 16), 256, 0, stream>>>(l2_ow, out_wt1, 512, 512);
  wtrans_kernel<<<2, 256, 0, stream>>>(w7, w5, w3, wtb);

  gemm_bt<<<dim3(4, 125), 256, 0, stream>>>(data, 1024, fc1_wt, 1024, h + 512, 512,
                                            16000, 1024, 1, fc1_b);
  assemble_kernel<<<260, 256, 0, stream>>>(h, cls);

  for (int layer = 0; layer < 2; ++layer) {
    const float* gg = layer ? l2_g   : l1_g;
    const float* bb = layer ? l2_b   : l1_b;
    const ushort* qw = layer ? qkv_wt1 : qkv_wt0;
    const ushort* ow = layer ? out_wt1 : out_wt0;
    const float* ob = layer ? l2_ob  : l1_ob;
    const float* rw = layer ? l2_rw  : l1_rw;

    ln_pad_kernel<<<16384, 256, 0, stream>>>(h, xn, gg, bb);
    gemm_bt<<<dim3(12, 128), 256, 0, stream>>>(xn, 512, qw, 512, qkv, 1536,
                                               16384, 512, 2, nullptr);
    landmark_kernel<<<dim3(256, 4), 256, 0, stream>>>(qkv, ql, kl);
    a2_kernel<<<dim3(8, 256), 256, 0, stream>>>(ql, kl, a2b);
    pinv_red1<<<8, 256, 0, stream>>>(a2b, red);
    pinv_red2<<<1, 1, 0, stream>>>(red);
    pinv_init<<<dim3(8, 256), 256, 0, stream>>>(a2b, red, z0);
    float* zc = z0; float* zn = z1;
    for (int it = 0; it < 6; ++it) {
      nmm_kernel<<<dim3(4, 4, 8), 256, 0, stream>>>(a2b, zc, xzb, 0);  // xz = a2@z
      nmm_kernel<<<dim3(4, 4, 8), 256, 0, stream>>>(xzb, xzb, tb, 1);  // u1 = 7xz - xz@xz
      nmm_kernel<<<dim3(4, 4, 8), 256, 0, stream>>>(xzb, tb, ub, 2);   // u2 = 15xz - xz@u1
      nmm_kernel<<<dim3(4, 4, 8), 256, 0, stream>>>(zc, ub, zn, 3);    // z' = .25(13z - z@u2)
      float* sw = zc; zc = zn; zn = sw;
    }
    a3v_mfma<<<dim3(8, CHK), 256, 0, stream>>>(qkv, ql, a3v_pacc, a3v_den);
    a3v_merge_kernel<<<dim3(8, 256), 64, 0, stream>>>(a3v_pacc, a3v_den, a3v);
    mmb_kernel<<<dim3(1, 4, 8), 256, 0, stream>>>(zc, a3v, w2, 64, 1.f);
    a1_mfma<<<dim3(8, 64), 256, 0, stream>>>(qkv, kl, w2, attn);
    resconv_kernel<<<dim3(2048, 2), 256, 0, stream>>>(qkv, rw, attn);
    gemm_bt<<<dim3(4, 127), 256, 0, stream>>>(attn + (size_t)254 * 512, 512, ow, 512,
                                              h, 512, 16130, 512, 3, ob);
    if (layer == 0) {
      // ppeg -> qkv scratch (dead until layer-1 recomputes it), memcpy back (round-7 proven)
      ppeg_kernel<<<dim3((NPIX + 63) / 64, 4), 256, 0, stream>>>(h, qkv, wtb, b7, b5, b3);
      hipMemcpyAsync(h + 512, qkv, (size_t)16129 * 512 * 4,
                     hipMemcpyDeviceToDevice, stream);
    }
  }
  final_kernel<<<1, 256, 0, stream>>>(h, ng, nb, fc2_w, fc2_b, out);
}